// Round 6
// baseline (345.303 us; speedup 1.0000x reference)
//
#include <hip/hip_runtime.h>
#include <cmath>
#include <complex>
#include <algorithm>

// ---------------------------------------------------------------------------
// Problem constants: LMAX=2, NC=9, H=8, DQK=32, CV=16, K=8, U=25, N=2048, C=256
// ---------------------------------------------------------------------------

typedef _Float16 half8 __attribute__((ext_vector_type(8)));
typedef _Float16 half4v __attribute__((ext_vector_type(4)));
typedef float float4v __attribute__((ext_vector_type(4)));

// ========================= host-side constant tables ========================
namespace {

using cd = std::complex<double>;

static double fct(int n) { double r = 1.0; for (int i = 2; i <= n; ++i) r *= i; return r; }

static double cg_coef(int j1, int m1, int j2, int m2, int j, int m) {
    if (m1 + m2 != m || j < std::abs(j1 - j2) || j > j1 + j2) return 0.0;
    double pref = std::sqrt((2 * j + 1) * fct(j + j1 - j2) * fct(j - j1 + j2) * fct(j1 + j2 - j) / fct(j1 + j2 + j + 1));
    pref *= std::sqrt(fct(j + m) * fct(j - m) * fct(j1 - m1) * fct(j1 + m1) * fct(j2 - m2) * fct(j2 + m2));
    double s = 0.0;
    for (int k = 0; k <= j1 + j2 - j; ++k) {
        int d0 = k, d1 = j1 + j2 - j - k, d2 = j1 - m1 - k, d3 = j2 + m2 - k, d4 = j - j2 + m1 + k, d5 = j - j1 - m2 + k;
        if (d0 < 0 || d1 < 0 || d2 < 0 || d3 < 0 || d4 < 0 || d5 < 0) continue;
        s += ((k & 1) ? -1.0 : 1.0) / (fct(d0) * fct(d1) * fct(d2) * fct(d3) * fct(d4) * fct(d5));
    }
    return pref * s;
}

static void umat(int l, cd u[5][5]) {
    for (int i = 0; i < 5; i++) for (int j = 0; j < 5; j++) u[i][j] = cd(0, 0);
    const double s = 1.0 / std::sqrt(2.0);
    for (int m = -l; m <= l; m++) {
        double sgn = (std::abs(m) & 1) ? -1.0 : 1.0;   // (-1)^m
        if (m > 0)      { u[l + m][l + m] = cd(sgn * s, 0); u[l + m][l - m] = cd(s, 0); }
        else if (m == 0){ u[l][l] = cd(1, 0); }
        else            { u[l + m][l + m] = cd(0, s);       u[l + m][l - m] = cd(0, -sgn * s); }
    }
}

static void real_cg_f(int l1, int l2, int L, double out[5][5][5]) {
    cd U1[5][5], U2[5][5], UL[5][5];
    umat(l1, U1); umat(l2, U2); umat(L, UL);
    const int n1 = 2 * l1 + 1, n2 = 2 * l2 + 1, n3 = 2 * L + 1;
    double cgt[5][5][5];
    for (int i1 = 0; i1 < n1; i1++) for (int i2 = 0; i2 < n2; i2++) for (int i3 = 0; i3 < n3; i3++)
        cgt[i1][i2][i3] = cg_coef(l1, i1 - l1, l2, i2 - l2, L, i3 - L);
    cd r[5][5][5];
    double nr = 0, ni = 0;
    for (int a1 = 0; a1 < n1; a1++) for (int b = 0; b < n2; b++) for (int c = 0; c < n3; c++) {
        cd acc(0, 0);
        for (int uu = 0; uu < n1; uu++) for (int vv = 0; vv < n2; vv++) for (int w = 0; w < n3; w++) {
            double cval = cgt[uu][vv][w];
            if (cval == 0.0) continue;
            acc += U1[a1][uu] * U2[b][vv] * std::conj(UL[c][w]) * cval;
        }
        r[a1][b][c] = acc;
        nr += acc.real() * acc.real();
        ni += acc.imag() * acc.imag();
    }
    const bool useRe = std::sqrt(nr) >= std::sqrt(ni);
    for (int a1 = 0; a1 < n1; a1++) for (int b = 0; b < n2; b++) for (int c = 0; c < n3; c++)
        out[a1][b][c] = useRe ? r[a1][b][c].real() : r[a1][b][c].imag();
}

// device constant buffer layout: YW[9*25] | RRED[9*81] | DIRS[25*3]  = 1029 floats
static float  h_const[1029];
static float* d_const_g = nullptr;

struct GlobalInit {
    GlobalInit() {
        const double PI = 3.14159265358979323846;
        const double gx[5] = {-0.9061798459386640, -0.5384693101056831, 0.0, 0.5384693101056831, 0.9061798459386640};
        const double gw[5] = { 0.23692688505618908, 0.47862867049936647, 0.5688888888888889, 0.47862867049936647, 0.23692688505618908};
        double YW[9][25], DIRS[25][3];
        for (int u = 0; u < 25; ++u) {
            const int it = u / 5, ip = u % 5;
            const double ct = gx[it], wq = gw[it] * (2.0 * PI / 5.0), ph = 2.0 * PI * ip / 5.0;
            const double st = std::sqrt(std::max(1.0 - ct * ct, 0.0));
            const double x = st * std::cos(ph), y = st * std::sin(ph), z = ct;
            DIRS[u][0] = x; DIRS[u][1] = y; DIRS[u][2] = z;
            double Y[9];
            Y[0] = 0.282095;           Y[1] = 0.488603 * y;      Y[2] = 0.488603 * z;
            Y[3] = 0.488603 * x;       Y[4] = 1.092548 * x * y;  Y[5] = 1.092548 * y * z;
            Y[6] = 0.315392 * (3 * z * z - 1); Y[7] = 1.092548 * x * z; Y[8] = 0.546274 * (x * x - y * y);
            for (int e = 0; e < 9; e++) YW[e][u] = Y[e] * wq;
        }
        double RRED[9][9][9];
        for (int i = 0; i < 9; i++) for (int j = 0; j < 9; j++) for (int k = 0; k < 9; k++) RRED[i][j][k] = 0.0;
        const int off[3] = {0, 1, 4};
        double cnt[3] = {0, 0, 0};
        double rc[5][5][5];
        for (int l1 = 0; l1 <= 2; l1++) for (int l2 = 0; l2 <= 2; l2++) {
            const int Llo = std::abs(l1 - l2), Lhi = std::min(l1 + l2, 2);
            for (int L = Llo; L <= Lhi; L++) {
                real_cg_f(l1, l2, L, rc);
                for (int i1 = 0; i1 < 2 * l1 + 1; i1++)
                    for (int i2 = 0; i2 < 2 * l2 + 1; i2++)
                        for (int i3 = 0; i3 < 2 * L + 1; i3++)
                            RRED[off[l1] + i1][off[l2] + i2][off[L] + i3] += rc[i1][i2][i3];
                cnt[L] += 1.0;
            }
        }
        for (int L = 0; L <= 2; L++) {
            const double dv = std::max(cnt[L], 1.0);
            for (int a1 = 0; a1 < 9; a1++) for (int b = 0; b < 9; b++)
                for (int k = 0; k < 2 * L + 1; k++) RRED[a1][b][off[L] + k] /= dv;
        }
        for (int e = 0; e < 9; e++) for (int u = 0; u < 25; u++) h_const[e * 25 + u] = (float)YW[e][u];
        for (int e = 0; e < 9; e++) for (int l = 0; l < 9; l++) for (int m = 0; m < 9; m++)
            h_const[225 + e * 81 + l * 9 + m] = (float)RRED[e][l][m];
        for (int u = 0; u < 25; u++) for (int ax = 0; ax < 3; ax++) h_const[954 + u * 3 + ax] = (float)DIRS[u][ax];
        if (hipMalloc((void**)&d_const_g, 1029 * sizeof(float)) == hipSuccess)
            hipMemcpy(d_const_g, h_const, 1029 * sizeof(float), hipMemcpyHostToDevice);
    }
} g_init;

} // namespace

// ============================== device kernels ==============================

// R[n][p][c]: p=0 -> feat(l=0); p=1 -> |l=1 block|; p=2 -> |l=2 block|
__global__ void radial_k(const float* __restrict__ feat, float* __restrict__ R) {
    const int n = blockIdx.x, c = threadIdx.x;
    const float* f = feat + (size_t)n * 9 * 256 + c;
    const float f0 = f[0];
    const float a1 = f[256], a2 = f[512], a3 = f[768];
    const float b1 = f[1024], b2 = f[1280], b3 = f[1536], b4 = f[1792], b5 = f[2048];
    const float r1 = sqrtf(a1 * a1 + a2 * a2 + a3 * a3 + 1e-8f);
    const float r2 = sqrtf(b1 * b1 + b2 * b2 + b3 * b3 + b4 * b4 + b5 * b5 + 1e-8f);
    float* o = R + (size_t)n * 768 + c;
    o[0] = f0; o[256] = r1; o[512] = r2;
}

// fused Q/K projection GEMM (f16 MFMA): A = R (2048x768), B = Wq or Wk (768x256)
// grid (8, 32): x<4 -> Wq cols (cb=x*64), epilogue elu+1 -> qf row-major f32
//               x>=4 -> Wk cols (cb=(x-4)*64), epilogue elu+1 -> kfA frag f16
__global__ __launch_bounds__(256) void qk_gemm_k(const float* __restrict__ A,
                                                 const float* __restrict__ Wq,
                                                 const float* __restrict__ Wk,
                                                 float* __restrict__ qf,
                                                 _Float16* __restrict__ kfA) {
    __shared__ __align__(16) _Float16 Af[64 * 40];
    __shared__ __align__(16) _Float16 Bf[64 * 40];
    const int tid = threadIdx.x;
    const int w = tid >> 6, lane = tid & 63;
    const int l15 = lane & 15, quad = lane >> 4;
    const bool isK = blockIdx.x >= 4;
    const int cb = (blockIdx.x & 3) * 64;
    const int rb = blockIdx.y * 64;
    const float* B = isK ? Wk : Wq;
    const int N = 256, Kd = 768;
    const int sr = tid >> 2, sq = tid & 3;

    float4v acc[4];
#pragma unroll
    for (int s = 0; s < 4; s++) acc[s] = float4v{0.f, 0.f, 0.f, 0.f};

    for (int k0 = 0; k0 < Kd; k0 += 32) {
        __syncthreads();
        {
            const float* Ap = A + (size_t)(rb + sr) * Kd + k0 + sq * 8;
            const float4 a0 = *(const float4*)(Ap);
            const float4 a1 = *(const float4*)(Ap + 4);
            half8 hv;
            hv[0] = (_Float16)a0.x; hv[1] = (_Float16)a0.y; hv[2] = (_Float16)a0.z; hv[3] = (_Float16)a0.w;
            hv[4] = (_Float16)a1.x; hv[5] = (_Float16)a1.y; hv[6] = (_Float16)a1.z; hv[7] = (_Float16)a1.w;
            *(half8*)&Af[sr * 40 + sq * 8] = hv;
        }
        {
            const float* Bp = B + (size_t)(k0 + sq * 8) * N + cb + sr;
            half8 hv;
#pragma unroll
            for (int i = 0; i < 8; i++) hv[i] = (_Float16)Bp[(size_t)i * N];
            *(half8*)&Bf[sr * 40 + sq * 8] = hv;
        }
        __syncthreads();
        const half8 af = *(const half8*)&Af[(w * 16 + l15) * 40 + quad * 8];
#pragma unroll
        for (int s = 0; s < 4; s++) {
            const half8 bf = *(const half8*)&Bf[(s * 16 + l15) * 40 + quad * 8];
            acc[s] = __builtin_amdgcn_mfma_f32_16x16x32_f16(af, bf, acc[s], 0, 0, 0);
        }
    }
#pragma unroll
    for (int s = 0; s < 4; s++) {
#pragma unroll
        for (int r = 0; r < 4; r++) {
            const int row = rb + w * 16 + quad * 4 + r;
            const int col = cb + s * 16 + l15;
            float val = acc[s][r];
            val = (val > 0.f ? val : expf(val) - 1.f) + 1.f;
            if (isK) {
                const int hh = col >> 5, dd = col & 31, tt = dd >> 4, ll = dd & 15;
                kfA[(size_t)hh * 65536 + (size_t)(row >> 5) * 1024 + tt * 512 + ll * 32 + (row & 31)] = (_Float16)val;
            } else {
                qf[(size_t)row * 256 + col] = val;
            }
        }
    }
}

// f16 MFMA GEMM, C = A(MxK) @ B(KxN), M%64==0, N%64==0, K%32==0.
// mode 2: A f32, v16T f16 scatter
// mode 4 (R19: extended-K over partials): A = 8 f16 partial buffers laid out
//   as K' = s*128 + j (s = k0>>7 selects buffer at stride 2359296 halves,
//   j = k0&127 the within-partial k). B row wraps: Wo[(k' % 128)]. The 8-way
//   partial sum happens inside the MFMA f32 accumulator; stage-A is a single
//   coalesced half8 load (R17's 8-stream gather was ~+17us). rz was already
//   applied in mm_local's epilogue. Plain f32 C row-major.
__global__ __launch_bounds__(256) void mfma_gemm16_k(const float* __restrict__ A, const float* __restrict__ B,
                                                     float* __restrict__ Cv, int M, int N, int Kd, int mode,
                                                     const float* __restrict__ rZ) {
    __shared__ __align__(16) _Float16 Af[64 * 40];   // [row][k], stride 40 halves (80 B)
    __shared__ __align__(16) _Float16 Bf[64 * 40];   // [col][k]
    const int tid = threadIdx.x;
    const int w = tid >> 6, lane = tid & 63;
    const int l15 = lane & 15, quad = lane >> 4;
    const int rb = blockIdx.y * 64, cb = blockIdx.x * 64;
    const int sr = tid >> 2, sq = tid & 3;           // stager: row/col 0..63, k-quartet 0..3

    float4v acc[4];
#pragma unroll
    for (int s = 0; s < 4; s++) acc[s] = float4v{0.f, 0.f, 0.f, 0.f};

    for (int k0 = 0; k0 < Kd; k0 += 32) {
        __syncthreads();
        // ---- stage A (-> f16, fragment order) ----
        if (mode == 4) {
            const int s8 = k0 >> 7;                  // partial buffer index
            const int j0 = (k0 & 127) + sq * 8;      // within-partial k
            const _Float16* Ap16 = (const _Float16*)A + (size_t)s8 * 2359296 + (size_t)(rb + sr) * 128 + j0;
            *(half8*)&Af[sr * 40 + sq * 8] = *(const half8*)Ap16;
        } else {
            const float* Ap = A + (size_t)(rb + sr) * Kd + k0 + sq * 8;
            const float4 a0 = *(const float4*)(Ap);
            const float4 a1 = *(const float4*)(Ap + 4);
            half8 hv;
            hv[0] = (_Float16)a0.x; hv[1] = (_Float16)a0.y; hv[2] = (_Float16)a0.z; hv[3] = (_Float16)a0.w;
            hv[4] = (_Float16)a1.x; hv[5] = (_Float16)a1.y; hv[6] = (_Float16)a1.z; hv[7] = (_Float16)a1.w;
            *(half8*)&Af[sr * 40 + sq * 8] = hv;
        }
        // ---- stage B (column gather; f32 -> f16; mode 4 wraps row % 128) ----
        {
            const int brow = (mode == 4) ? ((k0 & 127) + sq * 8) : (k0 + sq * 8);
            const float* Bp = B + (size_t)brow * N + cb + sr;
            half8 hv;
#pragma unroll
            for (int i = 0; i < 8; i++) hv[i] = (_Float16)Bp[(size_t)i * N];
            *(half8*)&Bf[sr * 40 + sq * 8] = hv;
        }
        __syncthreads();
        // ---- fragments + MFMA ----
        const half8 af = *(const half8*)&Af[(w * 16 + l15) * 40 + quad * 8];
#pragma unroll
        for (int s = 0; s < 4; s++) {
            const half8 bf = *(const half8*)&Bf[(s * 16 + l15) * 40 + quad * 8];
            acc[s] = __builtin_amdgcn_mfma_f32_16x16x32_f16(af, bf, acc[s], 0, 0, 0);
        }
    }
    // ---- epilogue: C fragment (row = rb+w*16+quad*4+r, col = cb+s*16+l15) ----
#pragma unroll
    for (int s = 0; s < 4; s++) {
#pragma unroll
        for (int r = 0; r < 4; r++) {
            const int row = rb + w * 16 + quad * 4 + r;
            const int col = cb + s * 16 + l15;
            float val = acc[s][r];
            if (mode == 2) {
                // v16T[(h*144 + c*9 + l)][n] f16
                const int n = row / 9, l = row - n * 9, hq = col >> 4, cvq = col & 15;
                _Float16* o = (_Float16*)Cv;
                o[((size_t)hq * 144 + cvq * 9 + l) * 2048 + n] = (_Float16)val;
            } else {
                Cv[(size_t)row * N + col] = val;
            }
        }
    }
}

// trigA[nb5][kkut][j] (f16, fragment-ordered) = cos/sin(kappa_kk * pos_n . dir_u)
//   kkut = (kk*25+u)*2+t (rows, padded to 512), nb5 = n>>5, j = n&31
// threads 200..255 zero the pad rows 400..511 for this n's j-slot (replaces memset)
__global__ void trig_k(const float* __restrict__ pos, const float* __restrict__ kappa,
                       const float* __restrict__ cst, _Float16* __restrict__ trigA) {
    const int n = blockIdx.x, t = threadIdx.x;
    const size_t base = (size_t)(n >> 5) * 16384 + (n & 31);
    if (t < 200) {
        const int kq = t / 25, u = t - kq * 25;
        const float* dirs = cst + 954;
        const float ph = kappa[kq] * (pos[n * 3] * dirs[u * 3] + pos[n * 3 + 1] * dirs[u * 3 + 1] + pos[n * 3 + 2] * dirs[u * 3 + 2]);
        float s, c;
        sincosf(ph, &s, &c);
        const int kkut = (kq * 25 + u) * 2;
        trigA[base + (size_t)kkut * 32] = (_Float16)c;
        trigA[base + (size_t)(kkut + 1) * 32] = (_Float16)s;
    } else {
        const int kkut = 400 + (t - 200) * 2;
        trigA[base + (size_t)kkut * 32] = (_Float16)0.f;
        trigA[base + (size_t)(kkut + 1) * 32] = (_Float16)0.f;
    }
}

// ksum[h*32+d] = sum_n kfA[h][nb5][t][l15][j]; one block per (h,d)
__global__ void ksumT_k(const _Float16* __restrict__ kfA, float* __restrict__ ksum) {
    const int b = blockIdx.x;                       // h*32+d
    const int h = b >> 5, d = b & 31, t = d >> 4, l15 = d & 15;
    const int i = threadIdx.x;                      // 256
    const half8 v = *(const half8*)(kfA + (size_t)h * 65536 + (size_t)(i >> 2) * 1024 + t * 512 + l15 * 32 + (i & 3) * 8);
    float s = 0.f;
#pragma unroll
    for (int k = 0; k < 8; k++) s += (float)v[k];
#pragma unroll
    for (int off = 32; off > 0; off >>= 1) s += __shfl_down(s, off, 64);
    __shared__ float red[4];
    if ((i & 63) == 0) red[i >> 6] = s;
    __syncthreads();
    if (i == 0) ksum[b] = red[0] + red[1] + red[2] + red[3];
}

// merged z + g (block-range dispatch, 128 blocks):
//   blocks 0..63:  rz[n][h] = 1 / (qf[n,h,:].ksum[h,:] + 1e-6)
//   blocks 64..127: G[kk][h][u][l*9+m] = sum_e aE[e,h,kk]*YW[e,u]*RRED[e,l,m]
__global__ void zg_k(const float* __restrict__ qf, const float* __restrict__ ksum, float* __restrict__ rz,
                     const float* __restrict__ a, const float* __restrict__ cst, float* __restrict__ G) {
    if (blockIdx.x < 64) {
        const int idx = blockIdx.x * 256 + threadIdx.x;   // N*H = 16384
        const int n = idx >> 3, h = idx & 7;
        float s = 0.f;
#pragma unroll
        for (int d = 0; d < 32; d++) s += qf[(size_t)n * 256 + h * 32 + d] * ksum[h * 32 + d];
        rz[idx] = 1.0f / (s + 1e-6f);
    } else {
        const int b = blockIdx.x - 64;
        const int kk = b & 7, h = b >> 3;
        __shared__ float ae[9];
        if (threadIdx.x < 9) {
            const int ldeg[9] = {0, 1, 1, 1, 2, 2, 2, 2, 2};
            ae[threadIdx.x] = a[ldeg[threadIdx.x] * 64 + h * 8 + kk];
        }
        __syncthreads();
        const float* yw = cst;
        const float* rred = cst + 225;
        for (int i = threadIdx.x; i < 25 * 81; i += 256) {
            const int u = i / 81, lm = i - u * 81;
            float s = 0.f;
#pragma unroll
            for (int e = 0; e < 9; e++) s += ae[e] * yw[e * 25 + u] * rred[e * 81 + lm];
            G[((size_t)(kk * 8 + h) * 25 + u) * 81 + lm] = s;
        }
    }
}

// MFMA multipole (R14: LDS operand sharing):
//   M16[kkut][h][cl*32+d] = sum_n trigA * kfA * v16T
// R13 post-mortem: af/kq loads are identical across the block's 4 waves; each
// wave privately pulled ~8KB/step through the CU's L1->RF return path
// (~64B/cyc) -> return-path bound at ~20% MfmaUtil regardless of pipelining.
// R14: per round of 4 steps (128 n), each wave gathers 5x16B/lane (its step's
// af0/af1/kq0/kq1 + its own vq slab) and ds_writes them fragment-ordered into
// a double-buffered LDS image. Compute reads af/kq lane-linear (conflict-free)
// and vq via quad-broadcast (LDS broadcast is free). Global bytes/block drop
// 4x for af/kq; fan-out moves to the wider LDS path. One barrier per round.
// grid (8 h, 9 colgroups, 13 rowpairs), 256 thr; gridDim.x==8 keeps h->XCD
// affinity (R12). __launch_bounds__(256,3): 3 blocks/CU (LDS 40KB, regs<=170).
__global__ __launch_bounds__(256, 3) void multipole_mm_k(const _Float16* __restrict__ trigA,
                                                         const _Float16* __restrict__ kfA,
                                                         const _Float16* __restrict__ v16T,
                                                         _Float16* __restrict__ M16) {
    const int h   = blockIdx.x;
    const int tid = threadIdx.x;
    const int w = tid >> 6, lane = tid & 63;
    const int l15 = lane & 15, quad = lane >> 4;
    const int cb  = blockIdx.y * 512 + w * 128;   // 4 cl per wave -> 128 cols
    const int cl0 = cb >> 5;
    const int r0  = blockIdx.z * 32;              // rows (kkut), 13*32 = 416

    // LDS: [buf][unit][512 halves]; unit s*4+{0:af0,1:af1,2:kq0,3:kq1} for step
    // s=0..3 of the round, unit 16+w = wave-private vq slab (4 steps x 4 c x 32 n).
    __shared__ __align__(16) _Float16 sb[2][20][512];   // 40 KB

    float4v acc[2][8];
#pragma unroll
    for (int rt = 0; rt < 2; rt++)
#pragma unroll
        for (int s = 0; s < 8; s++) acc[rt][s] = float4v{0.f, 0.f, 0.f, 0.f};

    // gather bases: this wave stages step s==w of each round (nb = nbr + w*32)
    const _Float16* afg0 = trigA + (size_t)(r0 + l15) * 32 + quad * 8;            // + nb5*16384
    const _Float16* afg1 = afg0 + 512;                                            // rows +16
    const _Float16* kqg0 = kfA + (size_t)h * 65536 + (size_t)l15 * 32 + quad * 8; // + nb5*1024
    const _Float16* kqg1 = kqg0 + 512;
    const int vs = lane >> 4, vc = (lane >> 2) & 3, vg = lane & 3;                // vq gather decomp
    const _Float16* vqg = v16T + (size_t)(h * 144 + cl0 + vc) * 2048 + vs * 32 + vg * 8; // + nbr

    half8 g0, g1, g2, g3, g4;

#define GATHER(nbr_) { \
        const size_t t5 = (size_t)((nbr_) >> 5) + w; \
        g0 = *(const half8*)(afg0 + t5 * 16384); \
        g1 = *(const half8*)(afg1 + t5 * 16384); \
        g2 = *(const half8*)(kqg0 + t5 * 1024); \
        g3 = *(const half8*)(kqg1 + t5 * 1024); \
        g4 = *(const half8*)(vqg + (nbr_)); }

#define DSWRITE(b_) { \
        *(half8*)&sb[b_][w * 4 + 0][lane * 8] = g0; \
        *(half8*)&sb[b_][w * 4 + 1][lane * 8] = g1; \
        *(half8*)&sb[b_][w * 4 + 2][lane * 8] = g2; \
        *(half8*)&sb[b_][w * 4 + 3][lane * 8] = g3; \
        *(half8*)&sb[b_][16 + w][lane * 8] = g4; }

#define STEP(s_) { \
        const half8 af0 = *(const half8*)&sb[cur][(s_) * 4 + 0][lane * 8]; \
        const half8 af1 = *(const half8*)&sb[cur][(s_) * 4 + 1][lane * 8]; \
        const half8 kq0 = *(const half8*)&sb[cur][(s_) * 4 + 2][lane * 8]; \
        const half8 kq1 = *(const half8*)&sb[cur][(s_) * 4 + 3][lane * 8]; \
        _Pragma("unroll") \
        for (int c = 0; c < 4; c++) { \
            const half8 vq = *(const half8*)&sb[cur][16 + w][((s_) * 4 + c) * 32 + quad * 8]; \
            const half8 b0 = kq0 * vq; \
            const half8 b1 = kq1 * vq; \
            acc[0][2 * c]     = __builtin_amdgcn_mfma_f32_16x16x32_f16(af0, b0, acc[0][2 * c],     0, 0, 0); \
            acc[0][2 * c + 1] = __builtin_amdgcn_mfma_f32_16x16x32_f16(af0, b1, acc[0][2 * c + 1], 0, 0, 0); \
            acc[1][2 * c]     = __builtin_amdgcn_mfma_f32_16x16x32_f16(af1, b0, acc[1][2 * c],     0, 0, 0); \
            acc[1][2 * c + 1] = __builtin_amdgcn_mfma_f32_16x16x32_f16(af1, b1, acc[1][2 * c + 1], 0, 0, 0); \
        } }

    int cur = 0;
    GATHER(0)
    DSWRITE(0)
    __syncthreads();
#pragma unroll 1
    for (int r = 0; r < 16; ++r) {
        if (r < 15) GATHER((r + 1) * 128)
        STEP(0)
        STEP(1)
        STEP(2)
        STEP(3)
        if (r < 15) DSWRITE(cur ^ 1)
        __syncthreads();
        cur ^= 1;
    }

#undef GATHER
#undef DSWRITE
#undef STEP

    // epilogue: C fragment -> M16[kkut][h][col]
#pragma unroll
    for (int rt = 0; rt < 2; rt++)
#pragma unroll
        for (int c = 0; c < 4; c++)
#pragma unroll
            for (int half = 0; half < 2; half++)
#pragma unroll
                for (int r = 0; r < 4; r++) {
                    const int row = r0 + rt * 16 + quad * 4 + r;
                    const int col = cb + c * 32 + half * 16 + l15;
                    M16[((size_t)row * 8 + h) * 4608 + col] = (_Float16)acc[rt][c * 2 + half][r];
                }
}

// MG[kt][h][ct*512 + quad*128 + l15*8 + j] (f16, fragment-ordered)
//   = sum_l M16[kt][h][(c*9+l)*32+d] * G[kk,h,u][l*9+m], cm=ct*16+l15, d=quad*8+j
__global__ __launch_bounds__(256) void fold_k(const _Float16* __restrict__ Mv, const float* __restrict__ G,
                                              _Float16* __restrict__ MG) {
    const int kt = blockIdx.x, h = blockIdx.y;
    const int tid = threadIdx.x;
    __shared__ float ms[144 * 33];   // [cl][d] padded 33
    __shared__ float gs[81];
    const _Float16* src = Mv + ((size_t)kt * 8 + h) * 4608;
    for (int i = tid; i < 4608; i += 256) {
        const int cl = i >> 5, d = i & 31;
        ms[cl * 33 + d] = (float)src[i];
    }
    const int kk = kt / 50, u = (kt >> 1) % 25;
    if (tid < 81) gs[tid] = G[(((size_t)kk * 8 + h) * 25 + u) * 81 + tid];
    __syncthreads();
    _Float16* dst = MG + ((size_t)kt * 8 + h) * 4608;
    for (int i = tid; i < 4608; i += 256) {
        const int ct = i >> 9, quad = (i >> 7) & 3, l15 = (i >> 3) & 15, j = i & 7;
        const int d = quad * 8 + j;
        const int cm = ct * 16 + l15, c = cm / 9, m = cm - c * 9;
        float s = 0.f;
#pragma unroll
        for (int l = 0; l < 9; l++) s += ms[(c * 9 + l) * 33 + d] * gs[l * 9 + m];
        dst[i] = (_Float16)s;
    }
}

// local stage via MFMA (R19: 64 rows/wave, 2 blocks/CU, 4-kt rounds):
// R17 post-mortem: 2-kt rounds gave only ~500cy compute per round -- too
// short to cover L2 latency of the prefetch (R15's working mechanism used
// ~1100cy rounds). R19 restores rounds of 4 kt (12 full + 2-kt tail) at 64
// rows/wave and 8 slices (512 blocks, 2/CU). LDS 73.7KB double-buffered
// (147KB/CU fits). rz[n][h] now applied here in the epilogue (f32 multiply
// before the single f16 rounding) so the out-GEMM reads plain partials.
__global__ __launch_bounds__(256, 2) void mm_local_k(const float* __restrict__ qf, const _Float16* __restrict__ trigA,
                                                     const _Float16* __restrict__ MG, const float* __restrict__ rZ,
                                                     _Float16* __restrict__ outp) {
    const int combo = blockIdx.y * 8 + blockIdx.x;
    const int h = combo >> 3;
    const int slice = combo & 7;
    const int n0 = blockIdx.z * 256;
    const int tid = threadIdx.x;
    const int w = tid >> 6, lane = tid & 63;
    const int l15 = lane & 15, quad = lane >> 4;

    // staging sb[2][4][4608] f16 (73728B), overlaid later by epilogue eb (37888B)
    __shared__ __align__(16) unsigned char smem_raw[73728];
    _Float16 (*sb)[4][4608] = (_Float16 (*)[4][4608])smem_raw;

    const int nbase = n0 + w * 64;                      // 64 rows per wave
    half8 qfr16[4];
#pragma unroll
    for (int rt = 0; rt < 4; rt++) {
        const int n = nbase + rt * 16 + l15;
        const float* qp = qf + (size_t)n * 256 + h * 32 + quad * 8;
#pragma unroll
        for (int j = 0; j < 8; j++) qfr16[rt][j] = (_Float16)qp[j];
    }
    float4v acc[4][9];
#pragma unroll
    for (int rt = 0; rt < 4; rt++)
#pragma unroll
        for (int ct = 0; ct < 9; ct++) acc[rt][ct] = float4v{0.f, 0.f, 0.f, 0.f};

    const int kt0 = slice * 50;
    // per-lane staging source: lane*8 halves = quad*128 + l15*8 (the read offset)
    const _Float16* mg0 = MG + (((size_t)kt0 * 8 + h) * 4608) + lane * 8;
    // trig scalars: trigA[nb5][kt][..]; rt0/1 at offsets 0/16 of slab nbase>>5,
    // rt2/3 at offsets 0/16 of slab +1 (+16384 halves)
    const _Float16* trg0 = trigA + (size_t)(nbase >> 5) * 16384 + (size_t)kt0 * 32 + l15;

    // wave w stages kt = base_ + w of this slice: 9 x global_load_lds_dwordx4
#define STAGE4(b_, base_) { \
        const _Float16* src = mg0 + (size_t)((base_) + w) * 8 * 4608; \
        _Float16* dstl = &sb[b_][w][0]; \
        _Pragma("unroll") \
        for (int i = 0; i < 9; i++) \
            __builtin_amdgcn_global_load_lds( \
                (const __attribute__((address_space(1))) void*)(src + i * 512), \
                (__attribute__((address_space(3))) void*)(dstl + i * 512), 16, 0, 0); }
#define STAGE2(b_, base_) if (w < 2) STAGE4(b_, base_)

#define COMPUTE(kl) { \
        half8 tv0, tv1, tv2, tv3; \
        _Pragma("unroll") \
        for (int j = 0; j < 8; j++) { tv0[j] = ta[kl]; tv1[j] = tb[kl]; tv2[j] = tc[kl]; tv3[j] = td[kl]; } \
        const half8 af0 = tv0 * qfr16[0]; \
        const half8 af1 = tv1 * qfr16[1]; \
        const half8 af2 = tv2 * qfr16[2]; \
        const half8 af3 = tv3 * qfr16[3]; \
        _Pragma("unroll") \
        for (int ct = 0; ct < 9; ct++) { \
            const half8 b = *(const half8*)&sb[cur][kl][ct * 512 + quad * 128 + l15 * 8]; \
            acc[0][ct] = __builtin_amdgcn_mfma_f32_16x16x32_f16(af0, b, acc[0][ct], 0, 0, 0); \
            acc[1][ct] = __builtin_amdgcn_mfma_f32_16x16x32_f16(af1, b, acc[1][ct], 0, 0, 0); \
            acc[2][ct] = __builtin_amdgcn_mfma_f32_16x16x32_f16(af2, b, acc[2][ct], 0, 0, 0); \
            acc[3][ct] = __builtin_amdgcn_mfma_f32_16x16x32_f16(af3, b, acc[3][ct], 0, 0, 0); \
        } }

    _Float16 ta[4], tb[4], tc[4], td[4], ua[4], ub[4], uc[4], ud[4];
    int cur = 0;
    STAGE4(0, 0)
#pragma unroll
    for (int kl = 0; kl < 4; kl++) {
        ta[kl] = trg0[kl * 32];           tb[kl] = trg0[kl * 32 + 16];
        tc[kl] = trg0[16384 + kl * 32];   td[kl] = trg0[16384 + kl * 32 + 16];
    }
    __syncthreads();

#pragma unroll 1
    for (int r = 0; r < 12; ++r) {
        if (r < 11) {
            STAGE4(cur ^ 1, (r + 1) * 4)
#pragma unroll
            for (int kl = 0; kl < 4; kl++) {
                const size_t o = (size_t)((r + 1) * 4 + kl) * 32;
                ua[kl] = trg0[o];           ub[kl] = trg0[o + 16];
                uc[kl] = trg0[16384 + o];   ud[kl] = trg0[16384 + o + 16];
            }
        } else {
            STAGE2(cur ^ 1, 48)
#pragma unroll
            for (int kl = 0; kl < 2; kl++) {
                const size_t o = (size_t)(48 + kl) * 32;
                ua[kl] = trg0[o];           ub[kl] = trg0[o + 16];
                uc[kl] = trg0[16384 + o];   ud[kl] = trg0[16384 + o + 16];
            }
            ua[2] = ub[2] = uc[2] = ud[2] = (_Float16)0.f;
            ua[3] = ub[3] = uc[3] = ud[3] = (_Float16)0.f;
        }
        COMPUTE(0) COMPUTE(1) COMPUTE(2) COMPUTE(3)
        __syncthreads();
        cur ^= 1;
#pragma unroll
        for (int kl = 0; kl < 4; kl++) { ta[kl] = ua[kl]; tb[kl] = ub[kl]; tc[kl] = uc[kl]; td[kl] = ud[kl]; }
    }
    // tail round: kt 48,49 already staged in sb[cur]
    COMPUTE(0) COMPUTE(1)

#undef STAGE4
#undef STAGE2
#undef COMPUTE

    // epilogue: LDS transpose -> coalesced f16 stores into outp[slice][n][m][h*16+c]
    // rz[n][h] applied here (f32, before the single f16 rounding).
    // eb overlaid on sb (dead; 37888B <= 73728B)
    float* ebp = (float*)smem_raw;
    _Float16* dst = outp + (size_t)slice * 2359296;
    const int g4 = lane >> 2, sub = lane & 3;
#pragma unroll
    for (int rt = 0; rt < 4; rt++) {
        __syncthreads();
#pragma unroll
        for (int ct = 0; ct < 9; ct++) {
            const int cm = ct * 16 + l15;
            const int c = cm / 9, m = cm - c * 9;
#pragma unroll
            for (int r = 0; r < 4; r++)
                ebp[(size_t)(w * 16 + quad * 4 + r) * 148 + m * 16 + c] = acc[rt][ct][r];
        }
        __syncthreads();
#pragma unroll
        for (int s = 0; s < 9; s++) {
            const int li = s * 16 + g4;            // 0..143 line index
            const int nl = li / 9, m = li - nl * 9;
            const float4 v4 = *(const float4*)&ebp[(size_t)(w * 16 + nl) * 148 + m * 16 + sub * 4];
            const int n = nbase + rt * 16 + nl;
            const float rzv = rZ[(size_t)n * 8 + h];
            half4v hv;
            hv[0] = (_Float16)(v4.x * rzv); hv[1] = (_Float16)(v4.y * rzv);
            hv[2] = (_Float16)(v4.z * rzv); hv[3] = (_Float16)(v4.w * rzv);
            *(half4v*)&dst[((size_t)n * 9 + m) * 128 + h * 16 + sub * 4] = hv;
        }
    }
}

// ================================ launcher =================================
extern "C" void kernel_launch(void* const* d_in, const int* in_sizes, int n_in,
                              void* d_out, int out_size, void* d_ws, size_t ws_size,
                              hipStream_t stream) {
    const float* pos  = (const float*)d_in[0];
    const float* feat = (const float*)d_in[1];
    const float* Wq   = (const float*)d_in[2];
    const float* Wk   = (const float*)d_in[3];
    const float* Wv   = (const float*)d_in[4];
    const float* Wo   = (const float*)d_in[5];
    const float* a    = (const float*)d_in[6];
    const float* kap  = (const float*)d_in[7];
    float* out = (float*)d_out;
    float* ws = (float*)d_ws;

    // float-slot layout (~77.8 MB total)
    float* qf    = ws;                    // 524288
    float* kfAF  = qf + 524288;           // 262144 slots = kfA f16[8][64][2][512]
    float* vTF   = kfAF + 262144;         // 1179648 slots = v16T f16[1152*2048]
    float* trigF = vTF + 1179648;         // 524288 slots = trigA f16[64][512][32]
    float* ksum  = trigF + 524288;        // 256
    float* rz    = ksum + 256;            // 16384
    float* G     = rz + 16384;            // 129600
    float* M16F  = G + 129600;            // 9437184 slots = M16 f16[512*8*4608]; later outp f16[8][2359296]
    float* regX  = M16F + 9437184;        // 7372800 slots: R (first 1572864), later MG f16[400*8*4608]
    float* R     = regX;
    _Float16* trigA = (_Float16*)trigF;
    _Float16* kfA   = (_Float16*)kfAF;
    _Float16* v16T  = (_Float16*)vTF;
    _Float16* M16   = (_Float16*)M16F;
    _Float16* MG16  = (_Float16*)regX;
    _Float16* outp16 = (_Float16*)M16F;   // overlay: M16 dead after fold_k; 8 f16 partial buffers

    const float* cst = d_const_g;

    hipLaunchKernelGGL(radial_k, dim3(2048), dim3(256), 0, stream, feat, R);
    hipLaunchKernelGGL(qk_gemm_k, dim3(8, 32), dim3(256), 0, stream, R, Wq, Wk, qf, kfA);
    hipLaunchKernelGGL(mfma_gemm16_k, dim3(2, 288), dim3(256), 0, stream, feat, Wv, vTF, 18432, 128, 256, 2, rz);
    hipLaunchKernelGGL(trig_k, dim3(2048), dim3(256), 0, stream, pos, kap, cst, trigA);
    hipLaunchKernelGGL(ksumT_k, dim3(256), dim3(256), 0, stream, kfA, ksum);
    hipLaunchKernelGGL(zg_k, dim3(128), dim3(256), 0, stream, qf, ksum, rz, a, cst, G);
    hipLaunchKernelGGL(multipole_mm_k, dim3(8, 9, 13), dim3(256), 0, stream, trigA, kfA, v16T, M16);
    hipLaunchKernelGGL(fold_k, dim3(400, 8), dim3(256), 0, stream, M16, G, MG16);
    hipLaunchKernelGGL(mm_local_k, dim3(8, 8, 8), dim3(256), 0, stream, qf, trigA, MG16, rz, outp16);
    hipLaunchKernelGGL(mfma_gemm16_k, dim3(4, 288), dim3(256), 0, stream, (const float*)outp16, Wo, out, 18432, 256, 1024, 4, rz);
}

// Round 7
// 324.944 us; speedup vs baseline: 1.0627x; 1.0627x over previous
//
#include <hip/hip_runtime.h>
#include <cmath>
#include <complex>
#include <algorithm>

// ---------------------------------------------------------------------------
// Problem constants: LMAX=2, NC=9, H=8, DQK=32, CV=16, K=8, U=25, N=2048, C=256
// ---------------------------------------------------------------------------

typedef _Float16 half8 __attribute__((ext_vector_type(8)));
typedef _Float16 half4v __attribute__((ext_vector_type(4)));
typedef float float4v __attribute__((ext_vector_type(4)));

// ========================= host-side constant tables ========================
namespace {

using cd = std::complex<double>;

static double fct(int n) { double r = 1.0; for (int i = 2; i <= n; ++i) r *= i; return r; }

static double cg_coef(int j1, int m1, int j2, int m2, int j, int m) {
    if (m1 + m2 != m || j < std::abs(j1 - j2) || j > j1 + j2) return 0.0;
    double pref = std::sqrt((2 * j + 1) * fct(j + j1 - j2) * fct(j - j1 + j2) * fct(j1 + j2 - j) / fct(j1 + j2 + j + 1));
    pref *= std::sqrt(fct(j + m) * fct(j - m) * fct(j1 - m1) * fct(j1 + m1) * fct(j2 - m2) * fct(j2 + m2));
    double s = 0.0;
    for (int k = 0; k <= j1 + j2 - j; ++k) {
        int d0 = k, d1 = j1 + j2 - j - k, d2 = j1 - m1 - k, d3 = j2 + m2 - k, d4 = j - j2 + m1 + k, d5 = j - j1 - m2 + k;
        if (d0 < 0 || d1 < 0 || d2 < 0 || d3 < 0 || d4 < 0 || d5 < 0) continue;
        s += ((k & 1) ? -1.0 : 1.0) / (fct(d0) * fct(d1) * fct(d2) * fct(d3) * fct(d4) * fct(d5));
    }
    return pref * s;
}

static void umat(int l, cd u[5][5]) {
    for (int i = 0; i < 5; i++) for (int j = 0; j < 5; j++) u[i][j] = cd(0, 0);
    const double s = 1.0 / std::sqrt(2.0);
    for (int m = -l; m <= l; m++) {
        double sgn = (std::abs(m) & 1) ? -1.0 : 1.0;   // (-1)^m
        if (m > 0)      { u[l + m][l + m] = cd(sgn * s, 0); u[l + m][l - m] = cd(s, 0); }
        else if (m == 0){ u[l][l] = cd(1, 0); }
        else            { u[l + m][l + m] = cd(0, s);       u[l + m][l - m] = cd(0, -sgn * s); }
    }
}

static void real_cg_f(int l1, int l2, int L, double out[5][5][5]) {
    cd U1[5][5], U2[5][5], UL[5][5];
    umat(l1, U1); umat(l2, U2); umat(L, UL);
    const int n1 = 2 * l1 + 1, n2 = 2 * l2 + 1, n3 = 2 * L + 1;
    double cgt[5][5][5];
    for (int i1 = 0; i1 < n1; i1++) for (int i2 = 0; i2 < n2; i2++) for (int i3 = 0; i3 < n3; i3++)
        cgt[i1][i2][i3] = cg_coef(l1, i1 - l1, l2, i2 - l2, L, i3 - L);
    cd r[5][5][5];
    double nr = 0, ni = 0;
    for (int a1 = 0; a1 < n1; a1++) for (int b = 0; b < n2; b++) for (int c = 0; c < n3; c++) {
        cd acc(0, 0);
        for (int uu = 0; uu < n1; uu++) for (int vv = 0; vv < n2; vv++) for (int w = 0; w < n3; w++) {
            double cval = cgt[uu][vv][w];
            if (cval == 0.0) continue;
            acc += U1[a1][uu] * U2[b][vv] * std::conj(UL[c][w]) * cval;
        }
        r[a1][b][c] = acc;
        nr += acc.real() * acc.real();
        ni += acc.imag() * acc.imag();
    }
    const bool useRe = std::sqrt(nr) >= std::sqrt(ni);
    for (int a1 = 0; a1 < n1; a1++) for (int b = 0; b < n2; b++) for (int c = 0; c < n3; c++)
        out[a1][b][c] = useRe ? r[a1][b][c].real() : r[a1][b][c].imag();
}

// device constant buffer layout: YW[9*25] | RRED[9*81] | DIRS[25*3]  = 1029 floats
static float  h_const[1029];
static float* d_const_g = nullptr;

struct GlobalInit {
    GlobalInit() {
        const double PI = 3.14159265358979323846;
        const double gx[5] = {-0.9061798459386640, -0.5384693101056831, 0.0, 0.5384693101056831, 0.9061798459386640};
        const double gw[5] = { 0.23692688505618908, 0.47862867049936647, 0.5688888888888889, 0.47862867049936647, 0.23692688505618908};
        double YW[9][25], DIRS[25][3];
        for (int u = 0; u < 25; ++u) {
            const int it = u / 5, ip = u % 5;
            const double ct = gx[it], wq = gw[it] * (2.0 * PI / 5.0), ph = 2.0 * PI * ip / 5.0;
            const double st = std::sqrt(std::max(1.0 - ct * ct, 0.0));
            const double x = st * std::cos(ph), y = st * std::sin(ph), z = ct;
            DIRS[u][0] = x; DIRS[u][1] = y; DIRS[u][2] = z;
            double Y[9];
            Y[0] = 0.282095;           Y[1] = 0.488603 * y;      Y[2] = 0.488603 * z;
            Y[3] = 0.488603 * x;       Y[4] = 1.092548 * x * y;  Y[5] = 1.092548 * y * z;
            Y[6] = 0.315392 * (3 * z * z - 1); Y[7] = 1.092548 * x * z; Y[8] = 0.546274 * (x * x - y * y);
            for (int e = 0; e < 9; e++) YW[e][u] = Y[e] * wq;
        }
        double RRED[9][9][9];
        for (int i = 0; i < 9; i++) for (int j = 0; j < 9; j++) for (int k = 0; k < 9; k++) RRED[i][j][k] = 0.0;
        const int off[3] = {0, 1, 4};
        double cnt[3] = {0, 0, 0};
        double rc[5][5][5];
        for (int l1 = 0; l1 <= 2; l1++) for (int l2 = 0; l2 <= 2; l2++) {
            const int Llo = std::abs(l1 - l2), Lhi = std::min(l1 + l2, 2);
            for (int L = Llo; L <= Lhi; L++) {
                real_cg_f(l1, l2, L, rc);
                for (int i1 = 0; i1 < 2 * l1 + 1; i1++)
                    for (int i2 = 0; i2 < 2 * l2 + 1; i2++)
                        for (int i3 = 0; i3 < 2 * L + 1; i3++)
                            RRED[off[l1] + i1][off[l2] + i2][off[L] + i3] += rc[i1][i2][i3];
                cnt[L] += 1.0;
            }
        }
        for (int L = 0; L <= 2; L++) {
            const double dv = std::max(cnt[L], 1.0);
            for (int a1 = 0; a1 < 9; a1++) for (int b = 0; b < 9; b++)
                for (int k = 0; k < 2 * L + 1; k++) RRED[a1][b][off[L] + k] /= dv;
        }
        for (int e = 0; e < 9; e++) for (int u = 0; u < 25; u++) h_const[e * 25 + u] = (float)YW[e][u];
        for (int e = 0; e < 9; e++) for (int l = 0; l < 9; l++) for (int m = 0; m < 9; m++)
            h_const[225 + e * 81 + l * 9 + m] = (float)RRED[e][l][m];
        for (int u = 0; u < 25; u++) for (int ax = 0; ax < 3; ax++) h_const[954 + u * 3 + ax] = (float)DIRS[u][ax];
        if (hipMalloc((void**)&d_const_g, 1029 * sizeof(float)) == hipSuccess)
            hipMemcpy(d_const_g, h_const, 1029 * sizeof(float), hipMemcpyHostToDevice);
    }
} g_init;

} // namespace

// ============================== device kernels ==============================

// R[n][p][c]: p=0 -> feat(l=0); p=1 -> |l=1 block|; p=2 -> |l=2 block|
__global__ void radial_k(const float* __restrict__ feat, float* __restrict__ R) {
    const int n = blockIdx.x, c = threadIdx.x;
    const float* f = feat + (size_t)n * 9 * 256 + c;
    const float f0 = f[0];
    const float a1 = f[256], a2 = f[512], a3 = f[768];
    const float b1 = f[1024], b2 = f[1280], b3 = f[1536], b4 = f[1792], b5 = f[2048];
    const float r1 = sqrtf(a1 * a1 + a2 * a2 + a3 * a3 + 1e-8f);
    const float r2 = sqrtf(b1 * b1 + b2 * b2 + b3 * b3 + b4 * b4 + b5 * b5 + 1e-8f);
    float* o = R + (size_t)n * 768 + c;
    o[0] = f0; o[256] = r1; o[512] = r2;
}

// fused Q/K projection GEMM (f16 MFMA): A = R (2048x768), B = Wq or Wk (768x256)
// grid (8, 32): x<4 -> Wq cols (cb=x*64), epilogue elu+1 -> qf row-major f32
//               x>=4 -> Wk cols (cb=(x-4)*64), epilogue elu+1 -> kfA frag f16
__global__ __launch_bounds__(256) void qk_gemm_k(const float* __restrict__ A,
                                                 const float* __restrict__ Wq,
                                                 const float* __restrict__ Wk,
                                                 float* __restrict__ qf,
                                                 _Float16* __restrict__ kfA) {
    __shared__ __align__(16) _Float16 Af[64 * 40];
    __shared__ __align__(16) _Float16 Bf[64 * 40];
    const int tid = threadIdx.x;
    const int w = tid >> 6, lane = tid & 63;
    const int l15 = lane & 15, quad = lane >> 4;
    const bool isK = blockIdx.x >= 4;
    const int cb = (blockIdx.x & 3) * 64;
    const int rb = blockIdx.y * 64;
    const float* B = isK ? Wk : Wq;
    const int N = 256, Kd = 768;
    const int sr = tid >> 2, sq = tid & 3;

    float4v acc[4];
#pragma unroll
    for (int s = 0; s < 4; s++) acc[s] = float4v{0.f, 0.f, 0.f, 0.f};

    for (int k0 = 0; k0 < Kd; k0 += 32) {
        __syncthreads();
        {
            const float* Ap = A + (size_t)(rb + sr) * Kd + k0 + sq * 8;
            const float4 a0 = *(const float4*)(Ap);
            const float4 a1 = *(const float4*)(Ap + 4);
            half8 hv;
            hv[0] = (_Float16)a0.x; hv[1] = (_Float16)a0.y; hv[2] = (_Float16)a0.z; hv[3] = (_Float16)a0.w;
            hv[4] = (_Float16)a1.x; hv[5] = (_Float16)a1.y; hv[6] = (_Float16)a1.z; hv[7] = (_Float16)a1.w;
            *(half8*)&Af[sr * 40 + sq * 8] = hv;
        }
        {
            const float* Bp = B + (size_t)(k0 + sq * 8) * N + cb + sr;
            half8 hv;
#pragma unroll
            for (int i = 0; i < 8; i++) hv[i] = (_Float16)Bp[(size_t)i * N];
            *(half8*)&Bf[sr * 40 + sq * 8] = hv;
        }
        __syncthreads();
        const half8 af = *(const half8*)&Af[(w * 16 + l15) * 40 + quad * 8];
#pragma unroll
        for (int s = 0; s < 4; s++) {
            const half8 bf = *(const half8*)&Bf[(s * 16 + l15) * 40 + quad * 8];
            acc[s] = __builtin_amdgcn_mfma_f32_16x16x32_f16(af, bf, acc[s], 0, 0, 0);
        }
    }
#pragma unroll
    for (int s = 0; s < 4; s++) {
#pragma unroll
        for (int r = 0; r < 4; r++) {
            const int row = rb + w * 16 + quad * 4 + r;
            const int col = cb + s * 16 + l15;
            float val = acc[s][r];
            val = (val > 0.f ? val : expf(val) - 1.f) + 1.f;
            if (isK) {
                const int hh = col >> 5, dd = col & 31, tt = dd >> 4, ll = dd & 15;
                kfA[(size_t)hh * 65536 + (size_t)(row >> 5) * 1024 + tt * 512 + ll * 32 + (row & 31)] = (_Float16)val;
            } else {
                qf[(size_t)row * 256 + col] = val;
            }
        }
    }
}

// f16 MFMA GEMM, C = A(MxK) @ B(KxN), M%64==0, N%64==0, K%32==0.
// mode 2: A f32, v16T f16 scatter
// mode 4 (R20: back to R16's proven form): A = sum of 4 f16 partial buffers
//   (stride 2359296 halves), summed in f32 in stage-A. rz already applied in
//   mm_local's epilogue. Plain f32 C row-major. (R17's 8-stream gather was
//   +17us; R19's extended-K was +30us vs this.)
__global__ __launch_bounds__(256) void mfma_gemm16_k(const float* __restrict__ A, const float* __restrict__ B,
                                                     float* __restrict__ Cv, int M, int N, int Kd, int mode,
                                                     const float* __restrict__ rZ) {
    __shared__ __align__(16) _Float16 Af[64 * 40];   // [row][k], stride 40 halves (80 B)
    __shared__ __align__(16) _Float16 Bf[64 * 40];   // [col][k]
    const int tid = threadIdx.x;
    const int w = tid >> 6, lane = tid & 63;
    const int l15 = lane & 15, quad = lane >> 4;
    const int rb = blockIdx.y * 64, cb = blockIdx.x * 64;
    const int sr = tid >> 2, sq = tid & 3;           // stager: row/col 0..63, k-quartet 0..3

    float4v acc[4];
#pragma unroll
    for (int s = 0; s < 4; s++) acc[s] = float4v{0.f, 0.f, 0.f, 0.f};

    for (int k0 = 0; k0 < Kd; k0 += 32) {
        __syncthreads();
        // ---- stage A (-> f16, fragment order) ----
        if (mode == 4) {
            const _Float16* Ap16 = (const _Float16*)A + (size_t)(rb + sr) * Kd + k0 + sq * 8;
            const half8 p0 = *(const half8*)(Ap16);
            const half8 p1 = *(const half8*)(Ap16 + 2359296);
            const half8 p2 = *(const half8*)(Ap16 + 4718592);
            const half8 p3 = *(const half8*)(Ap16 + 7077888);
            half8 hv;
#pragma unroll
            for (int i = 0; i < 8; i++)
                hv[i] = (_Float16)((float)p0[i] + (float)p1[i] + (float)p2[i] + (float)p3[i]);
            *(half8*)&Af[sr * 40 + sq * 8] = hv;
        } else {
            const float* Ap = A + (size_t)(rb + sr) * Kd + k0 + sq * 8;
            const float4 a0 = *(const float4*)(Ap);
            const float4 a1 = *(const float4*)(Ap + 4);
            half8 hv;
            hv[0] = (_Float16)a0.x; hv[1] = (_Float16)a0.y; hv[2] = (_Float16)a0.z; hv[3] = (_Float16)a0.w;
            hv[4] = (_Float16)a1.x; hv[5] = (_Float16)a1.y; hv[6] = (_Float16)a1.z; hv[7] = (_Float16)a1.w;
            *(half8*)&Af[sr * 40 + sq * 8] = hv;
        }
        // ---- stage B (column gather; f32 -> f16) ----
        {
            const float* Bp = B + (size_t)(k0 + sq * 8) * N + cb + sr;
            half8 hv;
#pragma unroll
            for (int i = 0; i < 8; i++) hv[i] = (_Float16)Bp[(size_t)i * N];
            *(half8*)&Bf[sr * 40 + sq * 8] = hv;
        }
        __syncthreads();
        // ---- fragments + MFMA ----
        const half8 af = *(const half8*)&Af[(w * 16 + l15) * 40 + quad * 8];
#pragma unroll
        for (int s = 0; s < 4; s++) {
            const half8 bf = *(const half8*)&Bf[(s * 16 + l15) * 40 + quad * 8];
            acc[s] = __builtin_amdgcn_mfma_f32_16x16x32_f16(af, bf, acc[s], 0, 0, 0);
        }
    }
    // ---- epilogue: C fragment (row = rb+w*16+quad*4+r, col = cb+s*16+l15) ----
#pragma unroll
    for (int s = 0; s < 4; s++) {
#pragma unroll
        for (int r = 0; r < 4; r++) {
            const int row = rb + w * 16 + quad * 4 + r;
            const int col = cb + s * 16 + l15;
            float val = acc[s][r];
            if (mode == 2) {
                // v16T[(h*144 + c*9 + l)][n] f16
                const int n = row / 9, l = row - n * 9, hq = col >> 4, cvq = col & 15;
                _Float16* o = (_Float16*)Cv;
                o[((size_t)hq * 144 + cvq * 9 + l) * 2048 + n] = (_Float16)val;
            } else {
                Cv[(size_t)row * N + col] = val;
            }
        }
    }
}

// trigA[nb5][kkut][j] (f16, fragment-ordered) = cos/sin(kappa_kk * pos_n . dir_u)
//   kkut = (kk*25+u)*2+t (rows, padded to 512), nb5 = n>>5, j = n&31
// threads 200..255 zero the pad rows 400..511 for this n's j-slot (replaces memset)
__global__ void trig_k(const float* __restrict__ pos, const float* __restrict__ kappa,
                       const float* __restrict__ cst, _Float16* __restrict__ trigA) {
    const int n = blockIdx.x, t = threadIdx.x;
    const size_t base = (size_t)(n >> 5) * 16384 + (n & 31);
    if (t < 200) {
        const int kq = t / 25, u = t - kq * 25;
        const float* dirs = cst + 954;
        const float ph = kappa[kq] * (pos[n * 3] * dirs[u * 3] + pos[n * 3 + 1] * dirs[u * 3 + 1] + pos[n * 3 + 2] * dirs[u * 3 + 2]);
        float s, c;
        sincosf(ph, &s, &c);
        const int kkut = (kq * 25 + u) * 2;
        trigA[base + (size_t)kkut * 32] = (_Float16)c;
        trigA[base + (size_t)(kkut + 1) * 32] = (_Float16)s;
    } else {
        const int kkut = 400 + (t - 200) * 2;
        trigA[base + (size_t)kkut * 32] = (_Float16)0.f;
        trigA[base + (size_t)(kkut + 1) * 32] = (_Float16)0.f;
    }
}

// ksum[h*32+d] = sum_n kfA[h][nb5][t][l15][j]; one block per (h,d)
__global__ void ksumT_k(const _Float16* __restrict__ kfA, float* __restrict__ ksum) {
    const int b = blockIdx.x;                       // h*32+d
    const int h = b >> 5, d = b & 31, t = d >> 4, l15 = d & 15;
    const int i = threadIdx.x;                      // 256
    const half8 v = *(const half8*)(kfA + (size_t)h * 65536 + (size_t)(i >> 2) * 1024 + t * 512 + l15 * 32 + (i & 3) * 8);
    float s = 0.f;
#pragma unroll
    for (int k = 0; k < 8; k++) s += (float)v[k];
#pragma unroll
    for (int off = 32; off > 0; off >>= 1) s += __shfl_down(s, off, 64);
    __shared__ float red[4];
    if ((i & 63) == 0) red[i >> 6] = s;
    __syncthreads();
    if (i == 0) ksum[b] = red[0] + red[1] + red[2] + red[3];
}

// merged z + g (block-range dispatch, 128 blocks):
//   blocks 0..63:  rz[n][h] = 1 / (qf[n,h,:].ksum[h,:] + 1e-6)
//   blocks 64..127: G[kk][h][u][l*9+m] = sum_e aE[e,h,kk]*YW[e,u]*RRED[e,l,m]
__global__ void zg_k(const float* __restrict__ qf, const float* __restrict__ ksum, float* __restrict__ rz,
                     const float* __restrict__ a, const float* __restrict__ cst, float* __restrict__ G) {
    if (blockIdx.x < 64) {
        const int idx = blockIdx.x * 256 + threadIdx.x;   // N*H = 16384
        const int n = idx >> 3, h = idx & 7;
        float s = 0.f;
#pragma unroll
        for (int d = 0; d < 32; d++) s += qf[(size_t)n * 256 + h * 32 + d] * ksum[h * 32 + d];
        rz[idx] = 1.0f / (s + 1e-6f);
    } else {
        const int b = blockIdx.x - 64;
        const int kk = b & 7, h = b >> 3;
        __shared__ float ae[9];
        if (threadIdx.x < 9) {
            const int ldeg[9] = {0, 1, 1, 1, 2, 2, 2, 2, 2};
            ae[threadIdx.x] = a[ldeg[threadIdx.x] * 64 + h * 8 + kk];
        }
        __syncthreads();
        const float* yw = cst;
        const float* rred = cst + 225;
        for (int i = threadIdx.x; i < 25 * 81; i += 256) {
            const int u = i / 81, lm = i - u * 81;
            float s = 0.f;
#pragma unroll
            for (int e = 0; e < 9; e++) s += ae[e] * yw[e * 25 + u] * rred[e * 81 + lm];
            G[((size_t)(kk * 8 + h) * 25 + u) * 81 + lm] = s;
        }
    }
}

// MFMA multipole (R14: LDS operand sharing):
//   M16[kkut][h][cl*32+d] = sum_n trigA * kfA * v16T
// R13 post-mortem: af/kq loads are identical across the block's 4 waves; each
// wave privately pulled ~8KB/step through the CU's L1->RF return path
// (~64B/cyc) -> return-path bound at ~20% MfmaUtil regardless of pipelining.
// R14: per round of 4 steps (128 n), each wave gathers 5x16B/lane (its step's
// af0/af1/kq0/kq1 + its own vq slab) and ds_writes them fragment-ordered into
// a double-buffered LDS image. Compute reads af/kq lane-linear (conflict-free)
// and vq via quad-broadcast (LDS broadcast is free). Global bytes/block drop
// 4x for af/kq; fan-out moves to the wider LDS path. One barrier per round.
// grid (8 h, 9 colgroups, 13 rowpairs), 256 thr; gridDim.x==8 keeps h->XCD
// affinity (R12). __launch_bounds__(256,3): 3 blocks/CU (LDS 40KB, regs<=170).
__global__ __launch_bounds__(256, 3) void multipole_mm_k(const _Float16* __restrict__ trigA,
                                                         const _Float16* __restrict__ kfA,
                                                         const _Float16* __restrict__ v16T,
                                                         _Float16* __restrict__ M16) {
    const int h   = blockIdx.x;
    const int tid = threadIdx.x;
    const int w = tid >> 6, lane = tid & 63;
    const int l15 = lane & 15, quad = lane >> 4;
    const int cb  = blockIdx.y * 512 + w * 128;   // 4 cl per wave -> 128 cols
    const int cl0 = cb >> 5;
    const int r0  = blockIdx.z * 32;              // rows (kkut), 13*32 = 416

    // LDS: [buf][unit][512 halves]; unit s*4+{0:af0,1:af1,2:kq0,3:kq1} for step
    // s=0..3 of the round, unit 16+w = wave-private vq slab (4 steps x 4 c x 32 n).
    __shared__ __align__(16) _Float16 sb[2][20][512];   // 40 KB

    float4v acc[2][8];
#pragma unroll
    for (int rt = 0; rt < 2; rt++)
#pragma unroll
        for (int s = 0; s < 8; s++) acc[rt][s] = float4v{0.f, 0.f, 0.f, 0.f};

    // gather bases: this wave stages step s==w of each round (nb = nbr + w*32)
    const _Float16* afg0 = trigA + (size_t)(r0 + l15) * 32 + quad * 8;            // + nb5*16384
    const _Float16* afg1 = afg0 + 512;                                            // rows +16
    const _Float16* kqg0 = kfA + (size_t)h * 65536 + (size_t)l15 * 32 + quad * 8; // + nb5*1024
    const _Float16* kqg1 = kqg0 + 512;
    const int vs = lane >> 4, vc = (lane >> 2) & 3, vg = lane & 3;                // vq gather decomp
    const _Float16* vqg = v16T + (size_t)(h * 144 + cl0 + vc) * 2048 + vs * 32 + vg * 8; // + nbr

    half8 g0, g1, g2, g3, g4;

#define GATHER(nbr_) { \
        const size_t t5 = (size_t)((nbr_) >> 5) + w; \
        g0 = *(const half8*)(afg0 + t5 * 16384); \
        g1 = *(const half8*)(afg1 + t5 * 16384); \
        g2 = *(const half8*)(kqg0 + t5 * 1024); \
        g3 = *(const half8*)(kqg1 + t5 * 1024); \
        g4 = *(const half8*)(vqg + (nbr_)); }

#define DSWRITE(b_) { \
        *(half8*)&sb[b_][w * 4 + 0][lane * 8] = g0; \
        *(half8*)&sb[b_][w * 4 + 1][lane * 8] = g1; \
        *(half8*)&sb[b_][w * 4 + 2][lane * 8] = g2; \
        *(half8*)&sb[b_][w * 4 + 3][lane * 8] = g3; \
        *(half8*)&sb[b_][16 + w][lane * 8] = g4; }

#define STEP(s_) { \
        const half8 af0 = *(const half8*)&sb[cur][(s_) * 4 + 0][lane * 8]; \
        const half8 af1 = *(const half8*)&sb[cur][(s_) * 4 + 1][lane * 8]; \
        const half8 kq0 = *(const half8*)&sb[cur][(s_) * 4 + 2][lane * 8]; \
        const half8 kq1 = *(const half8*)&sb[cur][(s_) * 4 + 3][lane * 8]; \
        _Pragma("unroll") \
        for (int c = 0; c < 4; c++) { \
            const half8 vq = *(const half8*)&sb[cur][16 + w][((s_) * 4 + c) * 32 + quad * 8]; \
            const half8 b0 = kq0 * vq; \
            const half8 b1 = kq1 * vq; \
            acc[0][2 * c]     = __builtin_amdgcn_mfma_f32_16x16x32_f16(af0, b0, acc[0][2 * c],     0, 0, 0); \
            acc[0][2 * c + 1] = __builtin_amdgcn_mfma_f32_16x16x32_f16(af0, b1, acc[0][2 * c + 1], 0, 0, 0); \
            acc[1][2 * c]     = __builtin_amdgcn_mfma_f32_16x16x32_f16(af1, b0, acc[1][2 * c],     0, 0, 0); \
            acc[1][2 * c + 1] = __builtin_amdgcn_mfma_f32_16x16x32_f16(af1, b1, acc[1][2 * c + 1], 0, 0, 0); \
        } }

    int cur = 0;
    GATHER(0)
    DSWRITE(0)
    __syncthreads();
#pragma unroll 1
    for (int r = 0; r < 16; ++r) {
        if (r < 15) GATHER((r + 1) * 128)
        STEP(0)
        STEP(1)
        STEP(2)
        STEP(3)
        if (r < 15) DSWRITE(cur ^ 1)
        __syncthreads();
        cur ^= 1;
    }

#undef GATHER
#undef DSWRITE
#undef STEP

    // epilogue: C fragment -> M16[kkut][h][col]
#pragma unroll
    for (int rt = 0; rt < 2; rt++)
#pragma unroll
        for (int c = 0; c < 4; c++)
#pragma unroll
            for (int half = 0; half < 2; half++)
#pragma unroll
                for (int r = 0; r < 4; r++) {
                    const int row = r0 + rt * 16 + quad * 4 + r;
                    const int col = cb + c * 32 + half * 16 + l15;
                    M16[((size_t)row * 8 + h) * 4608 + col] = (_Float16)acc[rt][c * 2 + half][r];
                }
}

// MG[kt][h][ct*512 + quad*128 + l15*8 + j] (f16, fragment-ordered)
//   = sum_l M16[kt][h][(c*9+l)*32+d] * G[kk,h,u][l*9+m], cm=ct*16+l15, d=quad*8+j
__global__ __launch_bounds__(256) void fold_k(const _Float16* __restrict__ Mv, const float* __restrict__ G,
                                              _Float16* __restrict__ MG) {
    const int kt = blockIdx.x, h = blockIdx.y;
    const int tid = threadIdx.x;
    __shared__ float ms[144 * 33];   // [cl][d] padded 33
    __shared__ float gs[81];
    const _Float16* src = Mv + ((size_t)kt * 8 + h) * 4608;
    for (int i = tid; i < 4608; i += 256) {
        const int cl = i >> 5, d = i & 31;
        ms[cl * 33 + d] = (float)src[i];
    }
    const int kk = kt / 50, u = (kt >> 1) % 25;
    if (tid < 81) gs[tid] = G[(((size_t)kk * 8 + h) * 25 + u) * 81 + tid];
    __syncthreads();
    _Float16* dst = MG + ((size_t)kt * 8 + h) * 4608;
    for (int i = tid; i < 4608; i += 256) {
        const int ct = i >> 9, quad = (i >> 7) & 3, l15 = (i >> 3) & 15, j = i & 7;
        const int d = quad * 8 + j;
        const int cm = ct * 16 + l15, c = cm / 9, m = cm - c * 9;
        float s = 0.f;
#pragma unroll
        for (int l = 0; l < 9; l++) s += ms[(c * 9 + l) * 33 + d] * gs[l * 9 + m];
        dst[i] = (_Float16)s;
    }
}

// local stage via MFMA (R20: consolidate to measured best-of-each):
// Ledger: R15 (32 rows/wave, 4 slices x 100kt, 2 blk/CU, 4-kt rounds) had the
// best mm_local (~64us) AND produces only 4 partials -> cheapest out-GEMM
// (R16's rest=244us). R16's 64 rows/wave raised MfmaUtil but 1 blk/CU
// exposed latency (75.7); R17/R19's 8 slices made the out-GEMM pay more than
// mm_local saved. R20 = R15 geometry + f16 partial writes (halves WRITE) +
// rz applied here in f32 before the single f16 rounding (absmax 7.6e-6).
// grid (8, 4, 16) = 512 blocks = 2/CU; LDS 73.7KB dbuf; combo=y*8+x ->
// h=combo>>2, slice=combo&3; linear%8=x keeps per-XCD MG set 3.7MB < 4MB L2.
__global__ __launch_bounds__(256, 2) void mm_local_k(const float* __restrict__ qf, const _Float16* __restrict__ trigA,
                                                     const _Float16* __restrict__ MG, const float* __restrict__ rZ,
                                                     _Float16* __restrict__ outp) {
    const int combo = blockIdx.y * 8 + blockIdx.x;
    const int h = combo >> 2;
    const int slice = combo & 3;
    const int n0 = blockIdx.z * 128;
    const int tid = threadIdx.x;
    const int w = tid >> 6, lane = tid & 63;
    const int l15 = lane & 15, quad = lane >> 4;

    // staging sb[2][4][4608] f16 (73728B), overlaid later by epilogue eb (37888B)
    __shared__ __align__(16) unsigned char smem_raw[73728];
    _Float16 (*sb)[4][4608] = (_Float16 (*)[4][4608])smem_raw;

    const int nbase = n0 + w * 32;                      // 32 rows per wave
    half8 qfr16[2];
#pragma unroll
    for (int rt = 0; rt < 2; rt++) {
        const int n = nbase + rt * 16 + l15;
        const float* qp = qf + (size_t)n * 256 + h * 32 + quad * 8;
#pragma unroll
        for (int j = 0; j < 8; j++) qfr16[rt][j] = (_Float16)qp[j];
    }
    float4v acc[2][9];
#pragma unroll
    for (int rt = 0; rt < 2; rt++)
#pragma unroll
        for (int ct = 0; ct < 9; ct++) acc[rt][ct] = float4v{0.f, 0.f, 0.f, 0.f};

    const int kt0 = slice * 100;
    // per-lane staging source: lane*8 halves = quad*128 + l15*8 (the read offset)
    const _Float16* mg0 = MG + (((size_t)kt0 * 8 + h) * 4608) + lane * 8;
    // trig scalars: trigA[nb5][kt][rt*16+l15] (all 32 rows in slab nbase>>5)
    const _Float16* trg0 = trigA + (size_t)(nbase >> 5) * 16384 + (size_t)kt0 * 32 + l15;

    // wave w stages kt = base_ + w of this round: 9 x global_load_lds_dwordx4
#define STAGE4(b_, base_) { \
        const _Float16* src = mg0 + (size_t)((base_) + w) * 8 * 4608; \
        _Float16* dstl = &sb[b_][w][0]; \
        _Pragma("unroll") \
        for (int i = 0; i < 9; i++) \
            __builtin_amdgcn_global_load_lds( \
                (const __attribute__((address_space(1))) void*)(src + i * 512), \
                (__attribute__((address_space(3))) void*)(dstl + i * 512), 16, 0, 0); }

#define COMPUTE(kl) { \
        half8 tv0, tv1; \
        _Pragma("unroll") \
        for (int j = 0; j < 8; j++) { tv0[j] = ta[kl]; tv1[j] = tb[kl]; } \
        const half8 af0 = tv0 * qfr16[0]; \
        const half8 af1 = tv1 * qfr16[1]; \
        _Pragma("unroll") \
        for (int ct = 0; ct < 9; ct++) { \
            const half8 b = *(const half8*)&sb[cur][kl][ct * 512 + quad * 128 + l15 * 8]; \
            acc[0][ct] = __builtin_amdgcn_mfma_f32_16x16x32_f16(af0, b, acc[0][ct], 0, 0, 0); \
            acc[1][ct] = __builtin_amdgcn_mfma_f32_16x16x32_f16(af1, b, acc[1][ct], 0, 0, 0); \
        } }

    _Float16 ta[4], tb[4], ua[4], ub[4];
    int cur = 0;
    STAGE4(0, 0)
#pragma unroll
    for (int kl = 0; kl < 4; kl++) { ta[kl] = trg0[kl * 32]; tb[kl] = trg0[kl * 32 + 16]; }
    __syncthreads();

#pragma unroll 1
    for (int r = 0; r < 25; ++r) {
        if (r < 24) {
            STAGE4(cur ^ 1, (r + 1) * 4)
#pragma unroll
            for (int kl = 0; kl < 4; kl++) {
                const size_t o = (size_t)((r + 1) * 4 + kl) * 32;
                ua[kl] = trg0[o]; ub[kl] = trg0[o + 16];
            }
        }
        COMPUTE(0) COMPUTE(1) COMPUTE(2) COMPUTE(3)
        __syncthreads();
        cur ^= 1;
#pragma unroll
        for (int kl = 0; kl < 4; kl++) { ta[kl] = ua[kl]; tb[kl] = ub[kl]; }
    }

#undef STAGE4
#undef COMPUTE

    // epilogue: LDS transpose -> coalesced f16 stores into outp[slice][n][m][h*16+c]
    // rz[n][h] applied here (f32, before the single f16 rounding).
    // eb overlaid on sb (dead; 37888B <= 73728B)
    float* ebp = (float*)smem_raw;
    _Float16* dst = outp + (size_t)slice * 2359296;
    const int g4 = lane >> 2, sub = lane & 3;
#pragma unroll
    for (int rt = 0; rt < 2; rt++) {
        __syncthreads();
#pragma unroll
        for (int ct = 0; ct < 9; ct++) {
            const int cm = ct * 16 + l15;
            const int c = cm / 9, m = cm - c * 9;
#pragma unroll
            for (int r = 0; r < 4; r++)
                ebp[(size_t)(w * 16 + quad * 4 + r) * 148 + m * 16 + c] = acc[rt][ct][r];
        }
        __syncthreads();
#pragma unroll
        for (int s = 0; s < 9; s++) {
            const int li = s * 16 + g4;            // 0..143 line index
            const int nl = li / 9, m = li - nl * 9;
            const float4 v4 = *(const float4*)&ebp[(size_t)(w * 16 + nl) * 148 + m * 16 + sub * 4];
            const int n = nbase + rt * 16 + nl;
            const float rzv = rZ[(size_t)n * 8 + h];
            half4v hv;
            hv[0] = (_Float16)(v4.x * rzv); hv[1] = (_Float16)(v4.y * rzv);
            hv[2] = (_Float16)(v4.z * rzv); hv[3] = (_Float16)(v4.w * rzv);
            *(half4v*)&dst[((size_t)n * 9 + m) * 128 + h * 16 + sub * 4] = hv;
        }
    }
}

// ================================ launcher =================================
extern "C" void kernel_launch(void* const* d_in, const int* in_sizes, int n_in,
                              void* d_out, int out_size, void* d_ws, size_t ws_size,
                              hipStream_t stream) {
    const float* pos  = (const float*)d_in[0];
    const float* feat = (const float*)d_in[1];
    const float* Wq   = (const float*)d_in[2];
    const float* Wk   = (const float*)d_in[3];
    const float* Wv   = (const float*)d_in[4];
    const float* Wo   = (const float*)d_in[5];
    const float* a    = (const float*)d_in[6];
    const float* kap  = (const float*)d_in[7];
    float* out = (float*)d_out;
    float* ws = (float*)d_ws;

    // float-slot layout (~77.8 MB total)
    float* qf    = ws;                    // 524288
    float* kfAF  = qf + 524288;           // 262144 slots = kfA f16[8][64][2][512]
    float* vTF   = kfAF + 262144;         // 1179648 slots = v16T f16[1152*2048]
    float* trigF = vTF + 1179648;         // 524288 slots = trigA f16[64][512][32]
    float* ksum  = trigF + 524288;        // 256
    float* rz    = ksum + 256;            // 16384
    float* G     = rz + 16384;            // 129600
    float* M16F  = G + 129600;            // 9437184 slots = M16 f16[512*8*4608]; later outp f16[4][2359296]
    float* regX  = M16F + 9437184;        // 7372800 slots: R (first 1572864), later MG f16[400*8*4608]
    float* R     = regX;
    _Float16* trigA = (_Float16*)trigF;
    _Float16* kfA   = (_Float16*)kfAF;
    _Float16* v16T  = (_Float16*)vTF;
    _Float16* M16   = (_Float16*)M16F;
    _Float16* MG16  = (_Float16*)regX;
    _Float16* outp16 = (_Float16*)M16F;   // overlay: M16 dead after fold_k; 4 f16 partial buffers

    const float* cst = d_const_g;

    hipLaunchKernelGGL(radial_k, dim3(2048), dim3(256), 0, stream, feat, R);
    hipLaunchKernelGGL(qk_gemm_k, dim3(8, 32), dim3(256), 0, stream, R, Wq, Wk, qf, kfA);
    hipLaunchKernelGGL(mfma_gemm16_k, dim3(2, 288), dim3(256), 0, stream, feat, Wv, vTF, 18432, 128, 256, 2, rz);
    hipLaunchKernelGGL(trig_k, dim3(2048), dim3(256), 0, stream, pos, kap, cst, trigA);
    hipLaunchKernelGGL(ksumT_k, dim3(256), dim3(256), 0, stream, kfA, ksum);
    hipLaunchKernelGGL(zg_k, dim3(128), dim3(256), 0, stream, qf, ksum, rz, a, cst, G);
    hipLaunchKernelGGL(multipole_mm_k, dim3(8, 9, 13), dim3(256), 0, stream, trigA, kfA, v16T, M16);
    hipLaunchKernelGGL(fold_k, dim3(400, 8), dim3(256), 0, stream, M16, G, MG16);
    hipLaunchKernelGGL(mm_local_k, dim3(8, 4, 16), dim3(256), 0, stream, qf, trigA, MG16, rz, outp16);
    hipLaunchKernelGGL(mfma_gemm16_k, dim3(4, 288), dim3(256), 0, stream, (const float*)outp16, Wo, out, 18432, 256, 128, 4, rz);
}

// Round 8
// 299.780 us; speedup vs baseline: 1.1519x; 1.0839x over previous
//
#include <hip/hip_runtime.h>
#include <cmath>
#include <complex>
#include <algorithm>

// ---------------------------------------------------------------------------
// Problem constants: LMAX=2, NC=9, H=8, DQK=32, CV=16, K=8, U=25, N=2048, C=256
// ---------------------------------------------------------------------------

typedef _Float16 half8 __attribute__((ext_vector_type(8)));
typedef _Float16 half4v __attribute__((ext_vector_type(4)));
typedef float float4v __attribute__((ext_vector_type(4)));

// ========================= host-side constant tables ========================
namespace {

using cd = std::complex<double>;

static double fct(int n) { double r = 1.0; for (int i = 2; i <= n; ++i) r *= i; return r; }

static double cg_coef(int j1, int m1, int j2, int m2, int j, int m) {
    if (m1 + m2 != m || j < std::abs(j1 - j2) || j > j1 + j2) return 0.0;
    double pref = std::sqrt((2 * j + 1) * fct(j + j1 - j2) * fct(j - j1 + j2) * fct(j1 + j2 - j) / fct(j1 + j2 + j + 1));
    pref *= std::sqrt(fct(j + m) * fct(j - m) * fct(j1 - m1) * fct(j1 + m1) * fct(j2 - m2) * fct(j2 + m2));
    double s = 0.0;
    for (int k = 0; k <= j1 + j2 - j; ++k) {
        int d0 = k, d1 = j1 + j2 - j - k, d2 = j1 - m1 - k, d3 = j2 + m2 - k, d4 = j - j2 + m1 + k, d5 = j - j1 - m2 + k;
        if (d0 < 0 || d1 < 0 || d2 < 0 || d3 < 0 || d4 < 0 || d5 < 0) continue;
        s += ((k & 1) ? -1.0 : 1.0) / (fct(d0) * fct(d1) * fct(d2) * fct(d3) * fct(d4) * fct(d5));
    }
    return pref * s;
}

static void umat(int l, cd u[5][5]) {
    for (int i = 0; i < 5; i++) for (int j = 0; j < 5; j++) u[i][j] = cd(0, 0);
    const double s = 1.0 / std::sqrt(2.0);
    for (int m = -l; m <= l; m++) {
        double sgn = (std::abs(m) & 1) ? -1.0 : 1.0;   // (-1)^m
        if (m > 0)      { u[l + m][l + m] = cd(sgn * s, 0); u[l + m][l - m] = cd(s, 0); }
        else if (m == 0){ u[l][l] = cd(1, 0); }
        else            { u[l + m][l + m] = cd(0, s);       u[l + m][l - m] = cd(0, -sgn * s); }
    }
}

static void real_cg_f(int l1, int l2, int L, double out[5][5][5]) {
    cd U1[5][5], U2[5][5], UL[5][5];
    umat(l1, U1); umat(l2, U2); umat(L, UL);
    const int n1 = 2 * l1 + 1, n2 = 2 * l2 + 1, n3 = 2 * L + 1;
    double cgt[5][5][5];
    for (int i1 = 0; i1 < n1; i1++) for (int i2 = 0; i2 < n2; i2++) for (int i3 = 0; i3 < n3; i3++)
        cgt[i1][i2][i3] = cg_coef(l1, i1 - l1, l2, i2 - l2, L, i3 - L);
    cd r[5][5][5];
    double nr = 0, ni = 0;
    for (int a1 = 0; a1 < n1; a1++) for (int b = 0; b < n2; b++) for (int c = 0; c < n3; c++) {
        cd acc(0, 0);
        for (int uu = 0; uu < n1; uu++) for (int vv = 0; vv < n2; vv++) for (int w = 0; w < n3; w++) {
            double cval = cgt[uu][vv][w];
            if (cval == 0.0) continue;
            acc += U1[a1][uu] * U2[b][vv] * std::conj(UL[c][w]) * cval;
        }
        r[a1][b][c] = acc;
        nr += acc.real() * acc.real();
        ni += acc.imag() * acc.imag();
    }
    const bool useRe = std::sqrt(nr) >= std::sqrt(ni);
    for (int a1 = 0; a1 < n1; a1++) for (int b = 0; b < n2; b++) for (int c = 0; c < n3; c++)
        out[a1][b][c] = useRe ? r[a1][b][c].real() : r[a1][b][c].imag();
}

// device constant buffer layout: YW[9*25] | RRED[9*81] | DIRS[25*3]  = 1029 floats
static float  h_const[1029];
static float* d_const_g = nullptr;

struct GlobalInit {
    GlobalInit() {
        const double PI = 3.14159265358979323846;
        const double gx[5] = {-0.9061798459386640, -0.5384693101056831, 0.0, 0.5384693101056831, 0.9061798459386640};
        const double gw[5] = { 0.23692688505618908, 0.47862867049936647, 0.5688888888888889, 0.47862867049936647, 0.23692688505618908};
        double YW[9][25], DIRS[25][3];
        for (int u = 0; u < 25; ++u) {
            const int it = u / 5, ip = u % 5;
            const double ct = gx[it], wq = gw[it] * (2.0 * PI / 5.0), ph = 2.0 * PI * ip / 5.0;
            const double st = std::sqrt(std::max(1.0 - ct * ct, 0.0));
            const double x = st * std::cos(ph), y = st * std::sin(ph), z = ct;
            DIRS[u][0] = x; DIRS[u][1] = y; DIRS[u][2] = z;
            double Y[9];
            Y[0] = 0.282095;           Y[1] = 0.488603 * y;      Y[2] = 0.488603 * z;
            Y[3] = 0.488603 * x;       Y[4] = 1.092548 * x * y;  Y[5] = 1.092548 * y * z;
            Y[6] = 0.315392 * (3 * z * z - 1); Y[7] = 1.092548 * x * z; Y[8] = 0.546274 * (x * x - y * y);
            for (int e = 0; e < 9; e++) YW[e][u] = Y[e] * wq;
        }
        double RRED[9][9][9];
        for (int i = 0; i < 9; i++) for (int j = 0; j < 9; j++) for (int k = 0; k < 9; k++) RRED[i][j][k] = 0.0;
        const int off[3] = {0, 1, 4};
        double cnt[3] = {0, 0, 0};
        double rc[5][5][5];
        for (int l1 = 0; l1 <= 2; l1++) for (int l2 = 0; l2 <= 2; l2++) {
            const int Llo = std::abs(l1 - l2), Lhi = std::min(l1 + l2, 2);
            for (int L = Llo; L <= Lhi; L++) {
                real_cg_f(l1, l2, L, rc);
                for (int i1 = 0; i1 < 2 * l1 + 1; i1++)
                    for (int i2 = 0; i2 < 2 * l2 + 1; i2++)
                        for (int i3 = 0; i3 < 2 * L + 1; i3++)
                            RRED[off[l1] + i1][off[l2] + i2][off[L] + i3] += rc[i1][i2][i3];
                cnt[L] += 1.0;
            }
        }
        for (int L = 0; L <= 2; L++) {
            const double dv = std::max(cnt[L], 1.0);
            for (int a1 = 0; a1 < 9; a1++) for (int b = 0; b < 9; b++)
                for (int k = 0; k < 2 * L + 1; k++) RRED[a1][b][off[L] + k] /= dv;
        }
        for (int e = 0; e < 9; e++) for (int u = 0; u < 25; u++) h_const[e * 25 + u] = (float)YW[e][u];
        for (int e = 0; e < 9; e++) for (int l = 0; l < 9; l++) for (int m = 0; m < 9; m++)
            h_const[225 + e * 81 + l * 9 + m] = (float)RRED[e][l][m];
        for (int u = 0; u < 25; u++) for (int ax = 0; ax < 3; ax++) h_const[954 + u * 3 + ax] = (float)DIRS[u][ax];
        if (hipMalloc((void**)&d_const_g, 1029 * sizeof(float)) == hipSuccess)
            hipMemcpy(d_const_g, h_const, 1029 * sizeof(float), hipMemcpyHostToDevice);
    }
} g_init;

} // namespace

// ============================== device kernels ==============================

// R[n][p][c]: p=0 -> feat(l=0); p=1 -> |l=1 block|; p=2 -> |l=2 block|
__global__ void radial_k(const float* __restrict__ feat, float* __restrict__ R) {
    const int n = blockIdx.x, c = threadIdx.x;
    const float* f = feat + (size_t)n * 9 * 256 + c;
    const float f0 = f[0];
    const float a1 = f[256], a2 = f[512], a3 = f[768];
    const float b1 = f[1024], b2 = f[1280], b3 = f[1536], b4 = f[1792], b5 = f[2048];
    const float r1 = sqrtf(a1 * a1 + a2 * a2 + a3 * a3 + 1e-8f);
    const float r2 = sqrtf(b1 * b1 + b2 * b2 + b3 * b3 + b4 * b4 + b5 * b5 + 1e-8f);
    float* o = R + (size_t)n * 768 + c;
    o[0] = f0; o[256] = r1; o[512] = r2;
}

// fused Q/K projection GEMM (f16 MFMA): A = R (2048x768), B = Wq or Wk (768x256)
// grid (8, 32): x<4 -> Wq cols (cb=x*64), epilogue elu+1 -> qf row-major f32
//               x>=4 -> Wk cols (cb=(x-4)*64), epilogue elu+1 -> kfA frag f16
__global__ __launch_bounds__(256) void qk_gemm_k(const float* __restrict__ A,
                                                 const float* __restrict__ Wq,
                                                 const float* __restrict__ Wk,
                                                 float* __restrict__ qf,
                                                 _Float16* __restrict__ kfA) {
    __shared__ __align__(16) _Float16 Af[64 * 40];
    __shared__ __align__(16) _Float16 Bf[64 * 40];
    const int tid = threadIdx.x;
    const int w = tid >> 6, lane = tid & 63;
    const int l15 = lane & 15, quad = lane >> 4;
    const bool isK = blockIdx.x >= 4;
    const int cb = (blockIdx.x & 3) * 64;
    const int rb = blockIdx.y * 64;
    const float* B = isK ? Wk : Wq;
    const int N = 256, Kd = 768;
    const int sr = tid >> 2, sq = tid & 3;

    float4v acc[4];
#pragma unroll
    for (int s = 0; s < 4; s++) acc[s] = float4v{0.f, 0.f, 0.f, 0.f};

    for (int k0 = 0; k0 < Kd; k0 += 32) {
        __syncthreads();
        {
            const float* Ap = A + (size_t)(rb + sr) * Kd + k0 + sq * 8;
            const float4 a0 = *(const float4*)(Ap);
            const float4 a1 = *(const float4*)(Ap + 4);
            half8 hv;
            hv[0] = (_Float16)a0.x; hv[1] = (_Float16)a0.y; hv[2] = (_Float16)a0.z; hv[3] = (_Float16)a0.w;
            hv[4] = (_Float16)a1.x; hv[5] = (_Float16)a1.y; hv[6] = (_Float16)a1.z; hv[7] = (_Float16)a1.w;
            *(half8*)&Af[sr * 40 + sq * 8] = hv;
        }
        {
            const float* Bp = B + (size_t)(k0 + sq * 8) * N + cb + sr;
            half8 hv;
#pragma unroll
            for (int i = 0; i < 8; i++) hv[i] = (_Float16)Bp[(size_t)i * N];
            *(half8*)&Bf[sr * 40 + sq * 8] = hv;
        }
        __syncthreads();
        const half8 af = *(const half8*)&Af[(w * 16 + l15) * 40 + quad * 8];
#pragma unroll
        for (int s = 0; s < 4; s++) {
            const half8 bf = *(const half8*)&Bf[(s * 16 + l15) * 40 + quad * 8];
            acc[s] = __builtin_amdgcn_mfma_f32_16x16x32_f16(af, bf, acc[s], 0, 0, 0);
        }
    }
#pragma unroll
    for (int s = 0; s < 4; s++) {
#pragma unroll
        for (int r = 0; r < 4; r++) {
            const int row = rb + w * 16 + quad * 4 + r;
            const int col = cb + s * 16 + l15;
            float val = acc[s][r];
            val = (val > 0.f ? val : expf(val) - 1.f) + 1.f;
            if (isK) {
                const int hh = col >> 5, dd = col & 31, tt = dd >> 4, ll = dd & 15;
                kfA[(size_t)hh * 65536 + (size_t)(row >> 5) * 1024 + tt * 512 + ll * 32 + (row & 31)] = (_Float16)val;
            } else {
                qf[(size_t)row * 256 + col] = val;
            }
        }
    }
}

// f16 MFMA GEMM, C = A(MxK) @ B(KxN), M%64==0, N%64==0, K%32==0.
// mode 2: A f32, v16T f16 scatter
// mode 4: A = sum of 4 f16 partial buffers (stride 2359296 halves), summed in
//         f32 in stage-A. rz already applied in mm_local's epilogue. f32 C.
__global__ __launch_bounds__(256) void mfma_gemm16_k(const float* __restrict__ A, const float* __restrict__ B,
                                                     float* __restrict__ Cv, int M, int N, int Kd, int mode,
                                                     const float* __restrict__ rZ) {
    __shared__ __align__(16) _Float16 Af[64 * 40];   // [row][k], stride 40 halves (80 B)
    __shared__ __align__(16) _Float16 Bf[64 * 40];   // [col][k]
    const int tid = threadIdx.x;
    const int w = tid >> 6, lane = tid & 63;
    const int l15 = lane & 15, quad = lane >> 4;
    const int rb = blockIdx.y * 64, cb = blockIdx.x * 64;
    const int sr = tid >> 2, sq = tid & 3;           // stager: row/col 0..63, k-quartet 0..3

    float4v acc[4];
#pragma unroll
    for (int s = 0; s < 4; s++) acc[s] = float4v{0.f, 0.f, 0.f, 0.f};

    for (int k0 = 0; k0 < Kd; k0 += 32) {
        __syncthreads();
        // ---- stage A (-> f16, fragment order) ----
        if (mode == 4) {
            const _Float16* Ap16 = (const _Float16*)A + (size_t)(rb + sr) * Kd + k0 + sq * 8;
            const half8 p0 = *(const half8*)(Ap16);
            const half8 p1 = *(const half8*)(Ap16 + 2359296);
            const half8 p2 = *(const half8*)(Ap16 + 4718592);
            const half8 p3 = *(const half8*)(Ap16 + 7077888);
            half8 hv;
#pragma unroll
            for (int i = 0; i < 8; i++)
                hv[i] = (_Float16)((float)p0[i] + (float)p1[i] + (float)p2[i] + (float)p3[i]);
            *(half8*)&Af[sr * 40 + sq * 8] = hv;
        } else {
            const float* Ap = A + (size_t)(rb + sr) * Kd + k0 + sq * 8;
            const float4 a0 = *(const float4*)(Ap);
            const float4 a1 = *(const float4*)(Ap + 4);
            half8 hv;
            hv[0] = (_Float16)a0.x; hv[1] = (_Float16)a0.y; hv[2] = (_Float16)a0.z; hv[3] = (_Float16)a0.w;
            hv[4] = (_Float16)a1.x; hv[5] = (_Float16)a1.y; hv[6] = (_Float16)a1.z; hv[7] = (_Float16)a1.w;
            *(half8*)&Af[sr * 40 + sq * 8] = hv;
        }
        // ---- stage B (column gather; f32 -> f16) ----
        {
            const float* Bp = B + (size_t)(k0 + sq * 8) * N + cb + sr;
            half8 hv;
#pragma unroll
            for (int i = 0; i < 8; i++) hv[i] = (_Float16)Bp[(size_t)i * N];
            *(half8*)&Bf[sr * 40 + sq * 8] = hv;
        }
        __syncthreads();
        // ---- fragments + MFMA ----
        const half8 af = *(const half8*)&Af[(w * 16 + l15) * 40 + quad * 8];
#pragma unroll
        for (int s = 0; s < 4; s++) {
            const half8 bf = *(const half8*)&Bf[(s * 16 + l15) * 40 + quad * 8];
            acc[s] = __builtin_amdgcn_mfma_f32_16x16x32_f16(af, bf, acc[s], 0, 0, 0);
        }
    }
    // ---- epilogue: C fragment (row = rb+w*16+quad*4+r, col = cb+s*16+l15) ----
#pragma unroll
    for (int s = 0; s < 4; s++) {
#pragma unroll
        for (int r = 0; r < 4; r++) {
            const int row = rb + w * 16 + quad * 4 + r;
            const int col = cb + s * 16 + l15;
            float val = acc[s][r];
            if (mode == 2) {
                // v16T[(h*144 + c*9 + l)][n] f16
                const int n = row / 9, l = row - n * 9, hq = col >> 4, cvq = col & 15;
                _Float16* o = (_Float16*)Cv;
                o[((size_t)hq * 144 + cvq * 9 + l) * 2048 + n] = (_Float16)val;
            } else {
                Cv[(size_t)row * N + col] = val;
            }
        }
    }
}

// trigA[nb5][kkut][j] (f16, fragment-ordered) = cos/sin(kappa_kk * pos_n . dir_u)
//   kkut = (kk*25+u)*2+t (rows, padded to 512), nb5 = n>>5, j = n&31
// threads 200..255 zero the pad rows 400..511 for this n's j-slot (replaces memset)
__global__ void trig_k(const float* __restrict__ pos, const float* __restrict__ kappa,
                       const float* __restrict__ cst, _Float16* __restrict__ trigA) {
    const int n = blockIdx.x, t = threadIdx.x;
    const size_t base = (size_t)(n >> 5) * 16384 + (n & 31);
    if (t < 200) {
        const int kq = t / 25, u = t - kq * 25;
        const float* dirs = cst + 954;
        const float ph = kappa[kq] * (pos[n * 3] * dirs[u * 3] + pos[n * 3 + 1] * dirs[u * 3 + 1] + pos[n * 3 + 2] * dirs[u * 3 + 2]);
        float s, c;
        sincosf(ph, &s, &c);
        const int kkut = (kq * 25 + u) * 2;
        trigA[base + (size_t)kkut * 32] = (_Float16)c;
        trigA[base + (size_t)(kkut + 1) * 32] = (_Float16)s;
    } else {
        const int kkut = 400 + (t - 200) * 2;
        trigA[base + (size_t)kkut * 32] = (_Float16)0.f;
        trigA[base + (size_t)(kkut + 1) * 32] = (_Float16)0.f;
    }
}

// ksum[h*32+d] = sum_n kfA[h][nb5][t][l15][j]; one block per (h,d)
__global__ void ksumT_k(const _Float16* __restrict__ kfA, float* __restrict__ ksum) {
    const int b = blockIdx.x;                       // h*32+d
    const int h = b >> 5, d = b & 31, t = d >> 4, l15 = d & 15;
    const int i = threadIdx.x;                      // 256
    const half8 v = *(const half8*)(kfA + (size_t)h * 65536 + (size_t)(i >> 2) * 1024 + t * 512 + l15 * 32 + (i & 3) * 8);
    float s = 0.f;
#pragma unroll
    for (int k = 0; k < 8; k++) s += (float)v[k];
#pragma unroll
    for (int off = 32; off > 0; off >>= 1) s += __shfl_down(s, off, 64);
    __shared__ float red[4];
    if ((i & 63) == 0) red[i >> 6] = s;
    __syncthreads();
    if (i == 0) ksum[b] = red[0] + red[1] + red[2] + red[3];
}

// merged z + g (block-range dispatch, 128 blocks):
//   blocks 0..63:  rz[n][h] = 1 / (qf[n,h,:].ksum[h,:] + 1e-6)
//   blocks 64..127: G[kk][h][u][l*9+m] = sum_e aE[e,h,kk]*YW[e,u]*RRED[e,l,m]
__global__ void zg_k(const float* __restrict__ qf, const float* __restrict__ ksum, float* __restrict__ rz,
                     const float* __restrict__ a, const float* __restrict__ cst, float* __restrict__ G) {
    if (blockIdx.x < 64) {
        const int idx = blockIdx.x * 256 + threadIdx.x;   // N*H = 16384
        const int n = idx >> 3, h = idx & 7;
        float s = 0.f;
#pragma unroll
        for (int d = 0; d < 32; d++) s += qf[(size_t)n * 256 + h * 32 + d] * ksum[h * 32 + d];
        rz[idx] = 1.0f / (s + 1e-6f);
    } else {
        const int b = blockIdx.x - 64;
        const int kk = b & 7, h = b >> 3;
        __shared__ float ae[9];
        if (threadIdx.x < 9) {
            const int ldeg[9] = {0, 1, 1, 1, 2, 2, 2, 2, 2};
            ae[threadIdx.x] = a[ldeg[threadIdx.x] * 64 + h * 8 + kk];
        }
        __syncthreads();
        const float* yw = cst;
        const float* rred = cst + 225;
        for (int i = threadIdx.x; i < 25 * 81; i += 256) {
            const int u = i / 81, lm = i - u * 81;
            float s = 0.f;
#pragma unroll
            for (int e = 0; e < 9; e++) s += ae[e] * yw[e * 25 + u] * rred[e * 81 + lm];
            G[((size_t)(kk * 8 + h) * 25 + u) * 81 + lm] = s;
        }
    }
}

// MFMA multipole (R21: 64 rows/wave):
//   M16[kkut][h][cl*32+d] = sum_n trigA * kfA * v16T
// R20 counters: MfmaUtil 41%, 0 bank conflicts, stable 65.8us since R14.
// Pipe budget at 32 rows/wave: per block-round LDS = 128KB rd/85B + 20KB wr
// /128B ~ 1660cy vs MFMA 1240 SIMD-cy -> LDS-bound (ratio 1.34, matches the
// ~50% ceiling minus sync). R21 doubles rows/wave to 64 (4 row-tiles): per
// step a wave reads 4 af + 2 kq + 4 vq = 10 b128 for 32 MFMAs (0.31 vs 0.50)
// -> LDS 2145cy < MFMA 2480cy: MFMA-bound. Rows 416 -> 448 (7x64; pad rows
// zeroed by trig_k, M16 rows 400+ unread by fold). Grid (8 h, 9 colgroups,
// 7 rowquads) = 504 blocks = ~2/CU (also kills the 936@3/CU ragged tail).
// LDS sb[2][28][512] = 56KB dbuf; acc[4][8] = 128 VGPR, ~210 total ->
// launch_bounds(256,2). gridDim.x==8 keeps h->XCD affinity (R12).
__global__ __launch_bounds__(256, 2) void multipole_mm_k(const _Float16* __restrict__ trigA,
                                                         const _Float16* __restrict__ kfA,
                                                         const _Float16* __restrict__ v16T,
                                                         _Float16* __restrict__ M16) {
    const int h   = blockIdx.x;
    const int tid = threadIdx.x;
    const int w = tid >> 6, lane = tid & 63;
    const int l15 = lane & 15, quad = lane >> 4;
    const int cb  = blockIdx.y * 512 + w * 128;   // 4 cl per wave -> 128 cols
    const int cl0 = cb >> 5;
    const int r0  = blockIdx.z * 64;              // rows (kkut), 7*64 = 448

    // LDS: [buf][unit][512 halves]; step s units s*6+{0..3:af0-3, 4:kq0, 5:kq1};
    // unit 24+w = wave-private vq slab (4 steps x 4 c x 32 n).
    __shared__ __align__(16) _Float16 sb[2][28][512];   // 56 KB

    float4v acc[4][8];
#pragma unroll
    for (int rt = 0; rt < 4; rt++)
#pragma unroll
        for (int s = 0; s < 8; s++) acc[rt][s] = float4v{0.f, 0.f, 0.f, 0.f};

    // gather bases: this wave stages step s==w of each round (nb = nbr + w*32)
    const _Float16* afg0 = trigA + (size_t)(r0 + l15) * 32 + quad * 8;            // + nb5*16384; +512/row-tile
    const _Float16* kqg0 = kfA + (size_t)h * 65536 + (size_t)l15 * 32 + quad * 8; // + nb5*1024
    const _Float16* kqg1 = kqg0 + 512;
    const int vs = lane >> 4, vc = (lane >> 2) & 3, vg = lane & 3;                // vq gather decomp
    const _Float16* vqg = v16T + (size_t)(h * 144 + cl0 + vc) * 2048 + vs * 32 + vg * 8; // + nbr

    half8 g0, g1, g2, g3, g4, g5, g6;

#define GATHER(nbr_) { \
        const size_t t5 = (size_t)((nbr_) >> 5) + w; \
        g0 = *(const half8*)(afg0 + t5 * 16384); \
        g1 = *(const half8*)(afg0 + t5 * 16384 + 512); \
        g2 = *(const half8*)(afg0 + t5 * 16384 + 1024); \
        g3 = *(const half8*)(afg0 + t5 * 16384 + 1536); \
        g4 = *(const half8*)(kqg0 + t5 * 1024); \
        g5 = *(const half8*)(kqg1 + t5 * 1024); \
        g6 = *(const half8*)(vqg + (nbr_)); }

#define DSWRITE(b_) { \
        *(half8*)&sb[b_][w * 6 + 0][lane * 8] = g0; \
        *(half8*)&sb[b_][w * 6 + 1][lane * 8] = g1; \
        *(half8*)&sb[b_][w * 6 + 2][lane * 8] = g2; \
        *(half8*)&sb[b_][w * 6 + 3][lane * 8] = g3; \
        *(half8*)&sb[b_][w * 6 + 4][lane * 8] = g4; \
        *(half8*)&sb[b_][w * 6 + 5][lane * 8] = g5; \
        *(half8*)&sb[b_][24 + w][lane * 8] = g6; }

#define STEP(s_) { \
        const half8 af0 = *(const half8*)&sb[cur][(s_) * 6 + 0][lane * 8]; \
        const half8 af1 = *(const half8*)&sb[cur][(s_) * 6 + 1][lane * 8]; \
        const half8 af2 = *(const half8*)&sb[cur][(s_) * 6 + 2][lane * 8]; \
        const half8 af3 = *(const half8*)&sb[cur][(s_) * 6 + 3][lane * 8]; \
        const half8 kq0 = *(const half8*)&sb[cur][(s_) * 6 + 4][lane * 8]; \
        const half8 kq1 = *(const half8*)&sb[cur][(s_) * 6 + 5][lane * 8]; \
        _Pragma("unroll") \
        for (int c = 0; c < 4; c++) { \
            const half8 vq = *(const half8*)&sb[cur][24 + w][((s_) * 4 + c) * 32 + quad * 8]; \
            const half8 b0 = kq0 * vq; \
            const half8 b1 = kq1 * vq; \
            acc[0][2 * c]     = __builtin_amdgcn_mfma_f32_16x16x32_f16(af0, b0, acc[0][2 * c],     0, 0, 0); \
            acc[0][2 * c + 1] = __builtin_amdgcn_mfma_f32_16x16x32_f16(af0, b1, acc[0][2 * c + 1], 0, 0, 0); \
            acc[1][2 * c]     = __builtin_amdgcn_mfma_f32_16x16x32_f16(af1, b0, acc[1][2 * c],     0, 0, 0); \
            acc[1][2 * c + 1] = __builtin_amdgcn_mfma_f32_16x16x32_f16(af1, b1, acc[1][2 * c + 1], 0, 0, 0); \
            acc[2][2 * c]     = __builtin_amdgcn_mfma_f32_16x16x32_f16(af2, b0, acc[2][2 * c],     0, 0, 0); \
            acc[2][2 * c + 1] = __builtin_amdgcn_mfma_f32_16x16x32_f16(af2, b1, acc[2][2 * c + 1], 0, 0, 0); \
            acc[3][2 * c]     = __builtin_amdgcn_mfma_f32_16x16x32_f16(af3, b0, acc[3][2 * c],     0, 0, 0); \
            acc[3][2 * c + 1] = __builtin_amdgcn_mfma_f32_16x16x32_f16(af3, b1, acc[3][2 * c + 1], 0, 0, 0); \
        } }

    int cur = 0;
    GATHER(0)
    DSWRITE(0)
    __syncthreads();
#pragma unroll 1
    for (int r = 0; r < 16; ++r) {
        if (r < 15) GATHER((r + 1) * 128)
        STEP(0)
        STEP(1)
        STEP(2)
        STEP(3)
        if (r < 15) DSWRITE(cur ^ 1)
        __syncthreads();
        cur ^= 1;
    }

#undef GATHER
#undef DSWRITE
#undef STEP

    // epilogue: C fragment -> M16[kkut][h][col]
#pragma unroll
    for (int rt = 0; rt < 4; rt++)
#pragma unroll
        for (int c = 0; c < 4; c++)
#pragma unroll
            for (int half = 0; half < 2; half++)
#pragma unroll
                for (int r = 0; r < 4; r++) {
                    const int row = r0 + rt * 16 + quad * 4 + r;
                    const int col = cb + c * 32 + half * 16 + l15;
                    M16[((size_t)row * 8 + h) * 4608 + col] = (_Float16)acc[rt][c * 2 + half][r];
                }
}

// MG[kt][h][ct*512 + quad*128 + l15*8 + j] (f16, fragment-ordered)
//   = sum_l M16[kt][h][(c*9+l)*32+d] * G[kk,h,u][l*9+m], cm=ct*16+l15, d=quad*8+j
__global__ __launch_bounds__(256) void fold_k(const _Float16* __restrict__ Mv, const float* __restrict__ G,
                                              _Float16* __restrict__ MG) {
    const int kt = blockIdx.x, h = blockIdx.y;
    const int tid = threadIdx.x;
    __shared__ float ms[144 * 33];   // [cl][d] padded 33
    __shared__ float gs[81];
    const _Float16* src = Mv + ((size_t)kt * 8 + h) * 4608;
    for (int i = tid; i < 4608; i += 256) {
        const int cl = i >> 5, d = i & 31;
        ms[cl * 33 + d] = (float)src[i];
    }
    const int kk = kt / 50, u = (kt >> 1) % 25;
    if (tid < 81) gs[tid] = G[(((size_t)kk * 8 + h) * 25 + u) * 81 + tid];
    __syncthreads();
    _Float16* dst = MG + ((size_t)kt * 8 + h) * 4608;
    for (int i = tid; i < 4608; i += 256) {
        const int ct = i >> 9, quad = (i >> 7) & 3, l15 = (i >> 3) & 15, j = i & 7;
        const int d = quad * 8 + j;
        const int cm = ct * 16 + l15, c = cm / 9, m = cm - c * 9;
        float s = 0.f;
#pragma unroll
        for (int l = 0; l < 9; l++) s += ms[(c * 9 + l) * 33 + d] * gs[l * 9 + m];
        dst[i] = (_Float16)s;
    }
}

// local stage via MFMA (R20 config, unchanged in R21):
// R15 geometry (32 rows/wave, 4 slices x 100kt, 2 blk/CU, 4-kt rounds) +
// f16 partial writes + rz applied here in f32 before the single f16 rounding.
// grid (8, 4, 16) = 512 blocks = 2/CU; LDS 73.7KB dbuf.
__global__ __launch_bounds__(256, 2) void mm_local_k(const float* __restrict__ qf, const _Float16* __restrict__ trigA,
                                                     const _Float16* __restrict__ MG, const float* __restrict__ rZ,
                                                     _Float16* __restrict__ outp) {
    const int combo = blockIdx.y * 8 + blockIdx.x;
    const int h = combo >> 2;
    const int slice = combo & 3;
    const int n0 = blockIdx.z * 128;
    const int tid = threadIdx.x;
    const int w = tid >> 6, lane = tid & 63;
    const int l15 = lane & 15, quad = lane >> 4;

    // staging sb[2][4][4608] f16 (73728B), overlaid later by epilogue eb (37888B)
    __shared__ __align__(16) unsigned char smem_raw[73728];
    _Float16 (*sb)[4][4608] = (_Float16 (*)[4][4608])smem_raw;

    const int nbase = n0 + w * 32;                      // 32 rows per wave
    half8 qfr16[2];
#pragma unroll
    for (int rt = 0; rt < 2; rt++) {
        const int n = nbase + rt * 16 + l15;
        const float* qp = qf + (size_t)n * 256 + h * 32 + quad * 8;
#pragma unroll
        for (int j = 0; j < 8; j++) qfr16[rt][j] = (_Float16)qp[j];
    }
    float4v acc[2][9];
#pragma unroll
    for (int rt = 0; rt < 2; rt++)
#pragma unroll
        for (int ct = 0; ct < 9; ct++) acc[rt][ct] = float4v{0.f, 0.f, 0.f, 0.f};

    const int kt0 = slice * 100;
    // per-lane staging source: lane*8 halves = quad*128 + l15*8 (the read offset)
    const _Float16* mg0 = MG + (((size_t)kt0 * 8 + h) * 4608) + lane * 8;
    // trig scalars: trigA[nb5][kt][rt*16+l15] (all 32 rows in slab nbase>>5)
    const _Float16* trg0 = trigA + (size_t)(nbase >> 5) * 16384 + (size_t)kt0 * 32 + l15;

    // wave w stages kt = base_ + w of this round: 9 x global_load_lds_dwordx4
#define STAGE4(b_, base_) { \
        const _Float16* src = mg0 + (size_t)((base_) + w) * 8 * 4608; \
        _Float16* dstl = &sb[b_][w][0]; \
        _Pragma("unroll") \
        for (int i = 0; i < 9; i++) \
            __builtin_amdgcn_global_load_lds( \
                (const __attribute__((address_space(1))) void*)(src + i * 512), \
                (__attribute__((address_space(3))) void*)(dstl + i * 512), 16, 0, 0); }

#define COMPUTE(kl) { \
        half8 tv0, tv1; \
        _Pragma("unroll") \
        for (int j = 0; j < 8; j++) { tv0[j] = ta[kl]; tv1[j] = tb[kl]; } \
        const half8 af0 = tv0 * qfr16[0]; \
        const half8 af1 = tv1 * qfr16[1]; \
        _Pragma("unroll") \
        for (int ct = 0; ct < 9; ct++) { \
            const half8 b = *(const half8*)&sb[cur][kl][ct * 512 + quad * 128 + l15 * 8]; \
            acc[0][ct] = __builtin_amdgcn_mfma_f32_16x16x32_f16(af0, b, acc[0][ct], 0, 0, 0); \
            acc[1][ct] = __builtin_amdgcn_mfma_f32_16x16x32_f16(af1, b, acc[1][ct], 0, 0, 0); \
        } }

    _Float16 ta[4], tb[4], ua[4], ub[4];
    int cur = 0;
    STAGE4(0, 0)
#pragma unroll
    for (int kl = 0; kl < 4; kl++) { ta[kl] = trg0[kl * 32]; tb[kl] = trg0[kl * 32 + 16]; }
    __syncthreads();

#pragma unroll 1
    for (int r = 0; r < 25; ++r) {
        if (r < 24) {
            STAGE4(cur ^ 1, (r + 1) * 4)
#pragma unroll
            for (int kl = 0; kl < 4; kl++) {
                const size_t o = (size_t)((r + 1) * 4 + kl) * 32;
                ua[kl] = trg0[o]; ub[kl] = trg0[o + 16];
            }
        }
        COMPUTE(0) COMPUTE(1) COMPUTE(2) COMPUTE(3)
        __syncthreads();
        cur ^= 1;
#pragma unroll
        for (int kl = 0; kl < 4; kl++) { ta[kl] = ua[kl]; tb[kl] = ub[kl]; }
    }

#undef STAGE4
#undef COMPUTE

    // epilogue: LDS transpose -> coalesced f16 stores into outp[slice][n][m][h*16+c]
    // rz[n][h] applied here (f32, before the single f16 rounding).
    // eb overlaid on sb (dead; 37888B <= 73728B)
    float* ebp = (float*)smem_raw;
    _Float16* dst = outp + (size_t)slice * 2359296;
    const int g4 = lane >> 2, sub = lane & 3;
#pragma unroll
    for (int rt = 0; rt < 2; rt++) {
        __syncthreads();
#pragma unroll
        for (int ct = 0; ct < 9; ct++) {
            const int cm = ct * 16 + l15;
            const int c = cm / 9, m = cm - c * 9;
#pragma unroll
            for (int r = 0; r < 4; r++)
                ebp[(size_t)(w * 16 + quad * 4 + r) * 148 + m * 16 + c] = acc[rt][ct][r];
        }
        __syncthreads();
#pragma unroll
        for (int s = 0; s < 9; s++) {
            const int li = s * 16 + g4;            // 0..143 line index
            const int nl = li / 9, m = li - nl * 9;
            const float4 v4 = *(const float4*)&ebp[(size_t)(w * 16 + nl) * 148 + m * 16 + sub * 4];
            const int n = nbase + rt * 16 + nl;
            const float rzv = rZ[(size_t)n * 8 + h];
            half4v hv;
            hv[0] = (_Float16)(v4.x * rzv); hv[1] = (_Float16)(v4.y * rzv);
            hv[2] = (_Float16)(v4.z * rzv); hv[3] = (_Float16)(v4.w * rzv);
            *(half4v*)&dst[((size_t)n * 9 + m) * 128 + h * 16 + sub * 4] = hv;
        }
    }
}

// ================================ launcher =================================
extern "C" void kernel_launch(void* const* d_in, const int* in_sizes, int n_in,
                              void* d_out, int out_size, void* d_ws, size_t ws_size,
                              hipStream_t stream) {
    const float* pos  = (const float*)d_in[0];
    const float* feat = (const float*)d_in[1];
    const float* Wq   = (const float*)d_in[2];
    const float* Wk   = (const float*)d_in[3];
    const float* Wv   = (const float*)d_in[4];
    const float* Wo   = (const float*)d_in[5];
    const float* a    = (const float*)d_in[6];
    const float* kap  = (const float*)d_in[7];
    float* out = (float*)d_out;
    float* ws = (float*)d_ws;

    // float-slot layout (~77.8 MB total)
    float* qf    = ws;                    // 524288
    float* kfAF  = qf + 524288;           // 262144 slots = kfA f16[8][64][2][512]
    float* vTF   = kfAF + 262144;         // 1179648 slots = v16T f16[1152*2048]
    float* trigF = vTF + 1179648;         // 524288 slots = trigA f16[64][512][32]
    float* ksum  = trigF + 524288;        // 256
    float* rz    = ksum + 256;            // 16384
    float* G     = rz + 16384;            // 129600
    float* M16F  = G + 129600;            // 9437184 slots = M16 f16[512*8*4608]; later outp f16[4][2359296]
    float* regX  = M16F + 9437184;        // 7372800 slots: R (first 1572864), later MG f16[400*8*4608]
    float* R     = regX;
    _Float16* trigA = (_Float16*)trigF;
    _Float16* kfA   = (_Float16*)kfAF;
    _Float16* v16T  = (_Float16*)vTF;
    _Float16* M16   = (_Float16*)M16F;
    _Float16* MG16  = (_Float16*)regX;
    _Float16* outp16 = (_Float16*)M16F;   // overlay: M16 dead after fold_k; 4 f16 partial buffers

    const float* cst = d_const_g;

    hipLaunchKernelGGL(radial_k, dim3(2048), dim3(256), 0, stream, feat, R);
    hipLaunchKernelGGL(qk_gemm_k, dim3(8, 32), dim3(256), 0, stream, R, Wq, Wk, qf, kfA);
    hipLaunchKernelGGL(mfma_gemm16_k, dim3(2, 288), dim3(256), 0, stream, feat, Wv, vTF, 18432, 128, 256, 2, rz);
    hipLaunchKernelGGL(trig_k, dim3(2048), dim3(256), 0, stream, pos, kap, cst, trigA);
    hipLaunchKernelGGL(ksumT_k, dim3(256), dim3(256), 0, stream, kfA, ksum);
    hipLaunchKernelGGL(zg_k, dim3(128), dim3(256), 0, stream, qf, ksum, rz, a, cst, G);
    hipLaunchKernelGGL(multipole_mm_k, dim3(8, 9, 7), dim3(256), 0, stream, trigA, kfA, v16T, M16);
    hipLaunchKernelGGL(fold_k, dim3(400, 8), dim3(256), 0, stream, M16, G, MG16);
    hipLaunchKernelGGL(mm_local_k, dim3(8, 4, 16), dim3(256), 0, stream, qf, trigA, MG16, rz, outp16);
    hipLaunchKernelGGL(mfma_gemm16_k, dim3(4, 288), dim3(256), 0, stream, (const float*)outp16, Wo, out, 18432, 256, 128, 4, rz);
}

// Round 9
// 293.027 us; speedup vs baseline: 1.1784x; 1.0230x over previous
//
#include <hip/hip_runtime.h>
#include <cmath>
#include <complex>
#include <algorithm>

// ---------------------------------------------------------------------------
// Problem constants: LMAX=2, NC=9, H=8, DQK=32, CV=16, K=8, U=25, N=2048, C=256
// ---------------------------------------------------------------------------

typedef _Float16 half8 __attribute__((ext_vector_type(8)));
typedef _Float16 half4v __attribute__((ext_vector_type(4)));
typedef float float4v __attribute__((ext_vector_type(4)));

// ========================= host-side constant tables ========================
namespace {

using cd = std::complex<double>;

static double fct(int n) { double r = 1.0; for (int i = 2; i <= n; ++i) r *= i; return r; }

static double cg_coef(int j1, int m1, int j2, int m2, int j, int m) {
    if (m1 + m2 != m || j < std::abs(j1 - j2) || j > j1 + j2) return 0.0;
    double pref = std::sqrt((2 * j + 1) * fct(j + j1 - j2) * fct(j - j1 + j2) * fct(j1 + j2 - j) / fct(j1 + j2 + j + 1));
    pref *= std::sqrt(fct(j + m) * fct(j - m) * fct(j1 - m1) * fct(j1 + m1) * fct(j2 - m2) * fct(j2 + m2));
    double s = 0.0;
    for (int k = 0; k <= j1 + j2 - j; ++k) {
        int d0 = k, d1 = j1 + j2 - j - k, d2 = j1 - m1 - k, d3 = j2 + m2 - k, d4 = j - j2 + m1 + k, d5 = j - j1 - m2 + k;
        if (d0 < 0 || d1 < 0 || d2 < 0 || d3 < 0 || d4 < 0 || d5 < 0) continue;
        s += ((k & 1) ? -1.0 : 1.0) / (fct(d0) * fct(d1) * fct(d2) * fct(d3) * fct(d4) * fct(d5));
    }
    return pref * s;
}

static void umat(int l, cd u[5][5]) {
    for (int i = 0; i < 5; i++) for (int j = 0; j < 5; j++) u[i][j] = cd(0, 0);
    const double s = 1.0 / std::sqrt(2.0);
    for (int m = -l; m <= l; m++) {
        double sgn = (std::abs(m) & 1) ? -1.0 : 1.0;   // (-1)^m
        if (m > 0)      { u[l + m][l + m] = cd(sgn * s, 0); u[l + m][l - m] = cd(s, 0); }
        else if (m == 0){ u[l][l] = cd(1, 0); }
        else            { u[l + m][l + m] = cd(0, s);       u[l + m][l - m] = cd(0, -sgn * s); }
    }
}

static void real_cg_f(int l1, int l2, int L, double out[5][5][5]) {
    cd U1[5][5], U2[5][5], UL[5][5];
    umat(l1, U1); umat(l2, U2); umat(L, UL);
    const int n1 = 2 * l1 + 1, n2 = 2 * l2 + 1, n3 = 2 * L + 1;
    double cgt[5][5][5];
    for (int i1 = 0; i1 < n1; i1++) for (int i2 = 0; i2 < n2; i2++) for (int i3 = 0; i3 < n3; i3++)
        cgt[i1][i2][i3] = cg_coef(l1, i1 - l1, l2, i2 - l2, L, i3 - L);
    cd r[5][5][5];
    double nr = 0, ni = 0;
    for (int a1 = 0; a1 < n1; a1++) for (int b = 0; b < n2; b++) for (int c = 0; c < n3; c++) {
        cd acc(0, 0);
        for (int uu = 0; uu < n1; uu++) for (int vv = 0; vv < n2; vv++) for (int w = 0; w < n3; w++) {
            double cval = cgt[uu][vv][w];
            if (cval == 0.0) continue;
            acc += U1[a1][uu] * U2[b][vv] * std::conj(UL[c][w]) * cval;
        }
        r[a1][b][c] = acc;
        nr += acc.real() * acc.real();
        ni += acc.imag() * acc.imag();
    }
    const bool useRe = std::sqrt(nr) >= std::sqrt(ni);
    for (int a1 = 0; a1 < n1; a1++) for (int b = 0; b < n2; b++) for (int c = 0; c < n3; c++)
        out[a1][b][c] = useRe ? r[a1][b][c].real() : r[a1][b][c].imag();
}

// device constant buffer layout: YW[9*25] | RRED[9*81] | DIRS[25*3]  = 1029 floats
static float  h_const[1029];
static float* d_const_g = nullptr;

struct GlobalInit {
    GlobalInit() {
        const double PI = 3.14159265358979323846;
        const double gx[5] = {-0.9061798459386640, -0.5384693101056831, 0.0, 0.5384693101056831, 0.9061798459386640};
        const double gw[5] = { 0.23692688505618908, 0.47862867049936647, 0.5688888888888889, 0.47862867049936647, 0.23692688505618908};
        double YW[9][25], DIRS[25][3];
        for (int u = 0; u < 25; ++u) {
            const int it = u / 5, ip = u % 5;
            const double ct = gx[it], wq = gw[it] * (2.0 * PI / 5.0), ph = 2.0 * PI * ip / 5.0;
            const double st = std::sqrt(std::max(1.0 - ct * ct, 0.0));
            const double x = st * std::cos(ph), y = st * std::sin(ph), z = ct;
            DIRS[u][0] = x; DIRS[u][1] = y; DIRS[u][2] = z;
            double Y[9];
            Y[0] = 0.282095;           Y[1] = 0.488603 * y;      Y[2] = 0.488603 * z;
            Y[3] = 0.488603 * x;       Y[4] = 1.092548 * x * y;  Y[5] = 1.092548 * y * z;
            Y[6] = 0.315392 * (3 * z * z - 1); Y[7] = 1.092548 * x * z; Y[8] = 0.546274 * (x * x - y * y);
            for (int e = 0; e < 9; e++) YW[e][u] = Y[e] * wq;
        }
        double RRED[9][9][9];
        for (int i = 0; i < 9; i++) for (int j = 0; j < 9; j++) for (int k = 0; k < 9; k++) RRED[i][j][k] = 0.0;
        const int off[3] = {0, 1, 4};
        double cnt[3] = {0, 0, 0};
        double rc[5][5][5];
        for (int l1 = 0; l1 <= 2; l1++) for (int l2 = 0; l2 <= 2; l2++) {
            const int Llo = std::abs(l1 - l2), Lhi = std::min(l1 + l2, 2);
            for (int L = Llo; L <= Lhi; L++) {
                real_cg_f(l1, l2, L, rc);
                for (int i1 = 0; i1 < 2 * l1 + 1; i1++)
                    for (int i2 = 0; i2 < 2 * l2 + 1; i2++)
                        for (int i3 = 0; i3 < 2 * L + 1; i3++)
                            RRED[off[l1] + i1][off[l2] + i2][off[L] + i3] += rc[i1][i2][i3];
                cnt[L] += 1.0;
            }
        }
        for (int L = 0; L <= 2; L++) {
            const double dv = std::max(cnt[L], 1.0);
            for (int a1 = 0; a1 < 9; a1++) for (int b = 0; b < 9; b++)
                for (int k = 0; k < 2 * L + 1; k++) RRED[a1][b][off[L] + k] /= dv;
        }
        for (int e = 0; e < 9; e++) for (int u = 0; u < 25; u++) h_const[e * 25 + u] = (float)YW[e][u];
        for (int e = 0; e < 9; e++) for (int l = 0; l < 9; l++) for (int m = 0; m < 9; m++)
            h_const[225 + e * 81 + l * 9 + m] = (float)RRED[e][l][m];
        for (int u = 0; u < 25; u++) for (int ax = 0; ax < 3; ax++) h_const[954 + u * 3 + ax] = (float)DIRS[u][ax];
        if (hipMalloc((void**)&d_const_g, 1029 * sizeof(float)) == hipSuccess)
            hipMemcpy(d_const_g, h_const, 1029 * sizeof(float), hipMemcpyHostToDevice);
    }
} g_init;

} // namespace

// ============================== device kernels ==============================

// R[n][p][c]: p=0 -> feat(l=0); p=1 -> |l=1 block|; p=2 -> |l=2 block|
__global__ void radial_k(const float* __restrict__ feat, float* __restrict__ R) {
    const int n = blockIdx.x, c = threadIdx.x;
    const float* f = feat + (size_t)n * 9 * 256 + c;
    const float f0 = f[0];
    const float a1 = f[256], a2 = f[512], a3 = f[768];
    const float b1 = f[1024], b2 = f[1280], b3 = f[1536], b4 = f[1792], b5 = f[2048];
    const float r1 = sqrtf(a1 * a1 + a2 * a2 + a3 * a3 + 1e-8f);
    const float r2 = sqrtf(b1 * b1 + b2 * b2 + b3 * b3 + b4 * b4 + b5 * b5 + 1e-8f);
    float* o = R + (size_t)n * 768 + c;
    o[0] = f0; o[256] = r1; o[512] = r2;
}

// fused Q/K projection GEMM (f16 MFMA): A = R (2048x768), B = Wq or Wk (768x256)
// grid (8, 32): x<4 -> Wq cols (cb=x*64), epilogue elu+1 -> qf row-major f32
//               x>=4 -> Wk cols (cb=(x-4)*64), epilogue elu+1 -> kfA frag f16
__global__ __launch_bounds__(256) void qk_gemm_k(const float* __restrict__ A,
                                                 const float* __restrict__ Wq,
                                                 const float* __restrict__ Wk,
                                                 float* __restrict__ qf,
                                                 _Float16* __restrict__ kfA) {
    __shared__ __align__(16) _Float16 Af[64 * 40];
    __shared__ __align__(16) _Float16 Bf[64 * 40];
    const int tid = threadIdx.x;
    const int w = tid >> 6, lane = tid & 63;
    const int l15 = lane & 15, quad = lane >> 4;
    const bool isK = blockIdx.x >= 4;
    const int cb = (blockIdx.x & 3) * 64;
    const int rb = blockIdx.y * 64;
    const float* B = isK ? Wk : Wq;
    const int N = 256, Kd = 768;
    const int sr = tid >> 2, sq = tid & 3;

    float4v acc[4];
#pragma unroll
    for (int s = 0; s < 4; s++) acc[s] = float4v{0.f, 0.f, 0.f, 0.f};

    for (int k0 = 0; k0 < Kd; k0 += 32) {
        __syncthreads();
        {
            const float* Ap = A + (size_t)(rb + sr) * Kd + k0 + sq * 8;
            const float4 a0 = *(const float4*)(Ap);
            const float4 a1 = *(const float4*)(Ap + 4);
            half8 hv;
            hv[0] = (_Float16)a0.x; hv[1] = (_Float16)a0.y; hv[2] = (_Float16)a0.z; hv[3] = (_Float16)a0.w;
            hv[4] = (_Float16)a1.x; hv[5] = (_Float16)a1.y; hv[6] = (_Float16)a1.z; hv[7] = (_Float16)a1.w;
            *(half8*)&Af[sr * 40 + sq * 8] = hv;
        }
        {
            const float* Bp = B + (size_t)(k0 + sq * 8) * N + cb + sr;
            half8 hv;
#pragma unroll
            for (int i = 0; i < 8; i++) hv[i] = (_Float16)Bp[(size_t)i * N];
            *(half8*)&Bf[sr * 40 + sq * 8] = hv;
        }
        __syncthreads();
        const half8 af = *(const half8*)&Af[(w * 16 + l15) * 40 + quad * 8];
#pragma unroll
        for (int s = 0; s < 4; s++) {
            const half8 bf = *(const half8*)&Bf[(s * 16 + l15) * 40 + quad * 8];
            acc[s] = __builtin_amdgcn_mfma_f32_16x16x32_f16(af, bf, acc[s], 0, 0, 0);
        }
    }
#pragma unroll
    for (int s = 0; s < 4; s++) {
#pragma unroll
        for (int r = 0; r < 4; r++) {
            const int row = rb + w * 16 + quad * 4 + r;
            const int col = cb + s * 16 + l15;
            float val = acc[s][r];
            val = (val > 0.f ? val : expf(val) - 1.f) + 1.f;
            if (isK) {
                const int hh = col >> 5, dd = col & 31, tt = dd >> 4, ll = dd & 15;
                kfA[(size_t)hh * 65536 + (size_t)(row >> 5) * 1024 + tt * 512 + ll * 32 + (row & 31)] = (_Float16)val;
            } else {
                qf[(size_t)row * 256 + col] = val;
            }
        }
    }
}

// f16 MFMA GEMM, C = A(MxK) @ B(KxN), M%64==0, N%64==0, K%32==0.
// mode 2: A f32, v16T f16 scatter
// mode 4: A = sum of 4 f16 partial buffers (stride 2359296 halves), summed in
//         f32 in stage-A. rz already applied in mm_local's epilogue. f32 C.
__global__ __launch_bounds__(256) void mfma_gemm16_k(const float* __restrict__ A, const float* __restrict__ B,
                                                     float* __restrict__ Cv, int M, int N, int Kd, int mode,
                                                     const float* __restrict__ rZ) {
    __shared__ __align__(16) _Float16 Af[64 * 40];   // [row][k], stride 40 halves (80 B)
    __shared__ __align__(16) _Float16 Bf[64 * 40];   // [col][k]
    const int tid = threadIdx.x;
    const int w = tid >> 6, lane = tid & 63;
    const int l15 = lane & 15, quad = lane >> 4;
    const int rb = blockIdx.y * 64, cb = blockIdx.x * 64;
    const int sr = tid >> 2, sq = tid & 3;           // stager: row/col 0..63, k-quartet 0..3

    float4v acc[4];
#pragma unroll
    for (int s = 0; s < 4; s++) acc[s] = float4v{0.f, 0.f, 0.f, 0.f};

    for (int k0 = 0; k0 < Kd; k0 += 32) {
        __syncthreads();
        // ---- stage A (-> f16, fragment order) ----
        if (mode == 4) {
            const _Float16* Ap16 = (const _Float16*)A + (size_t)(rb + sr) * Kd + k0 + sq * 8;
            const half8 p0 = *(const half8*)(Ap16);
            const half8 p1 = *(const half8*)(Ap16 + 2359296);
            const half8 p2 = *(const half8*)(Ap16 + 4718592);
            const half8 p3 = *(const half8*)(Ap16 + 7077888);
            half8 hv;
#pragma unroll
            for (int i = 0; i < 8; i++)
                hv[i] = (_Float16)((float)p0[i] + (float)p1[i] + (float)p2[i] + (float)p3[i]);
            *(half8*)&Af[sr * 40 + sq * 8] = hv;
        } else {
            const float* Ap = A + (size_t)(rb + sr) * Kd + k0 + sq * 8;
            const float4 a0 = *(const float4*)(Ap);
            const float4 a1 = *(const float4*)(Ap + 4);
            half8 hv;
            hv[0] = (_Float16)a0.x; hv[1] = (_Float16)a0.y; hv[2] = (_Float16)a0.z; hv[3] = (_Float16)a0.w;
            hv[4] = (_Float16)a1.x; hv[5] = (_Float16)a1.y; hv[6] = (_Float16)a1.z; hv[7] = (_Float16)a1.w;
            *(half8*)&Af[sr * 40 + sq * 8] = hv;
        }
        // ---- stage B (column gather; f32 -> f16) ----
        {
            const float* Bp = B + (size_t)(k0 + sq * 8) * N + cb + sr;
            half8 hv;
#pragma unroll
            for (int i = 0; i < 8; i++) hv[i] = (_Float16)Bp[(size_t)i * N];
            *(half8*)&Bf[sr * 40 + sq * 8] = hv;
        }
        __syncthreads();
        // ---- fragments + MFMA ----
        const half8 af = *(const half8*)&Af[(w * 16 + l15) * 40 + quad * 8];
#pragma unroll
        for (int s = 0; s < 4; s++) {
            const half8 bf = *(const half8*)&Bf[(s * 16 + l15) * 40 + quad * 8];
            acc[s] = __builtin_amdgcn_mfma_f32_16x16x32_f16(af, bf, acc[s], 0, 0, 0);
        }
    }
    // ---- epilogue: C fragment (row = rb+w*16+quad*4+r, col = cb+s*16+l15) ----
#pragma unroll
    for (int s = 0; s < 4; s++) {
#pragma unroll
        for (int r = 0; r < 4; r++) {
            const int row = rb + w * 16 + quad * 4 + r;
            const int col = cb + s * 16 + l15;
            float val = acc[s][r];
            if (mode == 2) {
                // v16T[(h*144 + c*9 + l)][n] f16
                const int n = row / 9, l = row - n * 9, hq = col >> 4, cvq = col & 15;
                _Float16* o = (_Float16*)Cv;
                o[((size_t)hq * 144 + cvq * 9 + l) * 2048 + n] = (_Float16)val;
            } else {
                Cv[(size_t)row * N + col] = val;
            }
        }
    }
}

// trigA[nb5][kkut][j] (f16, fragment-ordered) = cos/sin(kappa_kk * pos_n . dir_u)
//   kkut = (kk*25+u)*2+t (rows, padded to 512), nb5 = n>>5, j = n&31
// threads 200..255 zero the pad rows 400..511 for this n's j-slot (replaces memset)
__global__ void trig_k(const float* __restrict__ pos, const float* __restrict__ kappa,
                       const float* __restrict__ cst, _Float16* __restrict__ trigA) {
    const int n = blockIdx.x, t = threadIdx.x;
    const size_t base = (size_t)(n >> 5) * 16384 + (n & 31);
    if (t < 200) {
        const int kq = t / 25, u = t - kq * 25;
        const float* dirs = cst + 954;
        const float ph = kappa[kq] * (pos[n * 3] * dirs[u * 3] + pos[n * 3 + 1] * dirs[u * 3 + 1] + pos[n * 3 + 2] * dirs[u * 3 + 2]);
        float s, c;
        sincosf(ph, &s, &c);
        const int kkut = (kq * 25 + u) * 2;
        trigA[base + (size_t)kkut * 32] = (_Float16)c;
        trigA[base + (size_t)(kkut + 1) * 32] = (_Float16)s;
    } else {
        const int kkut = 400 + (t - 200) * 2;
        trigA[base + (size_t)kkut * 32] = (_Float16)0.f;
        trigA[base + (size_t)(kkut + 1) * 32] = (_Float16)0.f;
    }
}

// ksum[h*32+d] = sum_n kfA[h][nb5][t][l15][j]; one block per (h,d)
__global__ void ksumT_k(const _Float16* __restrict__ kfA, float* __restrict__ ksum) {
    const int b = blockIdx.x;                       // h*32+d
    const int h = b >> 5, d = b & 31, t = d >> 4, l15 = d & 15;
    const int i = threadIdx.x;                      // 256
    const half8 v = *(const half8*)(kfA + (size_t)h * 65536 + (size_t)(i >> 2) * 1024 + t * 512 + l15 * 32 + (i & 3) * 8);
    float s = 0.f;
#pragma unroll
    for (int k = 0; k < 8; k++) s += (float)v[k];
#pragma unroll
    for (int off = 32; off > 0; off >>= 1) s += __shfl_down(s, off, 64);
    __shared__ float red[4];
    if ((i & 63) == 0) red[i >> 6] = s;
    __syncthreads();
    if (i == 0) ksum[b] = red[0] + red[1] + red[2] + red[3];
}

// merged z + g (block-range dispatch, 128 blocks):
//   blocks 0..63:  rz[n][h] = 1 / (qf[n,h,:].ksum[h,:] + 1e-6)
//   blocks 64..127: G[kk][h][u][l*9+m] = sum_e aE[e,h,kk]*YW[e,u]*RRED[e,l,m]
__global__ void zg_k(const float* __restrict__ qf, const float* __restrict__ ksum, float* __restrict__ rz,
                     const float* __restrict__ a, const float* __restrict__ cst, float* __restrict__ G) {
    if (blockIdx.x < 64) {
        const int idx = blockIdx.x * 256 + threadIdx.x;   // N*H = 16384
        const int n = idx >> 3, h = idx & 7;
        float s = 0.f;
#pragma unroll
        for (int d = 0; d < 32; d++) s += qf[(size_t)n * 256 + h * 32 + d] * ksum[h * 32 + d];
        rz[idx] = 1.0f / (s + 1e-6f);
    } else {
        const int b = blockIdx.x - 64;
        const int kk = b & 7, h = b >> 3;
        __shared__ float ae[9];
        if (threadIdx.x < 9) {
            const int ldeg[9] = {0, 1, 1, 1, 2, 2, 2, 2, 2};
            ae[threadIdx.x] = a[ldeg[threadIdx.x] * 64 + h * 8 + kk];
        }
        __syncthreads();
        const float* yw = cst;
        const float* rred = cst + 225;
        for (int i = threadIdx.x; i < 25 * 81; i += 256) {
            const int u = i / 81, lm = i - u * 81;
            float s = 0.f;
#pragma unroll
            for (int e = 0; e < 9; e++) s += ae[e] * yw[e * 25 + u] * rred[e * 81 + lm];
            G[((size_t)(kk * 8 + h) * 25 + u) * 81 + lm] = s;
        }
    }
}

// MFMA multipole (R21: 64 rows/wave):
//   M16[kkut][h][cl*32+d] = sum_n trigA * kfA * v16T
// Verified R21: 64 rows/wave (4 row-tiles) made the kernel MFMA-bound; total
// -25us, multipole out of top-5. Grid (8 h, 9 colgroups, 7 rowquads) = 504
// blocks ~2/CU; LDS 56KB dbuf; gridDim.x==8 keeps h->XCD affinity (R12).
__global__ __launch_bounds__(256, 2) void multipole_mm_k(const _Float16* __restrict__ trigA,
                                                         const _Float16* __restrict__ kfA,
                                                         const _Float16* __restrict__ v16T,
                                                         _Float16* __restrict__ M16) {
    const int h   = blockIdx.x;
    const int tid = threadIdx.x;
    const int w = tid >> 6, lane = tid & 63;
    const int l15 = lane & 15, quad = lane >> 4;
    const int cb  = blockIdx.y * 512 + w * 128;   // 4 cl per wave -> 128 cols
    const int cl0 = cb >> 5;
    const int r0  = blockIdx.z * 64;              // rows (kkut), 7*64 = 448

    // LDS: [buf][unit][512 halves]; step s units s*6+{0..3:af0-3, 4:kq0, 5:kq1};
    // unit 24+w = wave-private vq slab (4 steps x 4 c x 32 n).
    __shared__ __align__(16) _Float16 sb[2][28][512];   // 56 KB

    float4v acc[4][8];
#pragma unroll
    for (int rt = 0; rt < 4; rt++)
#pragma unroll
        for (int s = 0; s < 8; s++) acc[rt][s] = float4v{0.f, 0.f, 0.f, 0.f};

    // gather bases: this wave stages step s==w of each round (nb = nbr + w*32)
    const _Float16* afg0 = trigA + (size_t)(r0 + l15) * 32 + quad * 8;            // + nb5*16384; +512/row-tile
    const _Float16* kqg0 = kfA + (size_t)h * 65536 + (size_t)l15 * 32 + quad * 8; // + nb5*1024
    const _Float16* kqg1 = kqg0 + 512;
    const int vs = lane >> 4, vc = (lane >> 2) & 3, vg = lane & 3;                // vq gather decomp
    const _Float16* vqg = v16T + (size_t)(h * 144 + cl0 + vc) * 2048 + vs * 32 + vg * 8; // + nbr

    half8 g0, g1, g2, g3, g4, g5, g6;

#define GATHER(nbr_) { \
        const size_t t5 = (size_t)((nbr_) >> 5) + w; \
        g0 = *(const half8*)(afg0 + t5 * 16384); \
        g1 = *(const half8*)(afg0 + t5 * 16384 + 512); \
        g2 = *(const half8*)(afg0 + t5 * 16384 + 1024); \
        g3 = *(const half8*)(afg0 + t5 * 16384 + 1536); \
        g4 = *(const half8*)(kqg0 + t5 * 1024); \
        g5 = *(const half8*)(kqg1 + t5 * 1024); \
        g6 = *(const half8*)(vqg + (nbr_)); }

#define DSWRITE(b_) { \
        *(half8*)&sb[b_][w * 6 + 0][lane * 8] = g0; \
        *(half8*)&sb[b_][w * 6 + 1][lane * 8] = g1; \
        *(half8*)&sb[b_][w * 6 + 2][lane * 8] = g2; \
        *(half8*)&sb[b_][w * 6 + 3][lane * 8] = g3; \
        *(half8*)&sb[b_][w * 6 + 4][lane * 8] = g4; \
        *(half8*)&sb[b_][w * 6 + 5][lane * 8] = g5; \
        *(half8*)&sb[b_][24 + w][lane * 8] = g6; }

#define STEP(s_) { \
        const half8 af0 = *(const half8*)&sb[cur][(s_) * 6 + 0][lane * 8]; \
        const half8 af1 = *(const half8*)&sb[cur][(s_) * 6 + 1][lane * 8]; \
        const half8 af2 = *(const half8*)&sb[cur][(s_) * 6 + 2][lane * 8]; \
        const half8 af3 = *(const half8*)&sb[cur][(s_) * 6 + 3][lane * 8]; \
        const half8 kq0 = *(const half8*)&sb[cur][(s_) * 6 + 4][lane * 8]; \
        const half8 kq1 = *(const half8*)&sb[cur][(s_) * 6 + 5][lane * 8]; \
        _Pragma("unroll") \
        for (int c = 0; c < 4; c++) { \
            const half8 vq = *(const half8*)&sb[cur][24 + w][((s_) * 4 + c) * 32 + quad * 8]; \
            const half8 b0 = kq0 * vq; \
            const half8 b1 = kq1 * vq; \
            acc[0][2 * c]     = __builtin_amdgcn_mfma_f32_16x16x32_f16(af0, b0, acc[0][2 * c],     0, 0, 0); \
            acc[0][2 * c + 1] = __builtin_amdgcn_mfma_f32_16x16x32_f16(af0, b1, acc[0][2 * c + 1], 0, 0, 0); \
            acc[1][2 * c]     = __builtin_amdgcn_mfma_f32_16x16x32_f16(af1, b0, acc[1][2 * c],     0, 0, 0); \
            acc[1][2 * c + 1] = __builtin_amdgcn_mfma_f32_16x16x32_f16(af1, b1, acc[1][2 * c + 1], 0, 0, 0); \
            acc[2][2 * c]     = __builtin_amdgcn_mfma_f32_16x16x32_f16(af2, b0, acc[2][2 * c],     0, 0, 0); \
            acc[2][2 * c + 1] = __builtin_amdgcn_mfma_f32_16x16x32_f16(af2, b1, acc[2][2 * c + 1], 0, 0, 0); \
            acc[3][2 * c]     = __builtin_amdgcn_mfma_f32_16x16x32_f16(af3, b0, acc[3][2 * c],     0, 0, 0); \
            acc[3][2 * c + 1] = __builtin_amdgcn_mfma_f32_16x16x32_f16(af3, b1, acc[3][2 * c + 1], 0, 0, 0); \
        } }

    int cur = 0;
    GATHER(0)
    DSWRITE(0)
    __syncthreads();
#pragma unroll 1
    for (int r = 0; r < 16; ++r) {
        if (r < 15) GATHER((r + 1) * 128)
        STEP(0)
        STEP(1)
        STEP(2)
        STEP(3)
        if (r < 15) DSWRITE(cur ^ 1)
        __syncthreads();
        cur ^= 1;
    }

#undef GATHER
#undef DSWRITE
#undef STEP

    // epilogue: C fragment -> M16[kkut][h][col]
#pragma unroll
    for (int rt = 0; rt < 4; rt++)
#pragma unroll
        for (int c = 0; c < 4; c++)
#pragma unroll
            for (int half = 0; half < 2; half++)
#pragma unroll
                for (int r = 0; r < 4; r++) {
                    const int row = r0 + rt * 16 + quad * 4 + r;
                    const int col = cb + c * 32 + half * 16 + l15;
                    M16[((size_t)row * 8 + h) * 4608 + col] = (_Float16)acc[rt][c * 2 + half][r];
                }
}

// MG[kt][h][ct*512 + quad*128 + l15*8 + j] (f16, fragment-ordered)
//   = sum_l M16[kt][h][(c*9+l)*32+d] * G[kk,h,u][l*9+m], cm=ct*16+l15, d=quad*8+j
// R22: vectorized LDS path. Old inner loop did 9 scalar 4B ds_reads per output
// (41.5K scalar wave-instrs/block; ~20us of LDS issue serialization across
// 3200 blocks at ~5.8cy/instr). New: M16 slab staged as f16 with 40-half row
// stride (16B-aligned octets, <=2-way bank aliasing = free); each thread
// computes one half8 output octet with 9 ds_read_b128 -> 8x fewer LDS instrs.
// f32 accumulation unchanged; M16 was already f16, so results bit-identical.
__global__ __launch_bounds__(256) void fold_k(const _Float16* __restrict__ Mv, const float* __restrict__ G,
                                              _Float16* __restrict__ MG) {
    const int kt = blockIdx.x, h = blockIdx.y;
    const int tid = threadIdx.x;
    __shared__ __align__(16) _Float16 ms16[144 * 40];   // [cl][d], stride 40 halves (80 B)
    __shared__ float gs[81];
    const _Float16* src = Mv + ((size_t)kt * 8 + h) * 4608;
    // stage: 576 half8 octets; octet o covers src[o*8 .. o*8+7], cl = o>>2, d0 = (o&3)*8
    for (int o = tid; o < 576; o += 256) {
        const half8 v = *(const half8*)(src + o * 8);
        *(half8*)&ms16[(o >> 2) * 40 + (o & 3) * 8] = v;
    }
    const int kk = kt / 50, u = (kt >> 1) % 25;
    if (tid < 81) gs[tid] = G[(((size_t)kk * 8 + h) * 25 + u) * 81 + tid];
    __syncthreads();
    _Float16* dst = MG + ((size_t)kt * 8 + h) * 4608;
    for (int o = tid; o < 576; o += 256) {
        const int i0 = o * 8;
        const int ct = i0 >> 9, quad = (i0 >> 7) & 3, l15 = (i0 >> 3) & 15;
        const int d0 = quad * 8;
        const int cm = ct * 16 + l15, c = cm / 9, m = cm - c * 9;
        float s0 = 0.f, s1 = 0.f, s2 = 0.f, s3 = 0.f, s4 = 0.f, s5 = 0.f, s6 = 0.f, s7 = 0.f;
#pragma unroll
        for (int l = 0; l < 9; l++) {
            const float g = gs[l * 9 + m];
            const half8 mv = *(const half8*)&ms16[(c * 9 + l) * 40 + d0];
            s0 += (float)mv[0] * g; s1 += (float)mv[1] * g;
            s2 += (float)mv[2] * g; s3 += (float)mv[3] * g;
            s4 += (float)mv[4] * g; s5 += (float)mv[5] * g;
            s6 += (float)mv[6] * g; s7 += (float)mv[7] * g;
        }
        half8 hv;
        hv[0] = (_Float16)s0; hv[1] = (_Float16)s1; hv[2] = (_Float16)s2; hv[3] = (_Float16)s3;
        hv[4] = (_Float16)s4; hv[5] = (_Float16)s5; hv[6] = (_Float16)s6; hv[7] = (_Float16)s7;
        *(half8*)(dst + i0) = hv;
    }
}

// local stage via MFMA (R20 config, unchanged):
// R15 geometry (32 rows/wave, 4 slices x 100kt, 2 blk/CU, 4-kt rounds) +
// f16 partial writes + rz applied here in f32 before the single f16 rounding.
// grid (8, 4, 16) = 512 blocks = 2/CU; LDS 73.7KB dbuf.
__global__ __launch_bounds__(256, 2) void mm_local_k(const float* __restrict__ qf, const _Float16* __restrict__ trigA,
                                                     const _Float16* __restrict__ MG, const float* __restrict__ rZ,
                                                     _Float16* __restrict__ outp) {
    const int combo = blockIdx.y * 8 + blockIdx.x;
    const int h = combo >> 2;
    const int slice = combo & 3;
    const int n0 = blockIdx.z * 128;
    const int tid = threadIdx.x;
    const int w = tid >> 6, lane = tid & 63;
    const int l15 = lane & 15, quad = lane >> 4;

    // staging sb[2][4][4608] f16 (73728B), overlaid later by epilogue eb (37888B)
    __shared__ __align__(16) unsigned char smem_raw[73728];
    _Float16 (*sb)[4][4608] = (_Float16 (*)[4][4608])smem_raw;

    const int nbase = n0 + w * 32;                      // 32 rows per wave
    half8 qfr16[2];
#pragma unroll
    for (int rt = 0; rt < 2; rt++) {
        const int n = nbase + rt * 16 + l15;
        const float* qp = qf + (size_t)n * 256 + h * 32 + quad * 8;
#pragma unroll
        for (int j = 0; j < 8; j++) qfr16[rt][j] = (_Float16)qp[j];
    }
    float4v acc[2][9];
#pragma unroll
    for (int rt = 0; rt < 2; rt++)
#pragma unroll
        for (int ct = 0; ct < 9; ct++) acc[rt][ct] = float4v{0.f, 0.f, 0.f, 0.f};

    const int kt0 = slice * 100;
    // per-lane staging source: lane*8 halves = quad*128 + l15*8 (the read offset)
    const _Float16* mg0 = MG + (((size_t)kt0 * 8 + h) * 4608) + lane * 8;
    // trig scalars: trigA[nb5][kt][rt*16+l15] (all 32 rows in slab nbase>>5)
    const _Float16* trg0 = trigA + (size_t)(nbase >> 5) * 16384 + (size_t)kt0 * 32 + l15;

    // wave w stages kt = base_ + w of this round: 9 x global_load_lds_dwordx4
#define STAGE4(b_, base_) { \
        const _Float16* src = mg0 + (size_t)((base_) + w) * 8 * 4608; \
        _Float16* dstl = &sb[b_][w][0]; \
        _Pragma("unroll") \
        for (int i = 0; i < 9; i++) \
            __builtin_amdgcn_global_load_lds( \
                (const __attribute__((address_space(1))) void*)(src + i * 512), \
                (__attribute__((address_space(3))) void*)(dstl + i * 512), 16, 0, 0); }

#define COMPUTE(kl) { \
        half8 tv0, tv1; \
        _Pragma("unroll") \
        for (int j = 0; j < 8; j++) { tv0[j] = ta[kl]; tv1[j] = tb[kl]; } \
        const half8 af0 = tv0 * qfr16[0]; \
        const half8 af1 = tv1 * qfr16[1]; \
        _Pragma("unroll") \
        for (int ct = 0; ct < 9; ct++) { \
            const half8 b = *(const half8*)&sb[cur][kl][ct * 512 + quad * 128 + l15 * 8]; \
            acc[0][ct] = __builtin_amdgcn_mfma_f32_16x16x32_f16(af0, b, acc[0][ct], 0, 0, 0); \
            acc[1][ct] = __builtin_amdgcn_mfma_f32_16x16x32_f16(af1, b, acc[1][ct], 0, 0, 0); \
        } }

    _Float16 ta[4], tb[4], ua[4], ub[4];
    int cur = 0;
    STAGE4(0, 0)
#pragma unroll
    for (int kl = 0; kl < 4; kl++) { ta[kl] = trg0[kl * 32]; tb[kl] = trg0[kl * 32 + 16]; }
    __syncthreads();

#pragma unroll 1
    for (int r = 0; r < 25; ++r) {
        if (r < 24) {
            STAGE4(cur ^ 1, (r + 1) * 4)
#pragma unroll
            for (int kl = 0; kl < 4; kl++) {
                const size_t o = (size_t)((r + 1) * 4 + kl) * 32;
                ua[kl] = trg0[o]; ub[kl] = trg0[o + 16];
            }
        }
        COMPUTE(0) COMPUTE(1) COMPUTE(2) COMPUTE(3)
        __syncthreads();
        cur ^= 1;
#pragma unroll
        for (int kl = 0; kl < 4; kl++) { ta[kl] = ua[kl]; tb[kl] = ub[kl]; }
    }

#undef STAGE4
#undef COMPUTE

    // epilogue: LDS transpose -> coalesced f16 stores into outp[slice][n][m][h*16+c]
    // rz[n][h] applied here (f32, before the single f16 rounding).
    // eb overlaid on sb (dead; 37888B <= 73728B)
    float* ebp = (float*)smem_raw;
    _Float16* dst = outp + (size_t)slice * 2359296;
    const int g4 = lane >> 2, sub = lane & 3;
#pragma unroll
    for (int rt = 0; rt < 2; rt++) {
        __syncthreads();
#pragma unroll
        for (int ct = 0; ct < 9; ct++) {
            const int cm = ct * 16 + l15;
            const int c = cm / 9, m = cm - c * 9;
#pragma unroll
            for (int r = 0; r < 4; r++)
                ebp[(size_t)(w * 16 + quad * 4 + r) * 148 + m * 16 + c] = acc[rt][ct][r];
        }
        __syncthreads();
#pragma unroll
        for (int s = 0; s < 9; s++) {
            const int li = s * 16 + g4;            // 0..143 line index
            const int nl = li / 9, m = li - nl * 9;
            const float4 v4 = *(const float4*)&ebp[(size_t)(w * 16 + nl) * 148 + m * 16 + sub * 4];
            const int n = nbase + rt * 16 + nl;
            const float rzv = rZ[(size_t)n * 8 + h];
            half4v hv;
            hv[0] = (_Float16)(v4.x * rzv); hv[1] = (_Float16)(v4.y * rzv);
            hv[2] = (_Float16)(v4.z * rzv); hv[3] = (_Float16)(v4.w * rzv);
            *(half4v*)&dst[((size_t)n * 9 + m) * 128 + h * 16 + sub * 4] = hv;
        }
    }
}

// ================================ launcher =================================
extern "C" void kernel_launch(void* const* d_in, const int* in_sizes, int n_in,
                              void* d_out, int out_size, void* d_ws, size_t ws_size,
                              hipStream_t stream) {
    const float* pos  = (const float*)d_in[0];
    const float* feat = (const float*)d_in[1];
    const float* Wq   = (const float*)d_in[2];
    const float* Wk   = (const float*)d_in[3];
    const float* Wv   = (const float*)d_in[4];
    const float* Wo   = (const float*)d_in[5];
    const float* a    = (const float*)d_in[6];
    const float* kap  = (const float*)d_in[7];
    float* out = (float*)d_out;
    float* ws = (float*)d_ws;

    // float-slot layout (~77.8 MB total)
    float* qf    = ws;                    // 524288
    float* kfAF  = qf + 524288;           // 262144 slots = kfA f16[8][64][2][512]
    float* vTF   = kfAF + 262144;         // 1179648 slots = v16T f16[1152*2048]
    float* trigF = vTF + 1179648;         // 524288 slots = trigA f16[64][512][32]
    float* ksum  = trigF + 524288;        // 256
    float* rz    = ksum + 256;            // 16384
    float* G     = rz + 16384;            // 129600
    float* M16F  = G + 129600;            // 9437184 slots = M16 f16[512*8*4608]; later outp f16[4][2359296]
    float* regX  = M16F + 9437184;        // 7372800 slots: R (first 1572864), later MG f16[400*8*4608]
    float* R     = regX;
    _Float16* trigA = (_Float16*)trigF;
    _Float16* kfA   = (_Float16*)kfAF;
    _Float16* v16T  = (_Float16*)vTF;
    _Float16* M16   = (_Float16*)M16F;
    _Float16* MG16  = (_Float16*)regX;
    _Float16* outp16 = (_Float16*)M16F;   // overlay: M16 dead after fold_k; 4 f16 partial buffers

    const float* cst = d_const_g;

    hipLaunchKernelGGL(radial_k, dim3(2048), dim3(256), 0, stream, feat, R);
    hipLaunchKernelGGL(qk_gemm_k, dim3(8, 32), dim3(256), 0, stream, R, Wq, Wk, qf, kfA);
    hipLaunchKernelGGL(mfma_gemm16_k, dim3(2, 288), dim3(256), 0, stream, feat, Wv, vTF, 18432, 128, 256, 2, rz);
    hipLaunchKernelGGL(trig_k, dim3(2048), dim3(256), 0, stream, pos, kap, cst, trigA);
    hipLaunchKernelGGL(ksumT_k, dim3(256), dim3(256), 0, stream, kfA, ksum);
    hipLaunchKernelGGL(zg_k, dim3(128), dim3(256), 0, stream, qf, ksum, rz, a, cst, G);
    hipLaunchKernelGGL(multipole_mm_k, dim3(8, 9, 7), dim3(256), 0, stream, trigA, kfA, v16T, M16);
    hipLaunchKernelGGL(fold_k, dim3(400, 8), dim3(256), 0, stream, M16, G, MG16);
    hipLaunchKernelGGL(mm_local_k, dim3(8, 4, 16), dim3(256), 0, stream, qf, trigA, MG16, rz, outp16);
    hipLaunchKernelGGL(mfma_gemm16_k, dim3(4, 288), dim3(256), 0, stream, (const float*)outp16, Wo, out, 18432, 256, 128, 4, rz);
}

// Round 10
// 287.776 us; speedup vs baseline: 1.1999x; 1.0182x over previous
//
#include <hip/hip_runtime.h>
#include <cmath>
#include <complex>
#include <algorithm>

// ---------------------------------------------------------------------------
// Problem constants: LMAX=2, NC=9, H=8, DQK=32, CV=16, K=8, U=25, N=2048, C=256
// ---------------------------------------------------------------------------

typedef _Float16 half8 __attribute__((ext_vector_type(8)));
typedef _Float16 half4v __attribute__((ext_vector_type(4)));
typedef float float4v __attribute__((ext_vector_type(4)));

// ========================= host-side constant tables ========================
namespace {

using cd = std::complex<double>;

static double fct(int n) { double r = 1.0; for (int i = 2; i <= n; ++i) r *= i; return r; }

static double cg_coef(int j1, int m1, int j2, int m2, int j, int m) {
    if (m1 + m2 != m || j < std::abs(j1 - j2) || j > j1 + j2) return 0.0;
    double pref = std::sqrt((2 * j + 1) * fct(j + j1 - j2) * fct(j - j1 + j2) * fct(j1 + j2 - j) / fct(j1 + j2 + j + 1));
    pref *= std::sqrt(fct(j + m) * fct(j - m) * fct(j1 - m1) * fct(j1 + m1) * fct(j2 - m2) * fct(j2 + m2));
    double s = 0.0;
    for (int k = 0; k <= j1 + j2 - j; ++k) {
        int d0 = k, d1 = j1 + j2 - j - k, d2 = j1 - m1 - k, d3 = j2 + m2 - k, d4 = j - j2 + m1 + k, d5 = j - j1 - m2 + k;
        if (d0 < 0 || d1 < 0 || d2 < 0 || d3 < 0 || d4 < 0 || d5 < 0) continue;
        s += ((k & 1) ? -1.0 : 1.0) / (fct(d0) * fct(d1) * fct(d2) * fct(d3) * fct(d4) * fct(d5));
    }
    return pref * s;
}

static void umat(int l, cd u[5][5]) {
    for (int i = 0; i < 5; i++) for (int j = 0; j < 5; j++) u[i][j] = cd(0, 0);
    const double s = 1.0 / std::sqrt(2.0);
    for (int m = -l; m <= l; m++) {
        double sgn = (std::abs(m) & 1) ? -1.0 : 1.0;   // (-1)^m
        if (m > 0)      { u[l + m][l + m] = cd(sgn * s, 0); u[l + m][l - m] = cd(s, 0); }
        else if (m == 0){ u[l][l] = cd(1, 0); }
        else            { u[l + m][l + m] = cd(0, s);       u[l + m][l - m] = cd(0, -sgn * s); }
    }
}

static void real_cg_f(int l1, int l2, int L, double out[5][5][5]) {
    cd U1[5][5], U2[5][5], UL[5][5];
    umat(l1, U1); umat(l2, U2); umat(L, UL);
    const int n1 = 2 * l1 + 1, n2 = 2 * l2 + 1, n3 = 2 * L + 1;
    double cgt[5][5][5];
    for (int i1 = 0; i1 < n1; i1++) for (int i2 = 0; i2 < n2; i2++) for (int i3 = 0; i3 < n3; i3++)
        cgt[i1][i2][i3] = cg_coef(l1, i1 - l1, l2, i2 - l2, L, i3 - L);
    cd r[5][5][5];
    double nr = 0, ni = 0;
    for (int a1 = 0; a1 < n1; a1++) for (int b = 0; b < n2; b++) for (int c = 0; c < n3; c++) {
        cd acc(0, 0);
        for (int uu = 0; uu < n1; uu++) for (int vv = 0; vv < n2; vv++) for (int w = 0; w < n3; w++) {
            double cval = cgt[uu][vv][w];
            if (cval == 0.0) continue;
            acc += U1[a1][uu] * U2[b][vv] * std::conj(UL[c][w]) * cval;
        }
        r[a1][b][c] = acc;
        nr += acc.real() * acc.real();
        ni += acc.imag() * acc.imag();
    }
    const bool useRe = std::sqrt(nr) >= std::sqrt(ni);
    for (int a1 = 0; a1 < n1; a1++) for (int b = 0; b < n2; b++) for (int c = 0; c < n3; c++)
        out[a1][b][c] = useRe ? r[a1][b][c].real() : r[a1][b][c].imag();
}

// device constant buffer layout: YW[9*25] | RRED[9*81] | DIRS[25*3]  = 1029 floats
static float  h_const[1029];
static float* d_const_g = nullptr;

struct GlobalInit {
    GlobalInit() {
        const double PI = 3.14159265358979323846;
        const double gx[5] = {-0.9061798459386640, -0.5384693101056831, 0.0, 0.5384693101056831, 0.9061798459386640};
        const double gw[5] = { 0.23692688505618908, 0.47862867049936647, 0.5688888888888889, 0.47862867049936647, 0.23692688505618908};
        double YW[9][25], DIRS[25][3];
        for (int u = 0; u < 25; ++u) {
            const int it = u / 5, ip = u % 5;
            const double ct = gx[it], wq = gw[it] * (2.0 * PI / 5.0), ph = 2.0 * PI * ip / 5.0;
            const double st = std::sqrt(std::max(1.0 - ct * ct, 0.0));
            const double x = st * std::cos(ph), y = st * std::sin(ph), z = ct;
            DIRS[u][0] = x; DIRS[u][1] = y; DIRS[u][2] = z;
            double Y[9];
            Y[0] = 0.282095;           Y[1] = 0.488603 * y;      Y[2] = 0.488603 * z;
            Y[3] = 0.488603 * x;       Y[4] = 1.092548 * x * y;  Y[5] = 1.092548 * y * z;
            Y[6] = 0.315392 * (3 * z * z - 1); Y[7] = 1.092548 * x * z; Y[8] = 0.546274 * (x * x - y * y);
            for (int e = 0; e < 9; e++) YW[e][u] = Y[e] * wq;
        }
        double RRED[9][9][9];
        for (int i = 0; i < 9; i++) for (int j = 0; j < 9; j++) for (int k = 0; k < 9; k++) RRED[i][j][k] = 0.0;
        const int off[3] = {0, 1, 4};
        double cnt[3] = {0, 0, 0};
        double rc[5][5][5];
        for (int l1 = 0; l1 <= 2; l1++) for (int l2 = 0; l2 <= 2; l2++) {
            const int Llo = std::abs(l1 - l2), Lhi = std::min(l1 + l2, 2);
            for (int L = Llo; L <= Lhi; L++) {
                real_cg_f(l1, l2, L, rc);
                for (int i1 = 0; i1 < 2 * l1 + 1; i1++)
                    for (int i2 = 0; i2 < 2 * l2 + 1; i2++)
                        for (int i3 = 0; i3 < 2 * L + 1; i3++)
                            RRED[off[l1] + i1][off[l2] + i2][off[L] + i3] += rc[i1][i2][i3];
                cnt[L] += 1.0;
            }
        }
        for (int L = 0; L <= 2; L++) {
            const double dv = std::max(cnt[L], 1.0);
            for (int a1 = 0; a1 < 9; a1++) for (int b = 0; b < 9; b++)
                for (int k = 0; k < 2 * L + 1; k++) RRED[a1][b][off[L] + k] /= dv;
        }
        for (int e = 0; e < 9; e++) for (int u = 0; u < 25; u++) h_const[e * 25 + u] = (float)YW[e][u];
        for (int e = 0; e < 9; e++) for (int l = 0; l < 9; l++) for (int m = 0; m < 9; m++)
            h_const[225 + e * 81 + l * 9 + m] = (float)RRED[e][l][m];
        for (int u = 0; u < 25; u++) for (int ax = 0; ax < 3; ax++) h_const[954 + u * 3 + ax] = (float)DIRS[u][ax];
        if (hipMalloc((void**)&d_const_g, 1029 * sizeof(float)) == hipSuccess)
            hipMemcpy(d_const_g, h_const, 1029 * sizeof(float), hipMemcpyHostToDevice);
    }
} g_init;

} // namespace

// ============================== device kernels ==============================

// merged radial + trig (R23: two independent elementwise phases, one launch):
// phase 1 (all 256 thr): R[n][p][c] = {feat(l0), |l1 block|, |l2 block|}
// phase 2 (thr<200): trigA[nb5][kkut][j] = cos/sin(kappa_kk * pos_n . dir_u);
//         thr 200..255 zero pad rows 400..511. No sync needed (disjoint data).
__global__ void radtrig_k(const float* __restrict__ feat, const float* __restrict__ pos,
                          const float* __restrict__ kappa, const float* __restrict__ cst,
                          float* __restrict__ R, _Float16* __restrict__ trigA) {
    const int n = blockIdx.x, t = threadIdx.x;
    {
        const float* f = feat + (size_t)n * 9 * 256 + t;
        const float f0 = f[0];
        const float a1 = f[256], a2 = f[512], a3 = f[768];
        const float b1 = f[1024], b2 = f[1280], b3 = f[1536], b4 = f[1792], b5 = f[2048];
        const float r1 = sqrtf(a1 * a1 + a2 * a2 + a3 * a3 + 1e-8f);
        const float r2 = sqrtf(b1 * b1 + b2 * b2 + b3 * b3 + b4 * b4 + b5 * b5 + 1e-8f);
        float* o = R + (size_t)n * 768 + t;
        o[0] = f0; o[256] = r1; o[512] = r2;
    }
    const size_t base = (size_t)(n >> 5) * 16384 + (n & 31);
    if (t < 200) {
        const int kq = t / 25, u = t - kq * 25;
        const float* dirs = cst + 954;
        const float ph = kappa[kq] * (pos[n * 3] * dirs[u * 3] + pos[n * 3 + 1] * dirs[u * 3 + 1] + pos[n * 3 + 2] * dirs[u * 3 + 2]);
        float s, c;
        sincosf(ph, &s, &c);
        const int kkut = (kq * 25 + u) * 2;
        trigA[base + (size_t)kkut * 32] = (_Float16)c;
        trigA[base + (size_t)(kkut + 1) * 32] = (_Float16)s;
    } else {
        const int kkut = 400 + (t - 200) * 2;
        trigA[base + (size_t)kkut * 32] = (_Float16)0.f;
        trigA[base + (size_t)(kkut + 1) * 32] = (_Float16)0.f;
    }
}

// fused Q/K projection GEMM (f16 MFMA): A = R (2048x768), B = Wq or Wk (768x256)
// grid (8, 32): x<4 -> Wq cols (cb=x*64), epilogue elu+1 -> qf row-major f32
//               x>=4 -> Wk cols (cb=(x-4)*64), epilogue elu+1 -> kfA frag f16
__global__ __launch_bounds__(256) void qk_gemm_k(const float* __restrict__ A,
                                                 const float* __restrict__ Wq,
                                                 const float* __restrict__ Wk,
                                                 float* __restrict__ qf,
                                                 _Float16* __restrict__ kfA) {
    __shared__ __align__(16) _Float16 Af[64 * 40];
    __shared__ __align__(16) _Float16 Bf[64 * 40];
    const int tid = threadIdx.x;
    const int w = tid >> 6, lane = tid & 63;
    const int l15 = lane & 15, quad = lane >> 4;
    const bool isK = blockIdx.x >= 4;
    const int cb = (blockIdx.x & 3) * 64;
    const int rb = blockIdx.y * 64;
    const float* B = isK ? Wk : Wq;
    const int N = 256, Kd = 768;
    const int sr = tid >> 2, sq = tid & 3;

    float4v acc[4];
#pragma unroll
    for (int s = 0; s < 4; s++) acc[s] = float4v{0.f, 0.f, 0.f, 0.f};

    for (int k0 = 0; k0 < Kd; k0 += 32) {
        __syncthreads();
        {
            const float* Ap = A + (size_t)(rb + sr) * Kd + k0 + sq * 8;
            const float4 a0 = *(const float4*)(Ap);
            const float4 a1 = *(const float4*)(Ap + 4);
            half8 hv;
            hv[0] = (_Float16)a0.x; hv[1] = (_Float16)a0.y; hv[2] = (_Float16)a0.z; hv[3] = (_Float16)a0.w;
            hv[4] = (_Float16)a1.x; hv[5] = (_Float16)a1.y; hv[6] = (_Float16)a1.z; hv[7] = (_Float16)a1.w;
            *(half8*)&Af[sr * 40 + sq * 8] = hv;
        }
        {
            const float* Bp = B + (size_t)(k0 + sq * 8) * N + cb + sr;
            half8 hv;
#pragma unroll
            for (int i = 0; i < 8; i++) hv[i] = (_Float16)Bp[(size_t)i * N];
            *(half8*)&Bf[sr * 40 + sq * 8] = hv;
        }
        __syncthreads();
        const half8 af = *(const half8*)&Af[(w * 16 + l15) * 40 + quad * 8];
#pragma unroll
        for (int s = 0; s < 4; s++) {
            const half8 bf = *(const half8*)&Bf[(s * 16 + l15) * 40 + quad * 8];
            acc[s] = __builtin_amdgcn_mfma_f32_16x16x32_f16(af, bf, acc[s], 0, 0, 0);
        }
    }
#pragma unroll
    for (int s = 0; s < 4; s++) {
#pragma unroll
        for (int r = 0; r < 4; r++) {
            const int row = rb + w * 16 + quad * 4 + r;
            const int col = cb + s * 16 + l15;
            float val = acc[s][r];
            val = (val > 0.f ? val : expf(val) - 1.f) + 1.f;
            if (isK) {
                const int hh = col >> 5, dd = col & 31, tt = dd >> 4, ll = dd & 15;
                kfA[(size_t)hh * 65536 + (size_t)(row >> 5) * 1024 + tt * 512 + ll * 32 + (row & 31)] = (_Float16)val;
            } else {
                qf[(size_t)row * 256 + col] = val;
            }
        }
    }
}

// f16 MFMA GEMM, C = A(MxK) @ B(KxN), M%64==0, N%64==0, K%32==0.
// mode 2: A f32, v16T f16 scatter (the only remaining user).
__global__ __launch_bounds__(256) void mfma_gemm16_k(const float* __restrict__ A, const float* __restrict__ B,
                                                     float* __restrict__ Cv, int M, int N, int Kd, int mode,
                                                     const float* __restrict__ rZ) {
    __shared__ __align__(16) _Float16 Af[64 * 40];   // [row][k], stride 40 halves (80 B)
    __shared__ __align__(16) _Float16 Bf[64 * 40];   // [col][k]
    const int tid = threadIdx.x;
    const int w = tid >> 6, lane = tid & 63;
    const int l15 = lane & 15, quad = lane >> 4;
    const int rb = blockIdx.y * 64, cb = blockIdx.x * 64;
    const int sr = tid >> 2, sq = tid & 3;           // stager: row/col 0..63, k-quartet 0..3

    float4v acc[4];
#pragma unroll
    for (int s = 0; s < 4; s++) acc[s] = float4v{0.f, 0.f, 0.f, 0.f};

    for (int k0 = 0; k0 < Kd; k0 += 32) {
        __syncthreads();
        // ---- stage A (f32 -> f16, fragment order) ----
        {
            const float* Ap = A + (size_t)(rb + sr) * Kd + k0 + sq * 8;
            const float4 a0 = *(const float4*)(Ap);
            const float4 a1 = *(const float4*)(Ap + 4);
            half8 hv;
            hv[0] = (_Float16)a0.x; hv[1] = (_Float16)a0.y; hv[2] = (_Float16)a0.z; hv[3] = (_Float16)a0.w;
            hv[4] = (_Float16)a1.x; hv[5] = (_Float16)a1.y; hv[6] = (_Float16)a1.z; hv[7] = (_Float16)a1.w;
            *(half8*)&Af[sr * 40 + sq * 8] = hv;
        }
        // ---- stage B (column gather; f32 -> f16) ----
        {
            const float* Bp = B + (size_t)(k0 + sq * 8) * N + cb + sr;
            half8 hv;
#pragma unroll
            for (int i = 0; i < 8; i++) hv[i] = (_Float16)Bp[(size_t)i * N];
            *(half8*)&Bf[sr * 40 + sq * 8] = hv;
        }
        __syncthreads();
        // ---- fragments + MFMA ----
        const half8 af = *(const half8*)&Af[(w * 16 + l15) * 40 + quad * 8];
#pragma unroll
        for (int s = 0; s < 4; s++) {
            const half8 bf = *(const half8*)&Bf[(s * 16 + l15) * 40 + quad * 8];
            acc[s] = __builtin_amdgcn_mfma_f32_16x16x32_f16(af, bf, acc[s], 0, 0, 0);
        }
    }
    // ---- epilogue: C fragment (row = rb+w*16+quad*4+r, col = cb+s*16+l15) ----
#pragma unroll
    for (int s = 0; s < 4; s++) {
#pragma unroll
        for (int r = 0; r < 4; r++) {
            const int row = rb + w * 16 + quad * 4 + r;
            const int col = cb + s * 16 + l15;
            float val = acc[s][r];
            if (mode == 2) {
                // v16T[(h*144 + c*9 + l)][n] f16
                const int n = row / 9, l = row - n * 9, hq = col >> 4, cvq = col & 15;
                _Float16* o = (_Float16*)Cv;
                o[((size_t)hq * 144 + cvq * 9 + l) * 2048 + n] = (_Float16)val;
            } else {
                Cv[(size_t)row * N + col] = val;
            }
        }
    }
}

// out-GEMM (R23: dedicated, N-tile 128): C = (sum of 4 f16 partials)(18432x128) @ Wo(128x256)
// R20's grid (4,288) N-tile 64 re-gathered each A slab (4x16B streams) 4x.
// N-tile 128 halves the passes and the block count: grid (2,288) = 576 blocks
// = 2.25/CU. acc[8] (32 VGPR). rz already applied in mm_local. f32 C row-major.
__global__ __launch_bounds__(256) void outg_k(const _Float16* __restrict__ A, const float* __restrict__ B,
                                              float* __restrict__ Cv) {
    __shared__ __align__(16) _Float16 Af[64 * 40];    // [row][k]
    __shared__ __align__(16) _Float16 Bf[128 * 40];   // [col][k]
    const int tid = threadIdx.x;
    const int w = tid >> 6, lane = tid & 63;
    const int l15 = lane & 15, quad = lane >> 4;
    const int rb = blockIdx.y * 64, cb = blockIdx.x * 128;
    const int sr = tid >> 2, sq = tid & 3;            // stager: row/col 0..63, k-quartet 0..3
    const int N = 256, Kd = 128;

    float4v acc[8];
#pragma unroll
    for (int s = 0; s < 8; s++) acc[s] = float4v{0.f, 0.f, 0.f, 0.f};

    for (int k0 = 0; k0 < Kd; k0 += 32) {
        __syncthreads();
        // ---- stage A: 4-partial f32 sum -> f16 ----
        {
            const _Float16* Ap16 = A + (size_t)(rb + sr) * Kd + k0 + sq * 8;
            const half8 p0 = *(const half8*)(Ap16);
            const half8 p1 = *(const half8*)(Ap16 + 2359296);
            const half8 p2 = *(const half8*)(Ap16 + 4718592);
            const half8 p3 = *(const half8*)(Ap16 + 7077888);
            half8 hv;
#pragma unroll
            for (int i = 0; i < 8; i++)
                hv[i] = (_Float16)((float)p0[i] + (float)p1[i] + (float)p2[i] + (float)p3[i]);
            *(half8*)&Af[sr * 40 + sq * 8] = hv;
        }
        // ---- stage B: 128 cols (two passes of 64) ----
#pragma unroll
        for (int hf = 0; hf < 2; hf++) {
            const float* Bp = B + (size_t)(k0 + sq * 8) * N + cb + hf * 64 + sr;
            half8 hv;
#pragma unroll
            for (int i = 0; i < 8; i++) hv[i] = (_Float16)Bp[(size_t)i * N];
            *(half8*)&Bf[(hf * 64 + sr) * 40 + sq * 8] = hv;
        }
        __syncthreads();
        const half8 af = *(const half8*)&Af[(w * 16 + l15) * 40 + quad * 8];
#pragma unroll
        for (int s = 0; s < 8; s++) {
            const half8 bf = *(const half8*)&Bf[(s * 16 + l15) * 40 + quad * 8];
            acc[s] = __builtin_amdgcn_mfma_f32_16x16x32_f16(af, bf, acc[s], 0, 0, 0);
        }
    }
    // ---- epilogue: plain f32 C ----
#pragma unroll
    for (int s = 0; s < 8; s++) {
#pragma unroll
        for (int r = 0; r < 4; r++) {
            const int row = rb + w * 16 + quad * 4 + r;
            const int col = cb + s * 16 + l15;
            Cv[(size_t)row * N + col] = acc[s][r];
        }
    }
}

// ksum[h*32+d] = sum_n kfA[h][nb5][t][l15][j]; one block per (h,d)
__global__ void ksumT_k(const _Float16* __restrict__ kfA, float* __restrict__ ksum) {
    const int b = blockIdx.x;                       // h*32+d
    const int h = b >> 5, d = b & 31, t = d >> 4, l15 = d & 15;
    const int i = threadIdx.x;                      // 256
    const half8 v = *(const half8*)(kfA + (size_t)h * 65536 + (size_t)(i >> 2) * 1024 + t * 512 + l15 * 32 + (i & 3) * 8);
    float s = 0.f;
#pragma unroll
    for (int k = 0; k < 8; k++) s += (float)v[k];
#pragma unroll
    for (int off = 32; off > 0; off >>= 1) s += __shfl_down(s, off, 64);
    __shared__ float red[4];
    if ((i & 63) == 0) red[i >> 6] = s;
    __syncthreads();
    if (i == 0) ksum[b] = red[0] + red[1] + red[2] + red[3];
}

// merged z + g (block-range dispatch, 128 blocks):
//   blocks 0..63:  rz[n][h] = 1 / (qf[n,h,:].ksum[h,:] + 1e-6)
//   blocks 64..127: G[kk][h][u][l*9+m] = sum_e aE[e,h,kk]*YW[e,u]*RRED[e,l,m]
__global__ void zg_k(const float* __restrict__ qf, const float* __restrict__ ksum, float* __restrict__ rz,
                     const float* __restrict__ a, const float* __restrict__ cst, float* __restrict__ G) {
    if (blockIdx.x < 64) {
        const int idx = blockIdx.x * 256 + threadIdx.x;   // N*H = 16384
        const int n = idx >> 3, h = idx & 7;
        float s = 0.f;
#pragma unroll
        for (int d = 0; d < 32; d++) s += qf[(size_t)n * 256 + h * 32 + d] * ksum[h * 32 + d];
        rz[idx] = 1.0f / (s + 1e-6f);
    } else {
        const int b = blockIdx.x - 64;
        const int kk = b & 7, h = b >> 3;
        __shared__ float ae[9];
        if (threadIdx.x < 9) {
            const int ldeg[9] = {0, 1, 1, 1, 2, 2, 2, 2, 2};
            ae[threadIdx.x] = a[ldeg[threadIdx.x] * 64 + h * 8 + kk];
        }
        __syncthreads();
        const float* yw = cst;
        const float* rred = cst + 225;
        for (int i = threadIdx.x; i < 25 * 81; i += 256) {
            const int u = i / 81, lm = i - u * 81;
            float s = 0.f;
#pragma unroll
            for (int e = 0; e < 9; e++) s += ae[e] * yw[e * 25 + u] * rred[e * 81 + lm];
            G[((size_t)(kk * 8 + h) * 25 + u) * 81 + lm] = s;
        }
    }
}

// MFMA multipole (R21: 64 rows/wave):
//   M16[kkut][h][cl*32+d] = sum_n trigA * kfA * v16T
// Verified R21: 64 rows/wave (4 row-tiles) made the kernel MFMA-bound; total
// -25us, multipole out of top-5. Grid (8 h, 9 colgroups, 7 rowquads) = 504
// blocks ~2/CU; LDS 56KB dbuf; gridDim.x==8 keeps h->XCD affinity (R12).
__global__ __launch_bounds__(256, 2) void multipole_mm_k(const _Float16* __restrict__ trigA,
                                                         const _Float16* __restrict__ kfA,
                                                         const _Float16* __restrict__ v16T,
                                                         _Float16* __restrict__ M16) {
    const int h   = blockIdx.x;
    const int tid = threadIdx.x;
    const int w = tid >> 6, lane = tid & 63;
    const int l15 = lane & 15, quad = lane >> 4;
    const int cb  = blockIdx.y * 512 + w * 128;   // 4 cl per wave -> 128 cols
    const int cl0 = cb >> 5;
    const int r0  = blockIdx.z * 64;              // rows (kkut), 7*64 = 448

    // LDS: [buf][unit][512 halves]; step s units s*6+{0..3:af0-3, 4:kq0, 5:kq1};
    // unit 24+w = wave-private vq slab (4 steps x 4 c x 32 n).
    __shared__ __align__(16) _Float16 sb[2][28][512];   // 56 KB

    float4v acc[4][8];
#pragma unroll
    for (int rt = 0; rt < 4; rt++)
#pragma unroll
        for (int s = 0; s < 8; s++) acc[rt][s] = float4v{0.f, 0.f, 0.f, 0.f};

    // gather bases: this wave stages step s==w of each round (nb = nbr + w*32)
    const _Float16* afg0 = trigA + (size_t)(r0 + l15) * 32 + quad * 8;            // + nb5*16384; +512/row-tile
    const _Float16* kqg0 = kfA + (size_t)h * 65536 + (size_t)l15 * 32 + quad * 8; // + nb5*1024
    const _Float16* kqg1 = kqg0 + 512;
    const int vs = lane >> 4, vc = (lane >> 2) & 3, vg = lane & 3;                // vq gather decomp
    const _Float16* vqg = v16T + (size_t)(h * 144 + cl0 + vc) * 2048 + vs * 32 + vg * 8; // + nbr

    half8 g0, g1, g2, g3, g4, g5, g6;

#define GATHER(nbr_) { \
        const size_t t5 = (size_t)((nbr_) >> 5) + w; \
        g0 = *(const half8*)(afg0 + t5 * 16384); \
        g1 = *(const half8*)(afg0 + t5 * 16384 + 512); \
        g2 = *(const half8*)(afg0 + t5 * 16384 + 1024); \
        g3 = *(const half8*)(afg0 + t5 * 16384 + 1536); \
        g4 = *(const half8*)(kqg0 + t5 * 1024); \
        g5 = *(const half8*)(kqg1 + t5 * 1024); \
        g6 = *(const half8*)(vqg + (nbr_)); }

#define DSWRITE(b_) { \
        *(half8*)&sb[b_][w * 6 + 0][lane * 8] = g0; \
        *(half8*)&sb[b_][w * 6 + 1][lane * 8] = g1; \
        *(half8*)&sb[b_][w * 6 + 2][lane * 8] = g2; \
        *(half8*)&sb[b_][w * 6 + 3][lane * 8] = g3; \
        *(half8*)&sb[b_][w * 6 + 4][lane * 8] = g4; \
        *(half8*)&sb[b_][w * 6 + 5][lane * 8] = g5; \
        *(half8*)&sb[b_][24 + w][lane * 8] = g6; }

#define STEP(s_) { \
        const half8 af0 = *(const half8*)&sb[cur][(s_) * 6 + 0][lane * 8]; \
        const half8 af1 = *(const half8*)&sb[cur][(s_) * 6 + 1][lane * 8]; \
        const half8 af2 = *(const half8*)&sb[cur][(s_) * 6 + 2][lane * 8]; \
        const half8 af3 = *(const half8*)&sb[cur][(s_) * 6 + 3][lane * 8]; \
        const half8 kq0 = *(const half8*)&sb[cur][(s_) * 6 + 4][lane * 8]; \
        const half8 kq1 = *(const half8*)&sb[cur][(s_) * 6 + 5][lane * 8]; \
        _Pragma("unroll") \
        for (int c = 0; c < 4; c++) { \
            const half8 vq = *(const half8*)&sb[cur][24 + w][((s_) * 4 + c) * 32 + quad * 8]; \
            const half8 b0 = kq0 * vq; \
            const half8 b1 = kq1 * vq; \
            acc[0][2 * c]     = __builtin_amdgcn_mfma_f32_16x16x32_f16(af0, b0, acc[0][2 * c],     0, 0, 0); \
            acc[0][2 * c + 1] = __builtin_amdgcn_mfma_f32_16x16x32_f16(af0, b1, acc[0][2 * c + 1], 0, 0, 0); \
            acc[1][2 * c]     = __builtin_amdgcn_mfma_f32_16x16x32_f16(af1, b0, acc[1][2 * c],     0, 0, 0); \
            acc[1][2 * c + 1] = __builtin_amdgcn_mfma_f32_16x16x32_f16(af1, b1, acc[1][2 * c + 1], 0, 0, 0); \
            acc[2][2 * c]     = __builtin_amdgcn_mfma_f32_16x16x32_f16(af2, b0, acc[2][2 * c],     0, 0, 0); \
            acc[2][2 * c + 1] = __builtin_amdgcn_mfma_f32_16x16x32_f16(af2, b1, acc[2][2 * c + 1], 0, 0, 0); \
            acc[3][2 * c]     = __builtin_amdgcn_mfma_f32_16x16x32_f16(af3, b0, acc[3][2 * c],     0, 0, 0); \
            acc[3][2 * c + 1] = __builtin_amdgcn_mfma_f32_16x16x32_f16(af3, b1, acc[3][2 * c + 1], 0, 0, 0); \
        } }

    int cur = 0;
    GATHER(0)
    DSWRITE(0)
    __syncthreads();
#pragma unroll 1
    for (int r = 0; r < 16; ++r) {
        if (r < 15) GATHER((r + 1) * 128)
        STEP(0)
        STEP(1)
        STEP(2)
        STEP(3)
        if (r < 15) DSWRITE(cur ^ 1)
        __syncthreads();
        cur ^= 1;
    }

#undef GATHER
#undef DSWRITE
#undef STEP

    // epilogue: C fragment -> M16[kkut][h][col]
#pragma unroll
    for (int rt = 0; rt < 4; rt++)
#pragma unroll
        for (int c = 0; c < 4; c++)
#pragma unroll
            for (int half = 0; half < 2; half++)
#pragma unroll
                for (int r = 0; r < 4; r++) {
                    const int row = r0 + rt * 16 + quad * 4 + r;
                    const int col = cb + c * 32 + half * 16 + l15;
                    M16[((size_t)row * 8 + h) * 4608 + col] = (_Float16)acc[rt][c * 2 + half][r];
                }
}

// MG[kt][h][ct*512 + quad*128 + l15*8 + j] (f16, fragment-ordered)
//   = sum_l M16[kt][h][(c*9+l)*32+d] * G[kk,h,u][l*9+m], cm=ct*16+l15, d=quad*8+j
// R22 (verified, -7us): vectorized LDS path, 9 ds_read_b128 per half8 octet.
__global__ __launch_bounds__(256) void fold_k(const _Float16* __restrict__ Mv, const float* __restrict__ G,
                                              _Float16* __restrict__ MG) {
    const int kt = blockIdx.x, h = blockIdx.y;
    const int tid = threadIdx.x;
    __shared__ __align__(16) _Float16 ms16[144 * 40];   // [cl][d], stride 40 halves (80 B)
    __shared__ float gs[81];
    const _Float16* src = Mv + ((size_t)kt * 8 + h) * 4608;
    // stage: 576 half8 octets; octet o covers src[o*8 .. o*8+7], cl = o>>2, d0 = (o&3)*8
    for (int o = tid; o < 576; o += 256) {
        const half8 v = *(const half8*)(src + o * 8);
        *(half8*)&ms16[(o >> 2) * 40 + (o & 3) * 8] = v;
    }
    const int kk = kt / 50, u = (kt >> 1) % 25;
    if (tid < 81) gs[tid] = G[(((size_t)kk * 8 + h) * 25 + u) * 81 + tid];
    __syncthreads();
    _Float16* dst = MG + ((size_t)kt * 8 + h) * 4608;
    for (int o = tid; o < 576; o += 256) {
        const int i0 = o * 8;
        const int ct = i0 >> 9, quad = (i0 >> 7) & 3, l15 = (i0 >> 3) & 15;
        const int d0 = quad * 8;
        const int cm = ct * 16 + l15, c = cm / 9, m = cm - c * 9;
        float s0 = 0.f, s1 = 0.f, s2 = 0.f, s3 = 0.f, s4 = 0.f, s5 = 0.f, s6 = 0.f, s7 = 0.f;
#pragma unroll
        for (int l = 0; l < 9; l++) {
            const float g = gs[l * 9 + m];
            const half8 mv = *(const half8*)&ms16[(c * 9 + l) * 40 + d0];
            s0 += (float)mv[0] * g; s1 += (float)mv[1] * g;
            s2 += (float)mv[2] * g; s3 += (float)mv[3] * g;
            s4 += (float)mv[4] * g; s5 += (float)mv[5] * g;
            s6 += (float)mv[6] * g; s7 += (float)mv[7] * g;
        }
        half8 hv;
        hv[0] = (_Float16)s0; hv[1] = (_Float16)s1; hv[2] = (_Float16)s2; hv[3] = (_Float16)s3;
        hv[4] = (_Float16)s4; hv[5] = (_Float16)s5; hv[6] = (_Float16)s6; hv[7] = (_Float16)s7;
        *(half8*)(dst + i0) = hv;
    }
}

// local stage via MFMA (R20 config, unchanged):
// R15 geometry (32 rows/wave, 4 slices x 100kt, 2 blk/CU, 4-kt rounds) +
// f16 partial writes + rz applied here in f32 before the single f16 rounding.
// grid (8, 4, 16) = 512 blocks = 2/CU; LDS 73.7KB dbuf.
__global__ __launch_bounds__(256, 2) void mm_local_k(const float* __restrict__ qf, const _Float16* __restrict__ trigA,
                                                     const _Float16* __restrict__ MG, const float* __restrict__ rZ,
                                                     _Float16* __restrict__ outp) {
    const int combo = blockIdx.y * 8 + blockIdx.x;
    const int h = combo >> 2;
    const int slice = combo & 3;
    const int n0 = blockIdx.z * 128;
    const int tid = threadIdx.x;
    const int w = tid >> 6, lane = tid & 63;
    const int l15 = lane & 15, quad = lane >> 4;

    // staging sb[2][4][4608] f16 (73728B), overlaid later by epilogue eb (37888B)
    __shared__ __align__(16) unsigned char smem_raw[73728];
    _Float16 (*sb)[4][4608] = (_Float16 (*)[4][4608])smem_raw;

    const int nbase = n0 + w * 32;                      // 32 rows per wave
    half8 qfr16[2];
#pragma unroll
    for (int rt = 0; rt < 2; rt++) {
        const int n = nbase + rt * 16 + l15;
        const float* qp = qf + (size_t)n * 256 + h * 32 + quad * 8;
#pragma unroll
        for (int j = 0; j < 8; j++) qfr16[rt][j] = (_Float16)qp[j];
    }
    float4v acc[2][9];
#pragma unroll
    for (int rt = 0; rt < 2; rt++)
#pragma unroll
        for (int ct = 0; ct < 9; ct++) acc[rt][ct] = float4v{0.f, 0.f, 0.f, 0.f};

    const int kt0 = slice * 100;
    // per-lane staging source: lane*8 halves = quad*128 + l15*8 (the read offset)
    const _Float16* mg0 = MG + (((size_t)kt0 * 8 + h) * 4608) + lane * 8;
    // trig scalars: trigA[nb5][kt][rt*16+l15] (all 32 rows in slab nbase>>5)
    const _Float16* trg0 = trigA + (size_t)(nbase >> 5) * 16384 + (size_t)kt0 * 32 + l15;

    // wave w stages kt = base_ + w of this round: 9 x global_load_lds_dwordx4
#define STAGE4(b_, base_) { \
        const _Float16* src = mg0 + (size_t)((base_) + w) * 8 * 4608; \
        _Float16* dstl = &sb[b_][w][0]; \
        _Pragma("unroll") \
        for (int i = 0; i < 9; i++) \
            __builtin_amdgcn_global_load_lds( \
                (const __attribute__((address_space(1))) void*)(src + i * 512), \
                (__attribute__((address_space(3))) void*)(dstl + i * 512), 16, 0, 0); }

#define COMPUTE(kl) { \
        half8 tv0, tv1; \
        _Pragma("unroll") \
        for (int j = 0; j < 8; j++) { tv0[j] = ta[kl]; tv1[j] = tb[kl]; } \
        const half8 af0 = tv0 * qfr16[0]; \
        const half8 af1 = tv1 * qfr16[1]; \
        _Pragma("unroll") \
        for (int ct = 0; ct < 9; ct++) { \
            const half8 b = *(const half8*)&sb[cur][kl][ct * 512 + quad * 128 + l15 * 8]; \
            acc[0][ct] = __builtin_amdgcn_mfma_f32_16x16x32_f16(af0, b, acc[0][ct], 0, 0, 0); \
            acc[1][ct] = __builtin_amdgcn_mfma_f32_16x16x32_f16(af1, b, acc[1][ct], 0, 0, 0); \
        } }

    _Float16 ta[4], tb[4], ua[4], ub[4];
    int cur = 0;
    STAGE4(0, 0)
#pragma unroll
    for (int kl = 0; kl < 4; kl++) { ta[kl] = trg0[kl * 32]; tb[kl] = trg0[kl * 32 + 16]; }
    __syncthreads();

#pragma unroll 1
    for (int r = 0; r < 25; ++r) {
        if (r < 24) {
            STAGE4(cur ^ 1, (r + 1) * 4)
#pragma unroll
            for (int kl = 0; kl < 4; kl++) {
                const size_t o = (size_t)((r + 1) * 4 + kl) * 32;
                ua[kl] = trg0[o]; ub[kl] = trg0[o + 16];
            }
        }
        COMPUTE(0) COMPUTE(1) COMPUTE(2) COMPUTE(3)
        __syncthreads();
        cur ^= 1;
#pragma unroll
        for (int kl = 0; kl < 4; kl++) { ta[kl] = ua[kl]; tb[kl] = ub[kl]; }
    }

#undef STAGE4
#undef COMPUTE

    // epilogue: LDS transpose -> coalesced f16 stores into outp[slice][n][m][h*16+c]
    // rz[n][h] applied here (f32, before the single f16 rounding).
    // eb overlaid on sb (dead; 37888B <= 73728B)
    float* ebp = (float*)smem_raw;
    _Float16* dst = outp + (size_t)slice * 2359296;
    const int g4 = lane >> 2, sub = lane & 3;
#pragma unroll
    for (int rt = 0; rt < 2; rt++) {
        __syncthreads();
#pragma unroll
        for (int ct = 0; ct < 9; ct++) {
            const int cm = ct * 16 + l15;
            const int c = cm / 9, m = cm - c * 9;
#pragma unroll
            for (int r = 0; r < 4; r++)
                ebp[(size_t)(w * 16 + quad * 4 + r) * 148 + m * 16 + c] = acc[rt][ct][r];
        }
        __syncthreads();
#pragma unroll
        for (int s = 0; s < 9; s++) {
            const int li = s * 16 + g4;            // 0..143 line index
            const int nl = li / 9, m = li - nl * 9;
            const float4 v4 = *(const float4*)&ebp[(size_t)(w * 16 + nl) * 148 + m * 16 + sub * 4];
            const int n = nbase + rt * 16 + nl;
            const float rzv = rZ[(size_t)n * 8 + h];
            half4v hv;
            hv[0] = (_Float16)(v4.x * rzv); hv[1] = (_Float16)(v4.y * rzv);
            hv[2] = (_Float16)(v4.z * rzv); hv[3] = (_Float16)(v4.w * rzv);
            *(half4v*)&dst[((size_t)n * 9 + m) * 128 + h * 16 + sub * 4] = hv;
        }
    }
}

// ================================ launcher =================================
extern "C" void kernel_launch(void* const* d_in, const int* in_sizes, int n_in,
                              void* d_out, int out_size, void* d_ws, size_t ws_size,
                              hipStream_t stream) {
    const float* pos  = (const float*)d_in[0];
    const float* feat = (const float*)d_in[1];
    const float* Wq   = (const float*)d_in[2];
    const float* Wk   = (const float*)d_in[3];
    const float* Wv   = (const float*)d_in[4];
    const float* Wo   = (const float*)d_in[5];
    const float* a    = (const float*)d_in[6];
    const float* kap  = (const float*)d_in[7];
    float* out = (float*)d_out;
    float* ws = (float*)d_ws;

    // float-slot layout (~77.8 MB total)
    float* qf    = ws;                    // 524288
    float* kfAF  = qf + 524288;           // 262144 slots = kfA f16[8][64][2][512]
    float* vTF   = kfAF + 262144;         // 1179648 slots = v16T f16[1152*2048]
    float* trigF = vTF + 1179648;         // 524288 slots = trigA f16[64][512][32]
    float* ksum  = trigF + 524288;        // 256
    float* rz    = ksum + 256;            // 16384
    float* G     = rz + 16384;            // 129600
    float* M16F  = G + 129600;            // 9437184 slots = M16 f16[512*8*4608]; later outp f16[4][2359296]
    float* regX  = M16F + 9437184;        // 7372800 slots: R (first 1572864), later MG f16[400*8*4608]
    float* R     = regX;
    _Float16* trigA = (_Float16*)trigF;
    _Float16* kfA   = (_Float16*)kfAF;
    _Float16* v16T  = (_Float16*)vTF;
    _Float16* M16   = (_Float16*)M16F;
    _Float16* MG16  = (_Float16*)regX;
    _Float16* outp16 = (_Float16*)M16F;   // overlay: M16 dead after fold_k; 4 f16 partial buffers

    const float* cst = d_const_g;

    hipLaunchKernelGGL(radtrig_k, dim3(2048), dim3(256), 0, stream, feat, pos, kap, cst, R, trigA);
    hipLaunchKernelGGL(qk_gemm_k, dim3(8, 32), dim3(256), 0, stream, R, Wq, Wk, qf, kfA);
    hipLaunchKernelGGL(mfma_gemm16_k, dim3(2, 288), dim3(256), 0, stream, feat, Wv, vTF, 18432, 128, 256, 2, rz);
    hipLaunchKernelGGL(ksumT_k, dim3(256), dim3(256), 0, stream, kfA, ksum);
    hipLaunchKernelGGL(zg_k, dim3(128), dim3(256), 0, stream, qf, ksum, rz, a, cst, G);
    hipLaunchKernelGGL(multipole_mm_k, dim3(8, 9, 7), dim3(256), 0, stream, trigA, kfA, v16T, M16);
    hipLaunchKernelGGL(fold_k, dim3(400, 8), dim3(256), 0, stream, M16, G, MG16);
    hipLaunchKernelGGL(mm_local_k, dim3(8, 4, 16), dim3(256), 0, stream, qf, trigA, MG16, rz, outp16);
    hipLaunchKernelGGL(outg_k, dim3(2, 288), dim3(256), 0, stream, outp16, Wo, out);
}

// Round 11
// 284.158 us; speedup vs baseline: 1.2152x; 1.0127x over previous
//
#include <hip/hip_runtime.h>
#include <cmath>
#include <complex>
#include <algorithm>

// ---------------------------------------------------------------------------
// Problem constants: LMAX=2, NC=9, H=8, DQK=32, CV=16, K=8, U=25, N=2048, C=256
// ---------------------------------------------------------------------------

typedef _Float16 half8 __attribute__((ext_vector_type(8)));
typedef _Float16 half4v __attribute__((ext_vector_type(4)));
typedef float float4v __attribute__((ext_vector_type(4)));

// ========================= host-side constant tables ========================
namespace {

using cd = std::complex<double>;

static double fct(int n) { double r = 1.0; for (int i = 2; i <= n; ++i) r *= i; return r; }

static double cg_coef(int j1, int m1, int j2, int m2, int j, int m) {
    if (m1 + m2 != m || j < std::abs(j1 - j2) || j > j1 + j2) return 0.0;
    double pref = std::sqrt((2 * j + 1) * fct(j + j1 - j2) * fct(j - j1 + j2) * fct(j1 + j2 - j) / fct(j1 + j2 + j + 1));
    pref *= std::sqrt(fct(j + m) * fct(j - m) * fct(j1 - m1) * fct(j1 + m1) * fct(j2 - m2) * fct(j2 + m2));
    double s = 0.0;
    for (int k = 0; k <= j1 + j2 - j; ++k) {
        int d0 = k, d1 = j1 + j2 - j - k, d2 = j1 - m1 - k, d3 = j2 + m2 - k, d4 = j - j2 + m1 + k, d5 = j - j1 - m2 + k;
        if (d0 < 0 || d1 < 0 || d2 < 0 || d3 < 0 || d4 < 0 || d5 < 0) continue;
        s += ((k & 1) ? -1.0 : 1.0) / (fct(d0) * fct(d1) * fct(d2) * fct(d3) * fct(d4) * fct(d5));
    }
    return pref * s;
}

static void umat(int l, cd u[5][5]) {
    for (int i = 0; i < 5; i++) for (int j = 0; j < 5; j++) u[i][j] = cd(0, 0);
    const double s = 1.0 / std::sqrt(2.0);
    for (int m = -l; m <= l; m++) {
        double sgn = (std::abs(m) & 1) ? -1.0 : 1.0;   // (-1)^m
        if (m > 0)      { u[l + m][l + m] = cd(sgn * s, 0); u[l + m][l - m] = cd(s, 0); }
        else if (m == 0){ u[l][l] = cd(1, 0); }
        else            { u[l + m][l + m] = cd(0, s);       u[l + m][l - m] = cd(0, -sgn * s); }
    }
}

static void real_cg_f(int l1, int l2, int L, double out[5][5][5]) {
    cd U1[5][5], U2[5][5], UL[5][5];
    umat(l1, U1); umat(l2, U2); umat(L, UL);
    const int n1 = 2 * l1 + 1, n2 = 2 * l2 + 1, n3 = 2 * L + 1;
    double cgt[5][5][5];
    for (int i1 = 0; i1 < n1; i1++) for (int i2 = 0; i2 < n2; i2++) for (int i3 = 0; i3 < n3; i3++)
        cgt[i1][i2][i3] = cg_coef(l1, i1 - l1, l2, i2 - l2, L, i3 - L);
    cd r[5][5][5];
    double nr = 0, ni = 0;
    for (int a1 = 0; a1 < n1; a1++) for (int b = 0; b < n2; b++) for (int c = 0; c < n3; c++) {
        cd acc(0, 0);
        for (int uu = 0; uu < n1; uu++) for (int vv = 0; vv < n2; vv++) for (int w = 0; w < n3; w++) {
            double cval = cgt[uu][vv][w];
            if (cval == 0.0) continue;
            acc += U1[a1][uu] * U2[b][vv] * std::conj(UL[c][w]) * cval;
        }
        r[a1][b][c] = acc;
        nr += acc.real() * acc.real();
        ni += acc.imag() * acc.imag();
    }
    const bool useRe = std::sqrt(nr) >= std::sqrt(ni);
    for (int a1 = 0; a1 < n1; a1++) for (int b = 0; b < n2; b++) for (int c = 0; c < n3; c++)
        out[a1][b][c] = useRe ? r[a1][b][c].real() : r[a1][b][c].imag();
}

// device constant buffer layout: YW[9*25] | RRED[9*81] | DIRS[25*3]  = 1029 floats
static float  h_const[1029];
static float* d_const_g = nullptr;

struct GlobalInit {
    GlobalInit() {
        const double PI = 3.14159265358979323846;
        const double gx[5] = {-0.9061798459386640, -0.5384693101056831, 0.0, 0.5384693101056831, 0.9061798459386640};
        const double gw[5] = { 0.23692688505618908, 0.47862867049936647, 0.5688888888888889, 0.47862867049936647, 0.23692688505618908};
        double YW[9][25], DIRS[25][3];
        for (int u = 0; u < 25; ++u) {
            const int it = u / 5, ip = u % 5;
            const double ct = gx[it], wq = gw[it] * (2.0 * PI / 5.0), ph = 2.0 * PI * ip / 5.0;
            const double st = std::sqrt(std::max(1.0 - ct * ct, 0.0));
            const double x = st * std::cos(ph), y = st * std::sin(ph), z = ct;
            DIRS[u][0] = x; DIRS[u][1] = y; DIRS[u][2] = z;
            double Y[9];
            Y[0] = 0.282095;           Y[1] = 0.488603 * y;      Y[2] = 0.488603 * z;
            Y[3] = 0.488603 * x;       Y[4] = 1.092548 * x * y;  Y[5] = 1.092548 * y * z;
            Y[6] = 0.315392 * (3 * z * z - 1); Y[7] = 1.092548 * x * z; Y[8] = 0.546274 * (x * x - y * y);
            for (int e = 0; e < 9; e++) YW[e][u] = Y[e] * wq;
        }
        double RRED[9][9][9];
        for (int i = 0; i < 9; i++) for (int j = 0; j < 9; j++) for (int k = 0; k < 9; k++) RRED[i][j][k] = 0.0;
        const int off[3] = {0, 1, 4};
        double cnt[3] = {0, 0, 0};
        double rc[5][5][5];
        for (int l1 = 0; l1 <= 2; l1++) for (int l2 = 0; l2 <= 2; l2++) {
            const int Llo = std::abs(l1 - l2), Lhi = std::min(l1 + l2, 2);
            for (int L = Llo; L <= Lhi; L++) {
                real_cg_f(l1, l2, L, rc);
                for (int i1 = 0; i1 < 2 * l1 + 1; i1++)
                    for (int i2 = 0; i2 < 2 * l2 + 1; i2++)
                        for (int i3 = 0; i3 < 2 * L + 1; i3++)
                            RRED[off[l1] + i1][off[l2] + i2][off[L] + i3] += rc[i1][i2][i3];
                cnt[L] += 1.0;
            }
        }
        for (int L = 0; L <= 2; L++) {
            const double dv = std::max(cnt[L], 1.0);
            for (int a1 = 0; a1 < 9; a1++) for (int b = 0; b < 9; b++)
                for (int k = 0; k < 2 * L + 1; k++) RRED[a1][b][off[L] + k] /= dv;
        }
        for (int e = 0; e < 9; e++) for (int u = 0; u < 25; u++) h_const[e * 25 + u] = (float)YW[e][u];
        for (int e = 0; e < 9; e++) for (int l = 0; l < 9; l++) for (int m = 0; m < 9; m++)
            h_const[225 + e * 81 + l * 9 + m] = (float)RRED[e][l][m];
        for (int u = 0; u < 25; u++) for (int ax = 0; ax < 3; ax++) h_const[954 + u * 3 + ax] = (float)DIRS[u][ax];
        if (hipMalloc((void**)&d_const_g, 1029 * sizeof(float)) == hipSuccess)
            hipMemcpy(d_const_g, h_const, 1029 * sizeof(float), hipMemcpyHostToDevice);
    }
} g_init;

} // namespace

// ============================== device kernels ==============================

// merged radial + trig (R23, verified):
__global__ void radtrig_k(const float* __restrict__ feat, const float* __restrict__ pos,
                          const float* __restrict__ kappa, const float* __restrict__ cst,
                          float* __restrict__ R, _Float16* __restrict__ trigA) {
    const int n = blockIdx.x, t = threadIdx.x;
    {
        const float* f = feat + (size_t)n * 9 * 256 + t;
        const float f0 = f[0];
        const float a1 = f[256], a2 = f[512], a3 = f[768];
        const float b1 = f[1024], b2 = f[1280], b3 = f[1536], b4 = f[1792], b5 = f[2048];
        const float r1 = sqrtf(a1 * a1 + a2 * a2 + a3 * a3 + 1e-8f);
        const float r2 = sqrtf(b1 * b1 + b2 * b2 + b3 * b3 + b4 * b4 + b5 * b5 + 1e-8f);
        float* o = R + (size_t)n * 768 + t;
        o[0] = f0; o[256] = r1; o[512] = r2;
    }
    const size_t base = (size_t)(n >> 5) * 16384 + (n & 31);
    if (t < 200) {
        const int kq = t / 25, u = t - kq * 25;
        const float* dirs = cst + 954;
        const float ph = kappa[kq] * (pos[n * 3] * dirs[u * 3] + pos[n * 3 + 1] * dirs[u * 3 + 1] + pos[n * 3 + 2] * dirs[u * 3 + 2]);
        float s, c;
        sincosf(ph, &s, &c);
        const int kkut = (kq * 25 + u) * 2;
        trigA[base + (size_t)kkut * 32] = (_Float16)c;
        trigA[base + (size_t)(kkut + 1) * 32] = (_Float16)s;
    } else {
        const int kkut = 400 + (t - 200) * 2;
        trigA[base + (size_t)kkut * 32] = (_Float16)0.f;
        trigA[base + (size_t)(kkut + 1) * 32] = (_Float16)0.f;
    }
}

// fused Q/K projection GEMM (R24: 2 blocks/CU):
// Old grid (8,32) = 256 blocks = 1 block/CU -> every per-iter barrier drain
// exposed on a lockstep block (the R16 failure mode, 24 K-iterations).
// R24 splits the row tile 64 -> 32: grid (8,64) = 512 blocks = 2/CU so one
// block's barrier drain overlaps the other's compute (mechanism verified in
// R15/R17/R21). Wave layout: w&1 = 16-row half, w>>1 = 32-col half; acc[2].
// x<4 -> Wq (qf f32 out), x>=4 -> Wk (kfA frag f16 out); epilogue elu+1.
__global__ __launch_bounds__(256) void qk_gemm_k(const float* __restrict__ A,
                                                 const float* __restrict__ Wq,
                                                 const float* __restrict__ Wk,
                                                 float* __restrict__ qf,
                                                 _Float16* __restrict__ kfA) {
    __shared__ __align__(16) _Float16 Af[32 * 40];
    __shared__ __align__(16) _Float16 Bf[64 * 40];
    const int tid = threadIdx.x;
    const int w = tid >> 6, lane = tid & 63;
    const int l15 = lane & 15, quad = lane >> 4;
    const int rh = w & 1, ch = w >> 1;
    const bool isK = blockIdx.x >= 4;
    const int cb = (blockIdx.x & 3) * 64;
    const int rb = blockIdx.y * 32;
    const float* B = isK ? Wk : Wq;
    const int N = 256, Kd = 768;
    const int sra = tid >> 3, sqa = tid & 7;   // A stager: 32 rows x 8 k-quads
    const int srb = tid >> 2, sqb = tid & 3;   // B stager: 64 cols x 4 k-octets

    float4v acc[2];
    acc[0] = float4v{0.f, 0.f, 0.f, 0.f};
    acc[1] = float4v{0.f, 0.f, 0.f, 0.f};

    for (int k0 = 0; k0 < Kd; k0 += 32) {
        __syncthreads();
        {
            const float* Ap = A + (size_t)(rb + sra) * Kd + k0 + sqa * 4;
            const float4 a0 = *(const float4*)(Ap);
            half4v hv;
            hv[0] = (_Float16)a0.x; hv[1] = (_Float16)a0.y; hv[2] = (_Float16)a0.z; hv[3] = (_Float16)a0.w;
            *(half4v*)&Af[sra * 40 + sqa * 4] = hv;
        }
        {
            const float* Bp = B + (size_t)(k0 + sqb * 8) * N + cb + srb;
            half8 hv;
#pragma unroll
            for (int i = 0; i < 8; i++) hv[i] = (_Float16)Bp[(size_t)i * N];
            *(half8*)&Bf[srb * 40 + sqb * 8] = hv;
        }
        __syncthreads();
        const half8 af = *(const half8*)&Af[(rh * 16 + l15) * 40 + quad * 8];
#pragma unroll
        for (int s = 0; s < 2; s++) {
            const half8 bf = *(const half8*)&Bf[(ch * 32 + s * 16 + l15) * 40 + quad * 8];
            acc[s] = __builtin_amdgcn_mfma_f32_16x16x32_f16(af, bf, acc[s], 0, 0, 0);
        }
    }
#pragma unroll
    for (int s = 0; s < 2; s++) {
#pragma unroll
        for (int r = 0; r < 4; r++) {
            const int row = rb + rh * 16 + quad * 4 + r;
            const int col = cb + ch * 32 + s * 16 + l15;
            float val = acc[s][r];
            val = (val > 0.f ? val : expf(val) - 1.f) + 1.f;
            if (isK) {
                const int hh = col >> 5, dd = col & 31, tt = dd >> 4, ll = dd & 15;
                kfA[(size_t)hh * 65536 + (size_t)(row >> 5) * 1024 + tt * 512 + ll * 32 + (row & 31)] = (_Float16)val;
            } else {
                qf[(size_t)row * 256 + col] = val;
            }
        }
    }
}

// f16 MFMA GEMM, C = A(MxK) @ B(KxN); mode 2: v16T f16 scatter (only user).
__global__ __launch_bounds__(256) void mfma_gemm16_k(const float* __restrict__ A, const float* __restrict__ B,
                                                     float* __restrict__ Cv, int M, int N, int Kd, int mode,
                                                     const float* __restrict__ rZ) {
    __shared__ __align__(16) _Float16 Af[64 * 40];   // [row][k], stride 40 halves (80 B)
    __shared__ __align__(16) _Float16 Bf[64 * 40];   // [col][k]
    const int tid = threadIdx.x;
    const int w = tid >> 6, lane = tid & 63;
    const int l15 = lane & 15, quad = lane >> 4;
    const int rb = blockIdx.y * 64, cb = blockIdx.x * 64;
    const int sr = tid >> 2, sq = tid & 3;           // stager: row/col 0..63, k-quartet 0..3

    float4v acc[4];
#pragma unroll
    for (int s = 0; s < 4; s++) acc[s] = float4v{0.f, 0.f, 0.f, 0.f};

    for (int k0 = 0; k0 < Kd; k0 += 32) {
        __syncthreads();
        // ---- stage A (f32 -> f16, fragment order) ----
        {
            const float* Ap = A + (size_t)(rb + sr) * Kd + k0 + sq * 8;
            const float4 a0 = *(const float4*)(Ap);
            const float4 a1 = *(const float4*)(Ap + 4);
            half8 hv;
            hv[0] = (_Float16)a0.x; hv[1] = (_Float16)a0.y; hv[2] = (_Float16)a0.z; hv[3] = (_Float16)a0.w;
            hv[4] = (_Float16)a1.x; hv[5] = (_Float16)a1.y; hv[6] = (_Float16)a1.z; hv[7] = (_Float16)a1.w;
            *(half8*)&Af[sr * 40 + sq * 8] = hv;
        }
        // ---- stage B (column gather; f32 -> f16) ----
        {
            const float* Bp = B + (size_t)(k0 + sq * 8) * N + cb + sr;
            half8 hv;
#pragma unroll
            for (int i = 0; i < 8; i++) hv[i] = (_Float16)Bp[(size_t)i * N];
            *(half8*)&Bf[sr * 40 + sq * 8] = hv;
        }
        __syncthreads();
        // ---- fragments + MFMA ----
        const half8 af = *(const half8*)&Af[(w * 16 + l15) * 40 + quad * 8];
#pragma unroll
        for (int s = 0; s < 4; s++) {
            const half8 bf = *(const half8*)&Bf[(s * 16 + l15) * 40 + quad * 8];
            acc[s] = __builtin_amdgcn_mfma_f32_16x16x32_f16(af, bf, acc[s], 0, 0, 0);
        }
    }
    // ---- epilogue: C fragment (row = rb+w*16+quad*4+r, col = cb+s*16+l15) ----
#pragma unroll
    for (int s = 0; s < 4; s++) {
#pragma unroll
        for (int r = 0; r < 4; r++) {
            const int row = rb + w * 16 + quad * 4 + r;
            const int col = cb + s * 16 + l15;
            float val = acc[s][r];
            if (mode == 2) {
                // v16T[(h*144 + c*9 + l)][n] f16
                const int n = row / 9, l = row - n * 9, hq = col >> 4, cvq = col & 15;
                _Float16* o = (_Float16*)Cv;
                o[((size_t)hq * 144 + cvq * 9 + l) * 2048 + n] = (_Float16)val;
            } else {
                Cv[(size_t)row * N + col] = val;
            }
        }
    }
}

// out-GEMM (R23, verified): C = (sum of 4 f16 partials)(18432x128) @ Wo(128x256)
// N-tile 128, grid (2,288) = 576 blocks = 2.25/CU.
__global__ __launch_bounds__(256) void outg_k(const _Float16* __restrict__ A, const float* __restrict__ B,
                                              float* __restrict__ Cv) {
    __shared__ __align__(16) _Float16 Af[64 * 40];    // [row][k]
    __shared__ __align__(16) _Float16 Bf[128 * 40];   // [col][k]
    const int tid = threadIdx.x;
    const int w = tid >> 6, lane = tid & 63;
    const int l15 = lane & 15, quad = lane >> 4;
    const int rb = blockIdx.y * 64, cb = blockIdx.x * 128;
    const int sr = tid >> 2, sq = tid & 3;            // stager: row/col 0..63, k-quartet 0..3
    const int N = 256, Kd = 128;

    float4v acc[8];
#pragma unroll
    for (int s = 0; s < 8; s++) acc[s] = float4v{0.f, 0.f, 0.f, 0.f};

    for (int k0 = 0; k0 < Kd; k0 += 32) {
        __syncthreads();
        // ---- stage A: 4-partial f32 sum -> f16 ----
        {
            const _Float16* Ap16 = A + (size_t)(rb + sr) * Kd + k0 + sq * 8;
            const half8 p0 = *(const half8*)(Ap16);
            const half8 p1 = *(const half8*)(Ap16 + 2359296);
            const half8 p2 = *(const half8*)(Ap16 + 4718592);
            const half8 p3 = *(const half8*)(Ap16 + 7077888);
            half8 hv;
#pragma unroll
            for (int i = 0; i < 8; i++)
                hv[i] = (_Float16)((float)p0[i] + (float)p1[i] + (float)p2[i] + (float)p3[i]);
            *(half8*)&Af[sr * 40 + sq * 8] = hv;
        }
        // ---- stage B: 128 cols (two passes of 64) ----
#pragma unroll
        for (int hf = 0; hf < 2; hf++) {
            const float* Bp = B + (size_t)(k0 + sq * 8) * N + cb + hf * 64 + sr;
            half8 hv;
#pragma unroll
            for (int i = 0; i < 8; i++) hv[i] = (_Float16)Bp[(size_t)i * N];
            *(half8*)&Bf[(hf * 64 + sr) * 40 + sq * 8] = hv;
        }
        __syncthreads();
        const half8 af = *(const half8*)&Af[(w * 16 + l15) * 40 + quad * 8];
#pragma unroll
        for (int s = 0; s < 8; s++) {
            const half8 bf = *(const half8*)&Bf[(s * 16 + l15) * 40 + quad * 8];
            acc[s] = __builtin_amdgcn_mfma_f32_16x16x32_f16(af, bf, acc[s], 0, 0, 0);
        }
    }
    // ---- epilogue: plain f32 C ----
#pragma unroll
    for (int s = 0; s < 8; s++) {
#pragma unroll
        for (int r = 0; r < 4; r++) {
            const int row = rb + w * 16 + quad * 4 + r;
            const int col = cb + s * 16 + l15;
            Cv[(size_t)row * N + col] = acc[s][r];
        }
    }
}

// ksum[h*32+d] = sum_n kfA[h][nb5][t][l15][j]; one block per (h,d)
__global__ void ksumT_k(const _Float16* __restrict__ kfA, float* __restrict__ ksum) {
    const int b = blockIdx.x;                       // h*32+d
    const int h = b >> 5, d = b & 31, t = d >> 4, l15 = d & 15;
    const int i = threadIdx.x;                      // 256
    const half8 v = *(const half8*)(kfA + (size_t)h * 65536 + (size_t)(i >> 2) * 1024 + t * 512 + l15 * 32 + (i & 3) * 8);
    float s = 0.f;
#pragma unroll
    for (int k = 0; k < 8; k++) s += (float)v[k];
#pragma unroll
    for (int off = 32; off > 0; off >>= 1) s += __shfl_down(s, off, 64);
    __shared__ float red[4];
    if ((i & 63) == 0) red[i >> 6] = s;
    __syncthreads();
    if (i == 0) ksum[b] = red[0] + red[1] + red[2] + red[3];
}

// merged z + g (block-range dispatch, 128 blocks):
//   blocks 0..63:  rz[n][h] = 1 / (qf[n,h,:].ksum[h,:] + 1e-6)
//   blocks 64..127: G[kk][h][u][l*9+m] = sum_e aE[e,h,kk]*YW[e,u]*RRED[e,l,m]
__global__ void zg_k(const float* __restrict__ qf, const float* __restrict__ ksum, float* __restrict__ rz,
                     const float* __restrict__ a, const float* __restrict__ cst, float* __restrict__ G) {
    if (blockIdx.x < 64) {
        const int idx = blockIdx.x * 256 + threadIdx.x;   // N*H = 16384
        const int n = idx >> 3, h = idx & 7;
        float s = 0.f;
#pragma unroll
        for (int d = 0; d < 32; d++) s += qf[(size_t)n * 256 + h * 32 + d] * ksum[h * 32 + d];
        rz[idx] = 1.0f / (s + 1e-6f);
    } else {
        const int b = blockIdx.x - 64;
        const int kk = b & 7, h = b >> 3;
        __shared__ float ae[9];
        if (threadIdx.x < 9) {
            const int ldeg[9] = {0, 1, 1, 1, 2, 2, 2, 2, 2};
            ae[threadIdx.x] = a[ldeg[threadIdx.x] * 64 + h * 8 + kk];
        }
        __syncthreads();
        const float* yw = cst;
        const float* rred = cst + 225;
        for (int i = threadIdx.x; i < 25 * 81; i += 256) {
            const int u = i / 81, lm = i - u * 81;
            float s = 0.f;
#pragma unroll
            for (int e = 0; e < 9; e++) s += ae[e] * yw[e * 25 + u] * rred[e * 81 + lm];
            G[((size_t)(kk * 8 + h) * 25 + u) * 81 + lm] = s;
        }
    }
}

// MFMA multipole (R21 + R24 setprio):
//   M16[kkut][h][cl*32+d] = sum_n trigA * kfA * v16T
// R21 (verified): 64 rows/wave made the kernel MFMA-bound; grid (8,9,7) = 504
// blocks ~2/CU; LDS 56KB dbuf; gridDim.x==8 keeps h->XCD affinity.
// R24: s_setprio(1) around the MFMA cluster (T5; staging/MFMA wave role-split
// exists here, catalog predicts 0..+20%).
__global__ __launch_bounds__(256, 2) void multipole_mm_k(const _Float16* __restrict__ trigA,
                                                         const _Float16* __restrict__ kfA,
                                                         const _Float16* __restrict__ v16T,
                                                         _Float16* __restrict__ M16) {
    const int h   = blockIdx.x;
    const int tid = threadIdx.x;
    const int w = tid >> 6, lane = tid & 63;
    const int l15 = lane & 15, quad = lane >> 4;
    const int cb  = blockIdx.y * 512 + w * 128;   // 4 cl per wave -> 128 cols
    const int cl0 = cb >> 5;
    const int r0  = blockIdx.z * 64;              // rows (kkut), 7*64 = 448

    __shared__ __align__(16) _Float16 sb[2][28][512];   // 56 KB

    float4v acc[4][8];
#pragma unroll
    for (int rt = 0; rt < 4; rt++)
#pragma unroll
        for (int s = 0; s < 8; s++) acc[rt][s] = float4v{0.f, 0.f, 0.f, 0.f};

    const _Float16* afg0 = trigA + (size_t)(r0 + l15) * 32 + quad * 8;            // + nb5*16384; +512/row-tile
    const _Float16* kqg0 = kfA + (size_t)h * 65536 + (size_t)l15 * 32 + quad * 8; // + nb5*1024
    const _Float16* kqg1 = kqg0 + 512;
    const int vs = lane >> 4, vc = (lane >> 2) & 3, vg = lane & 3;                // vq gather decomp
    const _Float16* vqg = v16T + (size_t)(h * 144 + cl0 + vc) * 2048 + vs * 32 + vg * 8; // + nbr

    half8 g0, g1, g2, g3, g4, g5, g6;

#define GATHER(nbr_) { \
        const size_t t5 = (size_t)((nbr_) >> 5) + w; \
        g0 = *(const half8*)(afg0 + t5 * 16384); \
        g1 = *(const half8*)(afg0 + t5 * 16384 + 512); \
        g2 = *(const half8*)(afg0 + t5 * 16384 + 1024); \
        g3 = *(const half8*)(afg0 + t5 * 16384 + 1536); \
        g4 = *(const half8*)(kqg0 + t5 * 1024); \
        g5 = *(const half8*)(kqg1 + t5 * 1024); \
        g6 = *(const half8*)(vqg + (nbr_)); }

#define DSWRITE(b_) { \
        *(half8*)&sb[b_][w * 6 + 0][lane * 8] = g0; \
        *(half8*)&sb[b_][w * 6 + 1][lane * 8] = g1; \
        *(half8*)&sb[b_][w * 6 + 2][lane * 8] = g2; \
        *(half8*)&sb[b_][w * 6 + 3][lane * 8] = g3; \
        *(half8*)&sb[b_][w * 6 + 4][lane * 8] = g4; \
        *(half8*)&sb[b_][w * 6 + 5][lane * 8] = g5; \
        *(half8*)&sb[b_][24 + w][lane * 8] = g6; }

#define STEP(s_) { \
        const half8 af0 = *(const half8*)&sb[cur][(s_) * 6 + 0][lane * 8]; \
        const half8 af1 = *(const half8*)&sb[cur][(s_) * 6 + 1][lane * 8]; \
        const half8 af2 = *(const half8*)&sb[cur][(s_) * 6 + 2][lane * 8]; \
        const half8 af3 = *(const half8*)&sb[cur][(s_) * 6 + 3][lane * 8]; \
        const half8 kq0 = *(const half8*)&sb[cur][(s_) * 6 + 4][lane * 8]; \
        const half8 kq1 = *(const half8*)&sb[cur][(s_) * 6 + 5][lane * 8]; \
        _Pragma("unroll") \
        for (int c = 0; c < 4; c++) { \
            const half8 vq = *(const half8*)&sb[cur][24 + w][((s_) * 4 + c) * 32 + quad * 8]; \
            const half8 b0 = kq0 * vq; \
            const half8 b1 = kq1 * vq; \
            acc[0][2 * c]     = __builtin_amdgcn_mfma_f32_16x16x32_f16(af0, b0, acc[0][2 * c],     0, 0, 0); \
            acc[0][2 * c + 1] = __builtin_amdgcn_mfma_f32_16x16x32_f16(af0, b1, acc[0][2 * c + 1], 0, 0, 0); \
            acc[1][2 * c]     = __builtin_amdgcn_mfma_f32_16x16x32_f16(af1, b0, acc[1][2 * c],     0, 0, 0); \
            acc[1][2 * c + 1] = __builtin_amdgcn_mfma_f32_16x16x32_f16(af1, b1, acc[1][2 * c + 1], 0, 0, 0); \
            acc[2][2 * c]     = __builtin_amdgcn_mfma_f32_16x16x32_f16(af2, b0, acc[2][2 * c],     0, 0, 0); \
            acc[2][2 * c + 1] = __builtin_amdgcn_mfma_f32_16x16x32_f16(af2, b1, acc[2][2 * c + 1], 0, 0, 0); \
            acc[3][2 * c]     = __builtin_amdgcn_mfma_f32_16x16x32_f16(af3, b0, acc[3][2 * c],     0, 0, 0); \
            acc[3][2 * c + 1] = __builtin_amdgcn_mfma_f32_16x16x32_f16(af3, b1, acc[3][2 * c + 1], 0, 0, 0); \
        } }

    int cur = 0;
    GATHER(0)
    DSWRITE(0)
    __syncthreads();
#pragma unroll 1
    for (int r = 0; r < 16; ++r) {
        if (r < 15) GATHER((r + 1) * 128)
        __builtin_amdgcn_s_setprio(1);
        STEP(0)
        STEP(1)
        STEP(2)
        STEP(3)
        __builtin_amdgcn_s_setprio(0);
        if (r < 15) DSWRITE(cur ^ 1)
        __syncthreads();
        cur ^= 1;
    }

#undef GATHER
#undef DSWRITE
#undef STEP

    // epilogue: C fragment -> M16[kkut][h][col]
#pragma unroll
    for (int rt = 0; rt < 4; rt++)
#pragma unroll
        for (int c = 0; c < 4; c++)
#pragma unroll
            for (int half = 0; half < 2; half++)
#pragma unroll
                for (int r = 0; r < 4; r++) {
                    const int row = r0 + rt * 16 + quad * 4 + r;
                    const int col = cb + c * 32 + half * 16 + l15;
                    M16[((size_t)row * 8 + h) * 4608 + col] = (_Float16)acc[rt][c * 2 + half][r];
                }
}

// MG[kt][h][...] = sum_l M16 * G  (R22, verified: 9 ds_read_b128 per octet)
__global__ __launch_bounds__(256) void fold_k(const _Float16* __restrict__ Mv, const float* __restrict__ G,
                                              _Float16* __restrict__ MG) {
    const int kt = blockIdx.x, h = blockIdx.y;
    const int tid = threadIdx.x;
    __shared__ __align__(16) _Float16 ms16[144 * 40];   // [cl][d], stride 40 halves (80 B)
    __shared__ float gs[81];
    const _Float16* src = Mv + ((size_t)kt * 8 + h) * 4608;
    for (int o = tid; o < 576; o += 256) {
        const half8 v = *(const half8*)(src + o * 8);
        *(half8*)&ms16[(o >> 2) * 40 + (o & 3) * 8] = v;
    }
    const int kk = kt / 50, u = (kt >> 1) % 25;
    if (tid < 81) gs[tid] = G[(((size_t)kk * 8 + h) * 25 + u) * 81 + tid];
    __syncthreads();
    _Float16* dst = MG + ((size_t)kt * 8 + h) * 4608;
    for (int o = tid; o < 576; o += 256) {
        const int i0 = o * 8;
        const int ct = i0 >> 9, quad = (i0 >> 7) & 3, l15 = (i0 >> 3) & 15;
        const int d0 = quad * 8;
        const int cm = ct * 16 + l15, c = cm / 9, m = cm - c * 9;
        float s0 = 0.f, s1 = 0.f, s2 = 0.f, s3 = 0.f, s4 = 0.f, s5 = 0.f, s6 = 0.f, s7 = 0.f;
#pragma unroll
        for (int l = 0; l < 9; l++) {
            const float g = gs[l * 9 + m];
            const half8 mv = *(const half8*)&ms16[(c * 9 + l) * 40 + d0];
            s0 += (float)mv[0] * g; s1 += (float)mv[1] * g;
            s2 += (float)mv[2] * g; s3 += (float)mv[3] * g;
            s4 += (float)mv[4] * g; s5 += (float)mv[5] * g;
            s6 += (float)mv[6] * g; s7 += (float)mv[7] * g;
        }
        half8 hv;
        hv[0] = (_Float16)s0; hv[1] = (_Float16)s1; hv[2] = (_Float16)s2; hv[3] = (_Float16)s3;
        hv[4] = (_Float16)s4; hv[5] = (_Float16)s5; hv[6] = (_Float16)s6; hv[7] = (_Float16)s7;
        *(half8*)(dst + i0) = hv;
    }
}

// local stage via MFMA (R20 config + R24 setprio):
// R15 geometry (32 rows/wave, 4 slices x 100kt, 2 blk/CU, 4-kt rounds) +
// f16 partial writes + rz in f32 epilogue. grid (8,4,16) = 512 = 2/CU.
__global__ __launch_bounds__(256, 2) void mm_local_k(const float* __restrict__ qf, const _Float16* __restrict__ trigA,
                                                     const _Float16* __restrict__ MG, const float* __restrict__ rZ,
                                                     _Float16* __restrict__ outp) {
    const int combo = blockIdx.y * 8 + blockIdx.x;
    const int h = combo >> 2;
    const int slice = combo & 3;
    const int n0 = blockIdx.z * 128;
    const int tid = threadIdx.x;
    const int w = tid >> 6, lane = tid & 63;
    const int l15 = lane & 15, quad = lane >> 4;

    // staging sb[2][4][4608] f16 (73728B), overlaid later by epilogue eb (37888B)
    __shared__ __align__(16) unsigned char smem_raw[73728];
    _Float16 (*sb)[4][4608] = (_Float16 (*)[4][4608])smem_raw;

    const int nbase = n0 + w * 32;                      // 32 rows per wave
    half8 qfr16[2];
#pragma unroll
    for (int rt = 0; rt < 2; rt++) {
        const int n = nbase + rt * 16 + l15;
        const float* qp = qf + (size_t)n * 256 + h * 32 + quad * 8;
#pragma unroll
        for (int j = 0; j < 8; j++) qfr16[rt][j] = (_Float16)qp[j];
    }
    float4v acc[2][9];
#pragma unroll
    for (int rt = 0; rt < 2; rt++)
#pragma unroll
        for (int ct = 0; ct < 9; ct++) acc[rt][ct] = float4v{0.f, 0.f, 0.f, 0.f};

    const int kt0 = slice * 100;
    const _Float16* mg0 = MG + (((size_t)kt0 * 8 + h) * 4608) + lane * 8;
    const _Float16* trg0 = trigA + (size_t)(nbase >> 5) * 16384 + (size_t)kt0 * 32 + l15;

#define STAGE4(b_, base_) { \
        const _Float16* src = mg0 + (size_t)((base_) + w) * 8 * 4608; \
        _Float16* dstl = &sb[b_][w][0]; \
        _Pragma("unroll") \
        for (int i = 0; i < 9; i++) \
            __builtin_amdgcn_global_load_lds( \
                (const __attribute__((address_space(1))) void*)(src + i * 512), \
                (__attribute__((address_space(3))) void*)(dstl + i * 512), 16, 0, 0); }

#define COMPUTE(kl) { \
        half8 tv0, tv1; \
        _Pragma("unroll") \
        for (int j = 0; j < 8; j++) { tv0[j] = ta[kl]; tv1[j] = tb[kl]; } \
        const half8 af0 = tv0 * qfr16[0]; \
        const half8 af1 = tv1 * qfr16[1]; \
        _Pragma("unroll") \
        for (int ct = 0; ct < 9; ct++) { \
            const half8 b = *(const half8*)&sb[cur][kl][ct * 512 + quad * 128 + l15 * 8]; \
            acc[0][ct] = __builtin_amdgcn_mfma_f32_16x16x32_f16(af0, b, acc[0][ct], 0, 0, 0); \
            acc[1][ct] = __builtin_amdgcn_mfma_f32_16x16x32_f16(af1, b, acc[1][ct], 0, 0, 0); \
        } }

    _Float16 ta[4], tb[4], ua[4], ub[4];
    int cur = 0;
    STAGE4(0, 0)
#pragma unroll
    for (int kl = 0; kl < 4; kl++) { ta[kl] = trg0[kl * 32]; tb[kl] = trg0[kl * 32 + 16]; }
    __syncthreads();

#pragma unroll 1
    for (int r = 0; r < 25; ++r) {
        if (r < 24) {
            STAGE4(cur ^ 1, (r + 1) * 4)
#pragma unroll
            for (int kl = 0; kl < 4; kl++) {
                const size_t o = (size_t)((r + 1) * 4 + kl) * 32;
                ua[kl] = trg0[o]; ub[kl] = trg0[o + 16];
            }
        }
        __builtin_amdgcn_s_setprio(1);
        COMPUTE(0) COMPUTE(1) COMPUTE(2) COMPUTE(3)
        __builtin_amdgcn_s_setprio(0);
        __syncthreads();
        cur ^= 1;
#pragma unroll
        for (int kl = 0; kl < 4; kl++) { ta[kl] = ua[kl]; tb[kl] = ub[kl]; }
    }

#undef STAGE4
#undef COMPUTE

    // epilogue: LDS transpose -> coalesced f16 stores into outp[slice][n][m][h*16+c]
    float* ebp = (float*)smem_raw;
    _Float16* dst = outp + (size_t)slice * 2359296;
    const int g4 = lane >> 2, sub = lane & 3;
#pragma unroll
    for (int rt = 0; rt < 2; rt++) {
        __syncthreads();
#pragma unroll
        for (int ct = 0; ct < 9; ct++) {
            const int cm = ct * 16 + l15;
            const int c = cm / 9, m = cm - c * 9;
#pragma unroll
            for (int r = 0; r < 4; r++)
                ebp[(size_t)(w * 16 + quad * 4 + r) * 148 + m * 16 + c] = acc[rt][ct][r];
        }
        __syncthreads();
#pragma unroll
        for (int s = 0; s < 9; s++) {
            const int li = s * 16 + g4;            // 0..143 line index
            const int nl = li / 9, m = li - nl * 9;
            const float4 v4 = *(const float4*)&ebp[(size_t)(w * 16 + nl) * 148 + m * 16 + sub * 4];
            const int n = nbase + rt * 16 + nl;
            const float rzv = rZ[(size_t)n * 8 + h];
            half4v hv;
            hv[0] = (_Float16)(v4.x * rzv); hv[1] = (_Float16)(v4.y * rzv);
            hv[2] = (_Float16)(v4.z * rzv); hv[3] = (_Float16)(v4.w * rzv);
            *(half4v*)&dst[((size_t)n * 9 + m) * 128 + h * 16 + sub * 4] = hv;
        }
    }
}

// ================================ launcher =================================
extern "C" void kernel_launch(void* const* d_in, const int* in_sizes, int n_in,
                              void* d_out, int out_size, void* d_ws, size_t ws_size,
                              hipStream_t stream) {
    const float* pos  = (const float*)d_in[0];
    const float* feat = (const float*)d_in[1];
    const float* Wq   = (const float*)d_in[2];
    const float* Wk   = (const float*)d_in[3];
    const float* Wv   = (const float*)d_in[4];
    const float* Wo   = (const float*)d_in[5];
    const float* a    = (const float*)d_in[6];
    const float* kap  = (const float*)d_in[7];
    float* out = (float*)d_out;
    float* ws = (float*)d_ws;

    // float-slot layout (~77.8 MB total)
    float* qf    = ws;                    // 524288
    float* kfAF  = qf + 524288;           // 262144 slots = kfA f16[8][64][2][512]
    float* vTF   = kfAF + 262144;         // 1179648 slots = v16T f16[1152*2048]
    float* trigF = vTF + 1179648;         // 524288 slots = trigA f16[64][512][32]
    float* ksum  = trigF + 524288;        // 256
    float* rz    = ksum + 256;            // 16384
    float* G     = rz + 16384;            // 129600
    float* M16F  = G + 129600;            // 9437184 slots = M16 f16[512*8*4608]; later outp f16[4][2359296]
    float* regX  = M16F + 9437184;        // 7372800 slots: R (first 1572864), later MG f16[400*8*4608]
    float* R     = regX;
    _Float16* trigA = (_Float16*)trigF;
    _Float16* kfA   = (_Float16*)kfAF;
    _Float16* v16T  = (_Float16*)vTF;
    _Float16* M16   = (_Float16*)M16F;
    _Float16* MG16  = (_Float16*)regX;
    _Float16* outp16 = (_Float16*)M16F;   // overlay: M16 dead after fold_k; 4 f16 partial buffers

    const float* cst = d_const_g;

    hipLaunchKernelGGL(radtrig_k, dim3(2048), dim3(256), 0, stream, feat, pos, kap, cst, R, trigA);
    hipLaunchKernelGGL(qk_gemm_k, dim3(8, 64), dim3(256), 0, stream, R, Wq, Wk, qf, kfA);
    hipLaunchKernelGGL(mfma_gemm16_k, dim3(2, 288), dim3(256), 0, stream, feat, Wv, vTF, 18432, 128, 256, 2, rz);
    hipLaunchKernelGGL(ksumT_k, dim3(256), dim3(256), 0, stream, kfA, ksum);
    hipLaunchKernelGGL(zg_k, dim3(128), dim3(256), 0, stream, qf, ksum, rz, a, cst, G);
    hipLaunchKernelGGL(multipole_mm_k, dim3(8, 9, 7), dim3(256), 0, stream, trigA, kfA, v16T, M16);
    hipLaunchKernelGGL(fold_k, dim3(400, 8), dim3(256), 0, stream, M16, G, MG16);
    hipLaunchKernelGGL(mm_local_k, dim3(8, 4, 16), dim3(256), 0, stream, qf, trigA, MG16, rz, outp16);
    hipLaunchKernelGGL(outg_k, dim3(2, 288), dim3(256), 0, stream, outp16, Wo, out);
}

// Round 12
// 281.701 us; speedup vs baseline: 1.2258x; 1.0087x over previous
//
#include <hip/hip_runtime.h>
#include <cmath>
#include <complex>
#include <algorithm>

// ---------------------------------------------------------------------------
// Problem constants: LMAX=2, NC=9, H=8, DQK=32, CV=16, K=8, U=25, N=2048, C=256
// ---------------------------------------------------------------------------

typedef _Float16 half8 __attribute__((ext_vector_type(8)));
typedef _Float16 half4v __attribute__((ext_vector_type(4)));
typedef float float4v __attribute__((ext_vector_type(4)));

// ========================= host-side constant tables ========================
namespace {

using cd = std::complex<double>;

static double fct(int n) { double r = 1.0; for (int i = 2; i <= n; ++i) r *= i; return r; }

static double cg_coef(int j1, int m1, int j2, int m2, int j, int m) {
    if (m1 + m2 != m || j < std::abs(j1 - j2) || j > j1 + j2) return 0.0;
    double pref = std::sqrt((2 * j + 1) * fct(j + j1 - j2) * fct(j - j1 + j2) * fct(j1 + j2 - j) / fct(j1 + j2 + j + 1));
    pref *= std::sqrt(fct(j + m) * fct(j - m) * fct(j1 - m1) * fct(j1 + m1) * fct(j2 - m2) * fct(j2 + m2));
    double s = 0.0;
    for (int k = 0; k <= j1 + j2 - j; ++k) {
        int d0 = k, d1 = j1 + j2 - j - k, d2 = j1 - m1 - k, d3 = j2 + m2 - k, d4 = j - j2 + m1 + k, d5 = j - j1 - m2 + k;
        if (d0 < 0 || d1 < 0 || d2 < 0 || d3 < 0 || d4 < 0 || d5 < 0) continue;
        s += ((k & 1) ? -1.0 : 1.0) / (fct(d0) * fct(d1) * fct(d2) * fct(d3) * fct(d4) * fct(d5));
    }
    return pref * s;
}

static void umat(int l, cd u[5][5]) {
    for (int i = 0; i < 5; i++) for (int j = 0; j < 5; j++) u[i][j] = cd(0, 0);
    const double s = 1.0 / std::sqrt(2.0);
    for (int m = -l; m <= l; m++) {
        double sgn = (std::abs(m) & 1) ? -1.0 : 1.0;   // (-1)^m
        if (m > 0)      { u[l + m][l + m] = cd(sgn * s, 0); u[l + m][l - m] = cd(s, 0); }
        else if (m == 0){ u[l][l] = cd(1, 0); }
        else            { u[l + m][l + m] = cd(0, s);       u[l + m][l - m] = cd(0, -sgn * s); }
    }
}

static void real_cg_f(int l1, int l2, int L, double out[5][5][5]) {
    cd U1[5][5], U2[5][5], UL[5][5];
    umat(l1, U1); umat(l2, U2); umat(L, UL);
    const int n1 = 2 * l1 + 1, n2 = 2 * l2 + 1, n3 = 2 * L + 1;
    double cgt[5][5][5];
    for (int i1 = 0; i1 < n1; i1++) for (int i2 = 0; i2 < n2; i2++) for (int i3 = 0; i3 < n3; i3++)
        cgt[i1][i2][i3] = cg_coef(l1, i1 - l1, l2, i2 - l2, L, i3 - L);
    cd r[5][5][5];
    double nr = 0, ni = 0;
    for (int a1 = 0; a1 < n1; a1++) for (int b = 0; b < n2; b++) for (int c = 0; c < n3; c++) {
        cd acc(0, 0);
        for (int uu = 0; uu < n1; uu++) for (int vv = 0; vv < n2; vv++) for (int w = 0; w < n3; w++) {
            double cval = cgt[uu][vv][w];
            if (cval == 0.0) continue;
            acc += U1[a1][uu] * U2[b][vv] * std::conj(UL[c][w]) * cval;
        }
        r[a1][b][c] = acc;
        nr += acc.real() * acc.real();
        ni += acc.imag() * acc.imag();
    }
    const bool useRe = std::sqrt(nr) >= std::sqrt(ni);
    for (int a1 = 0; a1 < n1; a1++) for (int b = 0; b < n2; b++) for (int c = 0; c < n3; c++)
        out[a1][b][c] = useRe ? r[a1][b][c].real() : r[a1][b][c].imag();
}

// device constant buffer layout: YW[9*25] | RRED[9*81] | DIRS[25*3]  = 1029 floats
static float  h_const[1029];
static float* d_const_g = nullptr;

struct GlobalInit {
    GlobalInit() {
        const double PI = 3.14159265358979323846;
        const double gx[5] = {-0.9061798459386640, -0.5384693101056831, 0.0, 0.5384693101056831, 0.9061798459386640};
        const double gw[5] = { 0.23692688505618908, 0.47862867049936647, 0.5688888888888889, 0.47862867049936647, 0.23692688505618908};
        double YW[9][25], DIRS[25][3];
        for (int u = 0; u < 25; ++u) {
            const int it = u / 5, ip = u % 5;
            const double ct = gx[it], wq = gw[it] * (2.0 * PI / 5.0), ph = 2.0 * PI * ip / 5.0;
            const double st = std::sqrt(std::max(1.0 - ct * ct, 0.0));
            const double x = st * std::cos(ph), y = st * std::sin(ph), z = ct;
            DIRS[u][0] = x; DIRS[u][1] = y; DIRS[u][2] = z;
            double Y[9];
            Y[0] = 0.282095;           Y[1] = 0.488603 * y;      Y[2] = 0.488603 * z;
            Y[3] = 0.488603 * x;       Y[4] = 1.092548 * x * y;  Y[5] = 1.092548 * y * z;
            Y[6] = 0.315392 * (3 * z * z - 1); Y[7] = 1.092548 * x * z; Y[8] = 0.546274 * (x * x - y * y);
            for (int e = 0; e < 9; e++) YW[e][u] = Y[e] * wq;
        }
        double RRED[9][9][9];
        for (int i = 0; i < 9; i++) for (int j = 0; j < 9; j++) for (int k = 0; k < 9; k++) RRED[i][j][k] = 0.0;
        const int off[3] = {0, 1, 4};
        double cnt[3] = {0, 0, 0};
        double rc[5][5][5];
        for (int l1 = 0; l1 <= 2; l1++) for (int l2 = 0; l2 <= 2; l2++) {
            const int Llo = std::abs(l1 - l2), Lhi = std::min(l1 + l2, 2);
            for (int L = Llo; L <= Lhi; L++) {
                real_cg_f(l1, l2, L, rc);
                for (int i1 = 0; i1 < 2 * l1 + 1; i1++)
                    for (int i2 = 0; i2 < 2 * l2 + 1; i2++)
                        for (int i3 = 0; i3 < 2 * L + 1; i3++)
                            RRED[off[l1] + i1][off[l2] + i2][off[L] + i3] += rc[i1][i2][i3];
                cnt[L] += 1.0;
            }
        }
        for (int L = 0; L <= 2; L++) {
            const double dv = std::max(cnt[L], 1.0);
            for (int a1 = 0; a1 < 9; a1++) for (int b = 0; b < 9; b++)
                for (int k = 0; k < 2 * L + 1; k++) RRED[a1][b][off[L] + k] /= dv;
        }
        for (int e = 0; e < 9; e++) for (int u = 0; u < 25; u++) h_const[e * 25 + u] = (float)YW[e][u];
        for (int e = 0; e < 9; e++) for (int l = 0; l < 9; l++) for (int m = 0; m < 9; m++)
            h_const[225 + e * 81 + l * 9 + m] = (float)RRED[e][l][m];
        for (int u = 0; u < 25; u++) for (int ax = 0; ax < 3; ax++) h_const[954 + u * 3 + ax] = (float)DIRS[u][ax];
        if (hipMalloc((void**)&d_const_g, 1029 * sizeof(float)) == hipSuccess)
            hipMemcpy(d_const_g, h_const, 1029 * sizeof(float), hipMemcpyHostToDevice);
    }
} g_init;

} // namespace

// ============================== device kernels ==============================

// merged radial + trig (R23, verified) + R25: block 0 zeroes ksum[256] for the
// qk_gemm epilogue atomics (stream-ordered before qk_gemm).
__global__ void radtrig_k(const float* __restrict__ feat, const float* __restrict__ pos,
                          const float* __restrict__ kappa, const float* __restrict__ cst,
                          float* __restrict__ R, _Float16* __restrict__ trigA,
                          float* __restrict__ ksum) {
    const int n = blockIdx.x, t = threadIdx.x;
    if (n == 0) ksum[t] = 0.f;
    {
        const float* f = feat + (size_t)n * 9 * 256 + t;
        const float f0 = f[0];
        const float a1 = f[256], a2 = f[512], a3 = f[768];
        const float b1 = f[1024], b2 = f[1280], b3 = f[1536], b4 = f[1792], b5 = f[2048];
        const float r1 = sqrtf(a1 * a1 + a2 * a2 + a3 * a3 + 1e-8f);
        const float r2 = sqrtf(b1 * b1 + b2 * b2 + b3 * b3 + b4 * b4 + b5 * b5 + 1e-8f);
        float* o = R + (size_t)n * 768 + t;
        o[0] = f0; o[256] = r1; o[512] = r2;
    }
    const size_t base = (size_t)(n >> 5) * 16384 + (n & 31);
    if (t < 200) {
        const int kq = t / 25, u = t - kq * 25;
        const float* dirs = cst + 954;
        const float ph = kappa[kq] * (pos[n * 3] * dirs[u * 3] + pos[n * 3 + 1] * dirs[u * 3 + 1] + pos[n * 3 + 2] * dirs[u * 3 + 2]);
        float s, c;
        sincosf(ph, &s, &c);
        const int kkut = (kq * 25 + u) * 2;
        trigA[base + (size_t)kkut * 32] = (_Float16)c;
        trigA[base + (size_t)(kkut + 1) * 32] = (_Float16)s;
    } else {
        const int kkut = 400 + (t - 200) * 2;
        trigA[base + (size_t)kkut * 32] = (_Float16)0.f;
        trigA[base + (size_t)(kkut + 1) * 32] = (_Float16)0.f;
    }
}

// fused Q/K projection GEMM (R24: 2 blocks/CU; R25: fused ksum):
// grid (8,64) = 512 blocks = 2/CU. Wave: w&1 = 16-row half, w>>1 = 32-col
// half; acc[2]. x<4 -> Wq (qf f32), x>=4 -> Wk (kfA frag f16); elu+1.
// R25: isK blocks also accumulate ksum[col] = sum_n kf[n][col]: per-thread
// 4-row partial -> LDS atomicAdd (8 threads/col) -> 64 global f32 atomicAdds
// per block (16K total to 256 addrs; device-scope per G12). Replaces the
// ksumT_k dispatch (same f32 accumulation of the same f16 values; order-only
// difference ~1e-7 rel in a denominator floored at 1e-6).
__global__ __launch_bounds__(256) void qk_gemm_k(const float* __restrict__ A,
                                                 const float* __restrict__ Wq,
                                                 const float* __restrict__ Wk,
                                                 float* __restrict__ qf,
                                                 _Float16* __restrict__ kfA,
                                                 float* __restrict__ ksum) {
    __shared__ __align__(16) _Float16 Af[32 * 40];
    __shared__ __align__(16) _Float16 Bf[64 * 40];
    __shared__ float kred[64];
    const int tid = threadIdx.x;
    const int w = tid >> 6, lane = tid & 63;
    const int l15 = lane & 15, quad = lane >> 4;
    const int rh = w & 1, ch = w >> 1;
    const bool isK = blockIdx.x >= 4;
    const int cb = (blockIdx.x & 3) * 64;
    const int rb = blockIdx.y * 32;
    const float* B = isK ? Wk : Wq;
    const int N = 256, Kd = 768;
    const int sra = tid >> 3, sqa = tid & 7;   // A stager: 32 rows x 8 k-quads
    const int srb = tid >> 2, sqb = tid & 3;   // B stager: 64 cols x 4 k-octets

    if (isK && tid < 64) kred[tid] = 0.f;

    float4v acc[2];
    acc[0] = float4v{0.f, 0.f, 0.f, 0.f};
    acc[1] = float4v{0.f, 0.f, 0.f, 0.f};

    for (int k0 = 0; k0 < Kd; k0 += 32) {
        __syncthreads();
        {
            const float* Ap = A + (size_t)(rb + sra) * Kd + k0 + sqa * 4;
            const float4 a0 = *(const float4*)(Ap);
            half4v hv;
            hv[0] = (_Float16)a0.x; hv[1] = (_Float16)a0.y; hv[2] = (_Float16)a0.z; hv[3] = (_Float16)a0.w;
            *(half4v*)&Af[sra * 40 + sqa * 4] = hv;
        }
        {
            const float* Bp = B + (size_t)(k0 + sqb * 8) * N + cb + srb;
            half8 hv;
#pragma unroll
            for (int i = 0; i < 8; i++) hv[i] = (_Float16)Bp[(size_t)i * N];
            *(half8*)&Bf[srb * 40 + sqb * 8] = hv;
        }
        __syncthreads();
        const half8 af = *(const half8*)&Af[(rh * 16 + l15) * 40 + quad * 8];
#pragma unroll
        for (int s = 0; s < 2; s++) {
            const half8 bf = *(const half8*)&Bf[(ch * 32 + s * 16 + l15) * 40 + quad * 8];
            acc[s] = __builtin_amdgcn_mfma_f32_16x16x32_f16(af, bf, acc[s], 0, 0, 0);
        }
    }
#pragma unroll
    for (int s = 0; s < 2; s++) {
        float colsum = 0.f;
#pragma unroll
        for (int r = 0; r < 4; r++) {
            const int row = rb + rh * 16 + quad * 4 + r;
            const int col = cb + ch * 32 + s * 16 + l15;
            float val = acc[s][r];
            val = (val > 0.f ? val : expf(val) - 1.f) + 1.f;
            if (isK) {
                const int hh = col >> 5, dd = col & 31, tt = dd >> 4, ll = dd & 15;
                const _Float16 h16 = (_Float16)val;
                kfA[(size_t)hh * 65536 + (size_t)(row >> 5) * 1024 + tt * 512 + ll * 32 + (row & 31)] = h16;
                colsum += (float)h16;
            } else {
                qf[(size_t)row * 256 + col] = val;
            }
        }
        if (isK) atomicAdd(&kred[ch * 32 + s * 16 + l15], colsum);
    }
    if (isK) {
        __syncthreads();
        if (tid < 64) atomicAdd(&ksum[cb + tid], kred[tid]);
    }
}

// f16 MFMA GEMM, C = A(MxK) @ B(KxN); mode 2: v16T f16 scatter (only user).
__global__ __launch_bounds__(256) void mfma_gemm16_k(const float* __restrict__ A, const float* __restrict__ B,
                                                     float* __restrict__ Cv, int M, int N, int Kd, int mode,
                                                     const float* __restrict__ rZ) {
    __shared__ __align__(16) _Float16 Af[64 * 40];   // [row][k], stride 40 halves (80 B)
    __shared__ __align__(16) _Float16 Bf[64 * 40];   // [col][k]
    const int tid = threadIdx.x;
    const int w = tid >> 6, lane = tid & 63;
    const int l15 = lane & 15, quad = lane >> 4;
    const int rb = blockIdx.y * 64, cb = blockIdx.x * 64;
    const int sr = tid >> 2, sq = tid & 3;           // stager: row/col 0..63, k-quartet 0..3

    float4v acc[4];
#pragma unroll
    for (int s = 0; s < 4; s++) acc[s] = float4v{0.f, 0.f, 0.f, 0.f};

    for (int k0 = 0; k0 < Kd; k0 += 32) {
        __syncthreads();
        // ---- stage A (f32 -> f16, fragment order) ----
        {
            const float* Ap = A + (size_t)(rb + sr) * Kd + k0 + sq * 8;
            const float4 a0 = *(const float4*)(Ap);
            const float4 a1 = *(const float4*)(Ap + 4);
            half8 hv;
            hv[0] = (_Float16)a0.x; hv[1] = (_Float16)a0.y; hv[2] = (_Float16)a0.z; hv[3] = (_Float16)a0.w;
            hv[4] = (_Float16)a1.x; hv[5] = (_Float16)a1.y; hv[6] = (_Float16)a1.z; hv[7] = (_Float16)a1.w;
            *(half8*)&Af[sr * 40 + sq * 8] = hv;
        }
        // ---- stage B (column gather; f32 -> f16) ----
        {
            const float* Bp = B + (size_t)(k0 + sq * 8) * N + cb + sr;
            half8 hv;
#pragma unroll
            for (int i = 0; i < 8; i++) hv[i] = (_Float16)Bp[(size_t)i * N];
            *(half8*)&Bf[sr * 40 + sq * 8] = hv;
        }
        __syncthreads();
        // ---- fragments + MFMA ----
        const half8 af = *(const half8*)&Af[(w * 16 + l15) * 40 + quad * 8];
#pragma unroll
        for (int s = 0; s < 4; s++) {
            const half8 bf = *(const half8*)&Bf[(s * 16 + l15) * 40 + quad * 8];
            acc[s] = __builtin_amdgcn_mfma_f32_16x16x32_f16(af, bf, acc[s], 0, 0, 0);
        }
    }
    // ---- epilogue: C fragment (row = rb+w*16+quad*4+r, col = cb+s*16+l15) ----
#pragma unroll
    for (int s = 0; s < 4; s++) {
#pragma unroll
        for (int r = 0; r < 4; r++) {
            const int row = rb + w * 16 + quad * 4 + r;
            const int col = cb + s * 16 + l15;
            float val = acc[s][r];
            if (mode == 2) {
                // v16T[(h*144 + c*9 + l)][n] f16
                const int n = row / 9, l = row - n * 9, hq = col >> 4, cvq = col & 15;
                _Float16* o = (_Float16*)Cv;
                o[((size_t)hq * 144 + cvq * 9 + l) * 2048 + n] = (_Float16)val;
            } else {
                Cv[(size_t)row * N + col] = val;
            }
        }
    }
}

// out-GEMM (R23, verified): C = (sum of 4 f16 partials)(18432x128) @ Wo(128x256)
// N-tile 128, grid (2,288) = 576 blocks = 2.25/CU.
__global__ __launch_bounds__(256) void outg_k(const _Float16* __restrict__ A, const float* __restrict__ B,
                                              float* __restrict__ Cv) {
    __shared__ __align__(16) _Float16 Af[64 * 40];    // [row][k]
    __shared__ __align__(16) _Float16 Bf[128 * 40];   // [col][k]
    const int tid = threadIdx.x;
    const int w = tid >> 6, lane = tid & 63;
    const int l15 = lane & 15, quad = lane >> 4;
    const int rb = blockIdx.y * 64, cb = blockIdx.x * 128;
    const int sr = tid >> 2, sq = tid & 3;            // stager: row/col 0..63, k-quartet 0..3
    const int N = 256, Kd = 128;

    float4v acc[8];
#pragma unroll
    for (int s = 0; s < 8; s++) acc[s] = float4v{0.f, 0.f, 0.f, 0.f};

    for (int k0 = 0; k0 < Kd; k0 += 32) {
        __syncthreads();
        // ---- stage A: 4-partial f32 sum -> f16 ----
        {
            const _Float16* Ap16 = A + (size_t)(rb + sr) * Kd + k0 + sq * 8;
            const half8 p0 = *(const half8*)(Ap16);
            const half8 p1 = *(const half8*)(Ap16 + 2359296);
            const half8 p2 = *(const half8*)(Ap16 + 4718592);
            const half8 p3 = *(const half8*)(Ap16 + 7077888);
            half8 hv;
#pragma unroll
            for (int i = 0; i < 8; i++)
                hv[i] = (_Float16)((float)p0[i] + (float)p1[i] + (float)p2[i] + (float)p3[i]);
            *(half8*)&Af[sr * 40 + sq * 8] = hv;
        }
        // ---- stage B: 128 cols (two passes of 64) ----
#pragma unroll
        for (int hf = 0; hf < 2; hf++) {
            const float* Bp = B + (size_t)(k0 + sq * 8) * N + cb + hf * 64 + sr;
            half8 hv;
#pragma unroll
            for (int i = 0; i < 8; i++) hv[i] = (_Float16)Bp[(size_t)i * N];
            *(half8*)&Bf[(hf * 64 + sr) * 40 + sq * 8] = hv;
        }
        __syncthreads();
        const half8 af = *(const half8*)&Af[(w * 16 + l15) * 40 + quad * 8];
#pragma unroll
        for (int s = 0; s < 8; s++) {
            const half8 bf = *(const half8*)&Bf[(s * 16 + l15) * 40 + quad * 8];
            acc[s] = __builtin_amdgcn_mfma_f32_16x16x32_f16(af, bf, acc[s], 0, 0, 0);
        }
    }
    // ---- epilogue: plain f32 C ----
#pragma unroll
    for (int s = 0; s < 8; s++) {
#pragma unroll
        for (int r = 0; r < 4; r++) {
            const int row = rb + w * 16 + quad * 4 + r;
            const int col = cb + s * 16 + l15;
            Cv[(size_t)row * N + col] = acc[s][r];
        }
    }
}

// merged z + g (block-range dispatch, 128 blocks):
//   blocks 0..63:  rz[n][h] = 1 / (qf[n,h,:].ksum[h,:] + 1e-6)
//   blocks 64..127: G[kk][h][u][l*9+m] = sum_e aE[e,h,kk]*YW[e,u]*RRED[e,l,m]
__global__ void zg_k(const float* __restrict__ qf, const float* __restrict__ ksum, float* __restrict__ rz,
                     const float* __restrict__ a, const float* __restrict__ cst, float* __restrict__ G) {
    if (blockIdx.x < 64) {
        const int idx = blockIdx.x * 256 + threadIdx.x;   // N*H = 16384
        const int n = idx >> 3, h = idx & 7;
        float s = 0.f;
#pragma unroll
        for (int d = 0; d < 32; d++) s += qf[(size_t)n * 256 + h * 32 + d] * ksum[h * 32 + d];
        rz[idx] = 1.0f / (s + 1e-6f);
    } else {
        const int b = blockIdx.x - 64;
        const int kk = b & 7, h = b >> 3;
        __shared__ float ae[9];
        if (threadIdx.x < 9) {
            const int ldeg[9] = {0, 1, 1, 1, 2, 2, 2, 2, 2};
            ae[threadIdx.x] = a[ldeg[threadIdx.x] * 64 + h * 8 + kk];
        }
        __syncthreads();
        const float* yw = cst;
        const float* rred = cst + 225;
        for (int i = threadIdx.x; i < 25 * 81; i += 256) {
            const int u = i / 81, lm = i - u * 81;
            float s = 0.f;
#pragma unroll
            for (int e = 0; e < 9; e++) s += ae[e] * yw[e * 25 + u] * rred[e * 81 + lm];
            G[((size_t)(kk * 8 + h) * 25 + u) * 81 + lm] = s;
        }
    }
}

// MFMA multipole (R21 + R24 setprio, verified):
//   M16[kkut][h][cl*32+d] = sum_n trigA * kfA * v16T
// grid (8,9,7) = 504 blocks ~2/CU; LDS 56KB dbuf; h->XCD affinity.
__global__ __launch_bounds__(256, 2) void multipole_mm_k(const _Float16* __restrict__ trigA,
                                                         const _Float16* __restrict__ kfA,
                                                         const _Float16* __restrict__ v16T,
                                                         _Float16* __restrict__ M16) {
    const int h   = blockIdx.x;
    const int tid = threadIdx.x;
    const int w = tid >> 6, lane = tid & 63;
    const int l15 = lane & 15, quad = lane >> 4;
    const int cb  = blockIdx.y * 512 + w * 128;   // 4 cl per wave -> 128 cols
    const int cl0 = cb >> 5;
    const int r0  = blockIdx.z * 64;              // rows (kkut), 7*64 = 448

    __shared__ __align__(16) _Float16 sb[2][28][512];   // 56 KB

    float4v acc[4][8];
#pragma unroll
    for (int rt = 0; rt < 4; rt++)
#pragma unroll
        for (int s = 0; s < 8; s++) acc[rt][s] = float4v{0.f, 0.f, 0.f, 0.f};

    const _Float16* afg0 = trigA + (size_t)(r0 + l15) * 32 + quad * 8;            // + nb5*16384; +512/row-tile
    const _Float16* kqg0 = kfA + (size_t)h * 65536 + (size_t)l15 * 32 + quad * 8; // + nb5*1024
    const _Float16* kqg1 = kqg0 + 512;
    const int vs = lane >> 4, vc = (lane >> 2) & 3, vg = lane & 3;                // vq gather decomp
    const _Float16* vqg = v16T + (size_t)(h * 144 + cl0 + vc) * 2048 + vs * 32 + vg * 8; // + nbr

    half8 g0, g1, g2, g3, g4, g5, g6;

#define GATHER(nbr_) { \
        const size_t t5 = (size_t)((nbr_) >> 5) + w; \
        g0 = *(const half8*)(afg0 + t5 * 16384); \
        g1 = *(const half8*)(afg0 + t5 * 16384 + 512); \
        g2 = *(const half8*)(afg0 + t5 * 16384 + 1024); \
        g3 = *(const half8*)(afg0 + t5 * 16384 + 1536); \
        g4 = *(const half8*)(kqg0 + t5 * 1024); \
        g5 = *(const half8*)(kqg1 + t5 * 1024); \
        g6 = *(const half8*)(vqg + (nbr_)); }

#define DSWRITE(b_) { \
        *(half8*)&sb[b_][w * 6 + 0][lane * 8] = g0; \
        *(half8*)&sb[b_][w * 6 + 1][lane * 8] = g1; \
        *(half8*)&sb[b_][w * 6 + 2][lane * 8] = g2; \
        *(half8*)&sb[b_][w * 6 + 3][lane * 8] = g3; \
        *(half8*)&sb[b_][w * 6 + 4][lane * 8] = g4; \
        *(half8*)&sb[b_][w * 6 + 5][lane * 8] = g5; \
        *(half8*)&sb[b_][24 + w][lane * 8] = g6; }

#define STEP(s_) { \
        const half8 af0 = *(const half8*)&sb[cur][(s_) * 6 + 0][lane * 8]; \
        const half8 af1 = *(const half8*)&sb[cur][(s_) * 6 + 1][lane * 8]; \
        const half8 af2 = *(const half8*)&sb[cur][(s_) * 6 + 2][lane * 8]; \
        const half8 af3 = *(const half8*)&sb[cur][(s_) * 6 + 3][lane * 8]; \
        const half8 kq0 = *(const half8*)&sb[cur][(s_) * 6 + 4][lane * 8]; \
        const half8 kq1 = *(const half8*)&sb[cur][(s_) * 6 + 5][lane * 8]; \
        _Pragma("unroll") \
        for (int c = 0; c < 4; c++) { \
            const half8 vq = *(const half8*)&sb[cur][24 + w][((s_) * 4 + c) * 32 + quad * 8]; \
            const half8 b0 = kq0 * vq; \
            const half8 b1 = kq1 * vq; \
            acc[0][2 * c]     = __builtin_amdgcn_mfma_f32_16x16x32_f16(af0, b0, acc[0][2 * c],     0, 0, 0); \
            acc[0][2 * c + 1] = __builtin_amdgcn_mfma_f32_16x16x32_f16(af0, b1, acc[0][2 * c + 1], 0, 0, 0); \
            acc[1][2 * c]     = __builtin_amdgcn_mfma_f32_16x16x32_f16(af1, b0, acc[1][2 * c],     0, 0, 0); \
            acc[1][2 * c + 1] = __builtin_amdgcn_mfma_f32_16x16x32_f16(af1, b1, acc[1][2 * c + 1], 0, 0, 0); \
            acc[2][2 * c]     = __builtin_amdgcn_mfma_f32_16x16x32_f16(af2, b0, acc[2][2 * c],     0, 0, 0); \
            acc[2][2 * c + 1] = __builtin_amdgcn_mfma_f32_16x16x32_f16(af2, b1, acc[2][2 * c + 1], 0, 0, 0); \
            acc[3][2 * c]     = __builtin_amdgcn_mfma_f32_16x16x32_f16(af3, b0, acc[3][2 * c],     0, 0, 0); \
            acc[3][2 * c + 1] = __builtin_amdgcn_mfma_f32_16x16x32_f16(af3, b1, acc[3][2 * c + 1], 0, 0, 0); \
        } }

    int cur = 0;
    GATHER(0)
    DSWRITE(0)
    __syncthreads();
#pragma unroll 1
    for (int r = 0; r < 16; ++r) {
        if (r < 15) GATHER((r + 1) * 128)
        __builtin_amdgcn_s_setprio(1);
        STEP(0)
        STEP(1)
        STEP(2)
        STEP(3)
        __builtin_amdgcn_s_setprio(0);
        if (r < 15) DSWRITE(cur ^ 1)
        __syncthreads();
        cur ^= 1;
    }

#undef GATHER
#undef DSWRITE
#undef STEP

    // epilogue: C fragment -> M16[kkut][h][col]
#pragma unroll
    for (int rt = 0; rt < 4; rt++)
#pragma unroll
        for (int c = 0; c < 4; c++)
#pragma unroll
            for (int half = 0; half < 2; half++)
#pragma unroll
                for (int r = 0; r < 4; r++) {
                    const int row = r0 + rt * 16 + quad * 4 + r;
                    const int col = cb + c * 32 + half * 16 + l15;
                    M16[((size_t)row * 8 + h) * 4608 + col] = (_Float16)acc[rt][c * 2 + half][r];
                }
}

// MG[kt][h][...] = sum_l M16 * G  (R22, verified: 9 ds_read_b128 per octet)
__global__ __launch_bounds__(256) void fold_k(const _Float16* __restrict__ Mv, const float* __restrict__ G,
                                              _Float16* __restrict__ MG) {
    const int kt = blockIdx.x, h = blockIdx.y;
    const int tid = threadIdx.x;
    __shared__ __align__(16) _Float16 ms16[144 * 40];   // [cl][d], stride 40 halves (80 B)
    __shared__ float gs[81];
    const _Float16* src = Mv + ((size_t)kt * 8 + h) * 4608;
    for (int o = tid; o < 576; o += 256) {
        const half8 v = *(const half8*)(src + o * 8);
        *(half8*)&ms16[(o >> 2) * 40 + (o & 3) * 8] = v;
    }
    const int kk = kt / 50, u = (kt >> 1) % 25;
    if (tid < 81) gs[tid] = G[(((size_t)kk * 8 + h) * 25 + u) * 81 + tid];
    __syncthreads();
    _Float16* dst = MG + ((size_t)kt * 8 + h) * 4608;
    for (int o = tid; o < 576; o += 256) {
        const int i0 = o * 8;
        const int ct = i0 >> 9, quad = (i0 >> 7) & 3, l15 = (i0 >> 3) & 15;
        const int d0 = quad * 8;
        const int cm = ct * 16 + l15, c = cm / 9, m = cm - c * 9;
        float s0 = 0.f, s1 = 0.f, s2 = 0.f, s3 = 0.f, s4 = 0.f, s5 = 0.f, s6 = 0.f, s7 = 0.f;
#pragma unroll
        for (int l = 0; l < 9; l++) {
            const float g = gs[l * 9 + m];
            const half8 mv = *(const half8*)&ms16[(c * 9 + l) * 40 + d0];
            s0 += (float)mv[0] * g; s1 += (float)mv[1] * g;
            s2 += (float)mv[2] * g; s3 += (float)mv[3] * g;
            s4 += (float)mv[4] * g; s5 += (float)mv[5] * g;
            s6 += (float)mv[6] * g; s7 += (float)mv[7] * g;
        }
        half8 hv;
        hv[0] = (_Float16)s0; hv[1] = (_Float16)s1; hv[2] = (_Float16)s2; hv[3] = (_Float16)s3;
        hv[4] = (_Float16)s4; hv[5] = (_Float16)s5; hv[6] = (_Float16)s6; hv[7] = (_Float16)s7;
        *(half8*)(dst + i0) = hv;
    }
}

// local stage via MFMA (R20 config + R24 setprio, verified):
// R15 geometry (32 rows/wave, 4 slices x 100kt, 2 blk/CU, 4-kt rounds) +
// f16 partial writes + rz in f32 epilogue. grid (8,4,16) = 512 = 2/CU.
__global__ __launch_bounds__(256, 2) void mm_local_k(const float* __restrict__ qf, const _Float16* __restrict__ trigA,
                                                     const _Float16* __restrict__ MG, const float* __restrict__ rZ,
                                                     _Float16* __restrict__ outp) {
    const int combo = blockIdx.y * 8 + blockIdx.x;
    const int h = combo >> 2;
    const int slice = combo & 3;
    const int n0 = blockIdx.z * 128;
    const int tid = threadIdx.x;
    const int w = tid >> 6, lane = tid & 63;
    const int l15 = lane & 15, quad = lane >> 4;

    // staging sb[2][4][4608] f16 (73728B), overlaid later by epilogue eb (37888B)
    __shared__ __align__(16) unsigned char smem_raw[73728];
    _Float16 (*sb)[4][4608] = (_Float16 (*)[4][4608])smem_raw;

    const int nbase = n0 + w * 32;                      // 32 rows per wave
    half8 qfr16[2];
#pragma unroll
    for (int rt = 0; rt < 2; rt++) {
        const int n = nbase + rt * 16 + l15;
        const float* qp = qf + (size_t)n * 256 + h * 32 + quad * 8;
#pragma unroll
        for (int j = 0; j < 8; j++) qfr16[rt][j] = (_Float16)qp[j];
    }
    float4v acc[2][9];
#pragma unroll
    for (int rt = 0; rt < 2; rt++)
#pragma unroll
        for (int ct = 0; ct < 9; ct++) acc[rt][ct] = float4v{0.f, 0.f, 0.f, 0.f};

    const int kt0 = slice * 100;
    const _Float16* mg0 = MG + (((size_t)kt0 * 8 + h) * 4608) + lane * 8;
    const _Float16* trg0 = trigA + (size_t)(nbase >> 5) * 16384 + (size_t)kt0 * 32 + l15;

#define STAGE4(b_, base_) { \
        const _Float16* src = mg0 + (size_t)((base_) + w) * 8 * 4608; \
        _Float16* dstl = &sb[b_][w][0]; \
        _Pragma("unroll") \
        for (int i = 0; i < 9; i++) \
            __builtin_amdgcn_global_load_lds( \
                (const __attribute__((address_space(1))) void*)(src + i * 512), \
                (__attribute__((address_space(3))) void*)(dstl + i * 512), 16, 0, 0); }

#define COMPUTE(kl) { \
        half8 tv0, tv1; \
        _Pragma("unroll") \
        for (int j = 0; j < 8; j++) { tv0[j] = ta[kl]; tv1[j] = tb[kl]; } \
        const half8 af0 = tv0 * qfr16[0]; \
        const half8 af1 = tv1 * qfr16[1]; \
        _Pragma("unroll") \
        for (int ct = 0; ct < 9; ct++) { \
            const half8 b = *(const half8*)&sb[cur][kl][ct * 512 + quad * 128 + l15 * 8]; \
            acc[0][ct] = __builtin_amdgcn_mfma_f32_16x16x32_f16(af0, b, acc[0][ct], 0, 0, 0); \
            acc[1][ct] = __builtin_amdgcn_mfma_f32_16x16x32_f16(af1, b, acc[1][ct], 0, 0, 0); \
        } }

    _Float16 ta[4], tb[4], ua[4], ub[4];
    int cur = 0;
    STAGE4(0, 0)
#pragma unroll
    for (int kl = 0; kl < 4; kl++) { ta[kl] = trg0[kl * 32]; tb[kl] = trg0[kl * 32 + 16]; }
    __syncthreads();

#pragma unroll 1
    for (int r = 0; r < 25; ++r) {
        if (r < 24) {
            STAGE4(cur ^ 1, (r + 1) * 4)
#pragma unroll
            for (int kl = 0; kl < 4; kl++) {
                const size_t o = (size_t)((r + 1) * 4 + kl) * 32;
                ua[kl] = trg0[o]; ub[kl] = trg0[o + 16];
            }
        }
        __builtin_amdgcn_s_setprio(1);
        COMPUTE(0) COMPUTE(1) COMPUTE(2) COMPUTE(3)
        __builtin_amdgcn_s_setprio(0);
        __syncthreads();
        cur ^= 1;
#pragma unroll
        for (int kl = 0; kl < 4; kl++) { ta[kl] = ua[kl]; tb[kl] = ub[kl]; }
    }

#undef STAGE4
#undef COMPUTE

    // epilogue: LDS transpose -> coalesced f16 stores into outp[slice][n][m][h*16+c]
    float* ebp = (float*)smem_raw;
    _Float16* dst = outp + (size_t)slice * 2359296;
    const int g4 = lane >> 2, sub = lane & 3;
#pragma unroll
    for (int rt = 0; rt < 2; rt++) {
        __syncthreads();
#pragma unroll
        for (int ct = 0; ct < 9; ct++) {
            const int cm = ct * 16 + l15;
            const int c = cm / 9, m = cm - c * 9;
#pragma unroll
            for (int r = 0; r < 4; r++)
                ebp[(size_t)(w * 16 + quad * 4 + r) * 148 + m * 16 + c] = acc[rt][ct][r];
        }
        __syncthreads();
#pragma unroll
        for (int s = 0; s < 9; s++) {
            const int li = s * 16 + g4;            // 0..143 line index
            const int nl = li / 9, m = li - nl * 9;
            const float4 v4 = *(const float4*)&ebp[(size_t)(w * 16 + nl) * 148 + m * 16 + sub * 4];
            const int n = nbase + rt * 16 + nl;
            const float rzv = rZ[(size_t)n * 8 + h];
            half4v hv;
            hv[0] = (_Float16)(v4.x * rzv); hv[1] = (_Float16)(v4.y * rzv);
            hv[2] = (_Float16)(v4.z * rzv); hv[3] = (_Float16)(v4.w * rzv);
            *(half4v*)&dst[((size_t)n * 9 + m) * 128 + h * 16 + sub * 4] = hv;
        }
    }
}

// ================================ launcher =================================
extern "C" void kernel_launch(void* const* d_in, const int* in_sizes, int n_in,
                              void* d_out, int out_size, void* d_ws, size_t ws_size,
                              hipStream_t stream) {
    const float* pos  = (const float*)d_in[0];
    const float* feat = (const float*)d_in[1];
    const float* Wq   = (const float*)d_in[2];
    const float* Wk   = (const float*)d_in[3];
    const float* Wv   = (const float*)d_in[4];
    const float* Wo   = (const float*)d_in[5];
    const float* a    = (const float*)d_in[6];
    const float* kap  = (const float*)d_in[7];
    float* out = (float*)d_out;
    float* ws = (float*)d_ws;

    // float-slot layout (~77.8 MB total)
    float* qf    = ws;                    // 524288
    float* kfAF  = qf + 524288;           // 262144 slots = kfA f16[8][64][2][512]
    float* vTF   = kfAF + 262144;         // 1179648 slots = v16T f16[1152*2048]
    float* trigF = vTF + 1179648;         // 524288 slots = trigA f16[64][512][32]
    float* ksum  = trigF + 524288;        // 256
    float* rz    = ksum + 256;            // 16384
    float* G     = rz + 16384;            // 129600
    float* M16F  = G + 129600;            // 9437184 slots = M16 f16[512*8*4608]; later outp f16[4][2359296]
    float* regX  = M16F + 9437184;        // 7372800 slots: R (first 1572864), later MG f16[400*8*4608]
    float* R     = regX;
    _Float16* trigA = (_Float16*)trigF;
    _Float16* kfA   = (_Float16*)kfAF;
    _Float16* v16T  = (_Float16*)vTF;
    _Float16* M16   = (_Float16*)M16F;
    _Float16* MG16  = (_Float16*)regX;
    _Float16* outp16 = (_Float16*)M16F;   // overlay: M16 dead after fold_k; 4 f16 partial buffers

    const float* cst = d_const_g;

    hipLaunchKernelGGL(radtrig_k, dim3(2048), dim3(256), 0, stream, feat, pos, kap, cst, R, trigA, ksum);
    hipLaunchKernelGGL(qk_gemm_k, dim3(8, 64), dim3(256), 0, stream, R, Wq, Wk, qf, kfA, ksum);
    hipLaunchKernelGGL(mfma_gemm16_k, dim3(2, 288), dim3(256), 0, stream, feat, Wv, vTF, 18432, 128, 256, 2, rz);
    hipLaunchKernelGGL(zg_k, dim3(128), dim3(256), 0, stream, qf, ksum, rz, a, cst, G);
    hipLaunchKernelGGL(multipole_mm_k, dim3(8, 9, 7), dim3(256), 0, stream, trigA, kfA, v16T, M16);
    hipLaunchKernelGGL(fold_k, dim3(400, 8), dim3(256), 0, stream, M16, G, MG16);
    hipLaunchKernelGGL(mm_local_k, dim3(8, 4, 16), dim3(256), 0, stream, qf, trigA, MG16, rz, outp16);
    hipLaunchKernelGGL(outg_k, dim3(2, 288), dim3(256), 0, stream, outp16, Wo, out);
}

// Round 14
// 276.539 us; speedup vs baseline: 1.2487x; 1.0187x over previous
//
#include <hip/hip_runtime.h>
#include <cmath>
#include <complex>
#include <algorithm>

// ---------------------------------------------------------------------------
// Problem constants: LMAX=2, NC=9, H=8, DQK=32, CV=16, K=8, U=25, N=2048, C=256
// ---------------------------------------------------------------------------

typedef _Float16 half8 __attribute__((ext_vector_type(8)));
typedef _Float16 half4v __attribute__((ext_vector_type(4)));
typedef float float4v __attribute__((ext_vector_type(4)));

// ========================= host-side constant tables ========================
namespace {

using cd = std::complex<double>;

static double fct(int n) { double r = 1.0; for (int i = 2; i <= n; ++i) r *= i; return r; }

static double cg_coef(int j1, int m1, int j2, int m2, int j, int m) {
    if (m1 + m2 != m || j < std::abs(j1 - j2) || j > j1 + j2) return 0.0;
    double pref = std::sqrt((2 * j + 1) * fct(j + j1 - j2) * fct(j - j1 + j2) * fct(j1 + j2 - j) / fct(j1 + j2 + j + 1));
    pref *= std::sqrt(fct(j + m) * fct(j - m) * fct(j1 - m1) * fct(j1 + m1) * fct(j2 - m2) * fct(j2 + m2));
    double s = 0.0;
    for (int k = 0; k <= j1 + j2 - j; ++k) {
        int d0 = k, d1 = j1 + j2 - j - k, d2 = j1 - m1 - k, d3 = j2 + m2 - k, d4 = j - j2 + m1 + k, d5 = j - j1 - m2 + k;
        if (d0 < 0 || d1 < 0 || d2 < 0 || d3 < 0 || d4 < 0 || d5 < 0) continue;
        s += ((k & 1) ? -1.0 : 1.0) / (fct(d0) * fct(d1) * fct(d2) * fct(d3) * fct(d4) * fct(d5));
    }
    return pref * s;
}

static void umat(int l, cd u[5][5]) {
    for (int i = 0; i < 5; i++) for (int j = 0; j < 5; j++) u[i][j] = cd(0, 0);
    const double s = 1.0 / std::sqrt(2.0);
    for (int m = -l; m <= l; m++) {
        double sgn = (std::abs(m) & 1) ? -1.0 : 1.0;   // (-1)^m
        if (m > 0)      { u[l + m][l + m] = cd(sgn * s, 0); u[l + m][l - m] = cd(s, 0); }
        else if (m == 0){ u[l][l] = cd(1, 0); }
        else            { u[l + m][l + m] = cd(0, s);       u[l + m][l - m] = cd(0, -sgn * s); }
    }
}

static void real_cg_f(int l1, int l2, int L, double out[5][5][5]) {
    cd U1[5][5], U2[5][5], UL[5][5];
    umat(l1, U1); umat(l2, U2); umat(L, UL);
    const int n1 = 2 * l1 + 1, n2 = 2 * l2 + 1, n3 = 2 * L + 1;
    double cgt[5][5][5];
    for (int i1 = 0; i1 < n1; i1++) for (int i2 = 0; i2 < n2; i2++) for (int i3 = 0; i3 < n3; i3++)
        cgt[i1][i2][i3] = cg_coef(l1, i1 - l1, l2, i2 - l2, L, i3 - L);
    cd r[5][5][5];
    double nr = 0, ni = 0;
    for (int a1 = 0; a1 < n1; a1++) for (int b = 0; b < n2; b++) for (int c = 0; c < n3; c++) {
        cd acc(0, 0);
        for (int uu = 0; uu < n1; uu++) for (int vv = 0; vv < n2; vv++) for (int w = 0; w < n3; w++) {
            double cval = cgt[uu][vv][w];
            if (cval == 0.0) continue;
            acc += U1[a1][uu] * U2[b][vv] * std::conj(UL[c][w]) * cval;
        }
        r[a1][b][c] = acc;
        nr += acc.real() * acc.real();
        ni += acc.imag() * acc.imag();
    }
    const bool useRe = std::sqrt(nr) >= std::sqrt(ni);
    for (int a1 = 0; a1 < n1; a1++) for (int b = 0; b < n2; b++) for (int c = 0; c < n3; c++)
        out[a1][b][c] = useRe ? r[a1][b][c].real() : r[a1][b][c].imag();
}

// device constant buffer layout: YW[9*25] | RRED[9*81] | DIRS[25*3]  = 1029 floats
static float  h_const[1029];
static float* d_const_g = nullptr;

struct GlobalInit {
    GlobalInit() {
        const double PI = 3.14159265358979323846;
        const double gx[5] = {-0.9061798459386640, -0.5384693101056831, 0.0, 0.5384693101056831, 0.9061798459386640};
        const double gw[5] = { 0.23692688505618908, 0.47862867049936647, 0.5688888888888889, 0.47862867049936647, 0.23692688505618908};
        double YW[9][25], DIRS[25][3];
        for (int u = 0; u < 25; ++u) {
            const int it = u / 5, ip = u % 5;
            const double ct = gx[it], wq = gw[it] * (2.0 * PI / 5.0), ph = 2.0 * PI * ip / 5.0;
            const double st = std::sqrt(std::max(1.0 - ct * ct, 0.0));
            const double x = st * std::cos(ph), y = st * std::sin(ph), z = ct;
            DIRS[u][0] = x; DIRS[u][1] = y; DIRS[u][2] = z;
            double Y[9];
            Y[0] = 0.282095;           Y[1] = 0.488603 * y;      Y[2] = 0.488603 * z;
            Y[3] = 0.488603 * x;       Y[4] = 1.092548 * x * y;  Y[5] = 1.092548 * y * z;
            Y[6] = 0.315392 * (3 * z * z - 1); Y[7] = 1.092548 * x * z; Y[8] = 0.546274 * (x * x - y * y);
            for (int e = 0; e < 9; e++) YW[e][u] = Y[e] * wq;
        }
        double RRED[9][9][9];
        for (int i = 0; i < 9; i++) for (int j = 0; j < 9; j++) for (int k = 0; k < 9; k++) RRED[i][j][k] = 0.0;
        const int off[3] = {0, 1, 4};
        double cnt[3] = {0, 0, 0};
        double rc[5][5][5];
        for (int l1 = 0; l1 <= 2; l1++) for (int l2 = 0; l2 <= 2; l2++) {
            const int Llo = std::abs(l1 - l2), Lhi = std::min(l1 + l2, 2);
            for (int L = Llo; L <= Lhi; L++) {
                real_cg_f(l1, l2, L, rc);
                for (int i1 = 0; i1 < 2 * l1 + 1; i1++)
                    for (int i2 = 0; i2 < 2 * l2 + 1; i2++)
                        for (int i3 = 0; i3 < 2 * L + 1; i3++)
                            RRED[off[l1] + i1][off[l2] + i2][off[L] + i3] += rc[i1][i2][i3];
                cnt[L] += 1.0;
            }
        }
        for (int L = 0; L <= 2; L++) {
            const double dv = std::max(cnt[L], 1.0);
            for (int a1 = 0; a1 < 9; a1++) for (int b = 0; b < 9; b++)
                for (int k = 0; k < 2 * L + 1; k++) RRED[a1][b][off[L] + k] /= dv;
        }
        for (int e = 0; e < 9; e++) for (int u = 0; u < 25; u++) h_const[e * 25 + u] = (float)YW[e][u];
        for (int e = 0; e < 9; e++) for (int l = 0; l < 9; l++) for (int m = 0; m < 9; m++)
            h_const[225 + e * 81 + l * 9 + m] = (float)RRED[e][l][m];
        for (int u = 0; u < 25; u++) for (int ax = 0; ax < 3; ax++) h_const[954 + u * 3 + ax] = (float)DIRS[u][ax];
        if (hipMalloc((void**)&d_const_g, 1029 * sizeof(float)) == hipSuccess)
            hipMemcpy(d_const_g, h_const, 1029 * sizeof(float), hipMemcpyHostToDevice);
    }
} g_init;

} // namespace

// ============================== device kernels ==============================

// merged radial + trig (R23, verified) + R25: block 0 zeroes ksum[256].
__global__ void radtrig_k(const float* __restrict__ feat, const float* __restrict__ pos,
                          const float* __restrict__ kappa, const float* __restrict__ cst,
                          float* __restrict__ R, _Float16* __restrict__ trigA,
                          float* __restrict__ ksum) {
    const int n = blockIdx.x, t = threadIdx.x;
    if (n == 0) ksum[t] = 0.f;
    {
        const float* f = feat + (size_t)n * 9 * 256 + t;
        const float f0 = f[0];
        const float a1 = f[256], a2 = f[512], a3 = f[768];
        const float b1 = f[1024], b2 = f[1280], b3 = f[1536], b4 = f[1792], b5 = f[2048];
        const float r1 = sqrtf(a1 * a1 + a2 * a2 + a3 * a3 + 1e-8f);
        const float r2 = sqrtf(b1 * b1 + b2 * b2 + b3 * b3 + b4 * b4 + b5 * b5 + 1e-8f);
        float* o = R + (size_t)n * 768 + t;
        o[0] = f0; o[256] = r1; o[512] = r2;
    }
    const size_t base = (size_t)(n >> 5) * 16384 + (n & 31);
    if (t < 200) {
        const int kq = t / 25, u = t - kq * 25;
        const float* dirs = cst + 954;
        const float ph = kappa[kq] * (pos[n * 3] * dirs[u * 3] + pos[n * 3 + 1] * dirs[u * 3 + 1] + pos[n * 3 + 2] * dirs[u * 3 + 2]);
        float s, c;
        sincosf(ph, &s, &c);
        const int kkut = (kq * 25 + u) * 2;
        trigA[base + (size_t)kkut * 32] = (_Float16)c;
        trigA[base + (size_t)(kkut + 1) * 32] = (_Float16)s;
    } else {
        const int kkut = 400 + (t - 200) * 2;
        trigA[base + (size_t)kkut * 32] = (_Float16)0.f;
        trigA[base + (size_t)(kkut + 1) * 32] = (_Float16)0.f;
    }
}

// fused Q/K projection GEMM (R24: 2 blocks/CU; R25: fused ksum — verified).
__global__ __launch_bounds__(256) void qk_gemm_k(const float* __restrict__ A,
                                                 const float* __restrict__ Wq,
                                                 const float* __restrict__ Wk,
                                                 float* __restrict__ qf,
                                                 _Float16* __restrict__ kfA,
                                                 float* __restrict__ ksum) {
    __shared__ __align__(16) _Float16 Af[32 * 40];
    __shared__ __align__(16) _Float16 Bf[64 * 40];
    __shared__ float kred[64];
    const int tid = threadIdx.x;
    const int w = tid >> 6, lane = tid & 63;
    const int l15 = lane & 15, quad = lane >> 4;
    const int rh = w & 1, ch = w >> 1;
    const bool isK = blockIdx.x >= 4;
    const int cb = (blockIdx.x & 3) * 64;
    const int rb = blockIdx.y * 32;
    const float* B = isK ? Wk : Wq;
    const int N = 256, Kd = 768;
    const int sra = tid >> 3, sqa = tid & 7;   // A stager: 32 rows x 8 k-quads
    const int srb = tid >> 2, sqb = tid & 3;   // B stager: 64 cols x 4 k-octets

    if (isK && tid < 64) kred[tid] = 0.f;

    float4v acc[2];
    acc[0] = float4v{0.f, 0.f, 0.f, 0.f};
    acc[1] = float4v{0.f, 0.f, 0.f, 0.f};

    for (int k0 = 0; k0 < Kd; k0 += 32) {
        __syncthreads();
        {
            const float* Ap = A + (size_t)(rb + sra) * Kd + k0 + sqa * 4;
            const float4 a0 = *(const float4*)(Ap);
            half4v hv;
            hv[0] = (_Float16)a0.x; hv[1] = (_Float16)a0.y; hv[2] = (_Float16)a0.z; hv[3] = (_Float16)a0.w;
            *(half4v*)&Af[sra * 40 + sqa * 4] = hv;
        }
        {
            const float* Bp = B + (size_t)(k0 + sqb * 8) * N + cb + srb;
            half8 hv;
#pragma unroll
            for (int i = 0; i < 8; i++) hv[i] = (_Float16)Bp[(size_t)i * N];
            *(half8*)&Bf[srb * 40 + sqb * 8] = hv;
        }
        __syncthreads();
        const half8 af = *(const half8*)&Af[(rh * 16 + l15) * 40 + quad * 8];
#pragma unroll
        for (int s = 0; s < 2; s++) {
            const half8 bf = *(const half8*)&Bf[(ch * 32 + s * 16 + l15) * 40 + quad * 8];
            acc[s] = __builtin_amdgcn_mfma_f32_16x16x32_f16(af, bf, acc[s], 0, 0, 0);
        }
    }
#pragma unroll
    for (int s = 0; s < 2; s++) {
        float colsum = 0.f;
#pragma unroll
        for (int r = 0; r < 4; r++) {
            const int row = rb + rh * 16 + quad * 4 + r;
            const int col = cb + ch * 32 + s * 16 + l15;
            float val = acc[s][r];
            val = (val > 0.f ? val : expf(val) - 1.f) + 1.f;
            if (isK) {
                const int hh = col >> 5, dd = col & 31, tt = dd >> 4, ll = dd & 15;
                const _Float16 h16 = (_Float16)val;
                kfA[(size_t)hh * 65536 + (size_t)(row >> 5) * 1024 + tt * 512 + ll * 32 + (row & 31)] = h16;
                colsum += (float)h16;
            } else {
                qf[(size_t)row * 256 + col] = val;
            }
        }
        if (isK) atomicAdd(&kred[ch * 32 + s * 16 + l15], colsum);
    }
    if (isK) {
        __syncthreads();
        if (tid < 64) atomicAdd(&ksum[cb + tid], kred[tid]);
    }
}

// V-GEMM + merged zg (R26): grid (2, 352).
//   blockIdx.y < 288: f16 MFMA GEMM, v16T f16 scatter (the R22-era mode 2).
//   blockIdx.y >= 288: 128 zg blocks (id = (y-288)*2 + x):
//     id < 64:  rz[n][h] = 1 / (qf[n,h,:].ksum[h,:] + 1e-6)
//     id >= 64: G[kk][h][u][l*9+m] = sum_e aE*YW*RRED
// Both halves depend only on qk outputs (qf/ksum) or raw inputs; rz/G are
// consumed by later kernels. Saves one dispatch + gap (R23/R25 mechanism).
__global__ __launch_bounds__(256) void vgemm_zg_k(const float* __restrict__ A, const float* __restrict__ B,
                                                  _Float16* __restrict__ v16T,
                                                  const float* __restrict__ qf, const float* __restrict__ ksum,
                                                  float* __restrict__ rz, const float* __restrict__ a,
                                                  const float* __restrict__ cst, float* __restrict__ G) {
    if (blockIdx.y >= 288) {
        const int zb = (blockIdx.y - 288) * 2 + blockIdx.x;   // 0..127
        if (zb < 64) {
            const int idx = zb * 256 + threadIdx.x;           // N*H = 16384
            const int n = idx >> 3, h = idx & 7;
            float s = 0.f;
#pragma unroll
            for (int d = 0; d < 32; d++) s += qf[(size_t)n * 256 + h * 32 + d] * ksum[h * 32 + d];
            rz[idx] = 1.0f / (s + 1e-6f);
        } else {
            const int b = zb - 64;
            const int kk = b & 7, h = b >> 3;
            __shared__ float ae[9];
            if (threadIdx.x < 9) {
                const int ldeg[9] = {0, 1, 1, 1, 2, 2, 2, 2, 2};
                ae[threadIdx.x] = a[ldeg[threadIdx.x] * 64 + h * 8 + kk];
            }
            __syncthreads();
            const float* yw = cst;
            const float* rred = cst + 225;
            for (int i = threadIdx.x; i < 25 * 81; i += 256) {
                const int u = i / 81, lm = i - u * 81;
                float s = 0.f;
#pragma unroll
                for (int e = 0; e < 9; e++) s += ae[e] * yw[e * 25 + u] * rred[e * 81 + lm];
                G[((size_t)(kk * 8 + h) * 25 + u) * 81 + lm] = s;
            }
        }
        return;
    }
    __shared__ __align__(16) _Float16 Af[64 * 40];   // [row][k], stride 40 halves (80 B)
    __shared__ __align__(16) _Float16 Bf[64 * 40];   // [col][k]
    const int tid = threadIdx.x;
    const int w = tid >> 6, lane = tid & 63;
    const int l15 = lane & 15, quad = lane >> 4;
    const int rb = blockIdx.y * 64, cb = blockIdx.x * 64;
    const int sr = tid >> 2, sq = tid & 3;           // stager: row/col 0..63, k-quartet 0..3
    const int N = 128, Kd = 256;

    float4v acc[4];
#pragma unroll
    for (int s = 0; s < 4; s++) acc[s] = float4v{0.f, 0.f, 0.f, 0.f};

    for (int k0 = 0; k0 < Kd; k0 += 32) {
        __syncthreads();
        // ---- stage A (f32 -> f16, fragment order) ----
        {
            const float* Ap = A + (size_t)(rb + sr) * Kd + k0 + sq * 8;
            const float4 a0 = *(const float4*)(Ap);
            const float4 a1 = *(const float4*)(Ap + 4);
            half8 hv;
            hv[0] = (_Float16)a0.x; hv[1] = (_Float16)a0.y; hv[2] = (_Float16)a0.z; hv[3] = (_Float16)a0.w;
            hv[4] = (_Float16)a1.x; hv[5] = (_Float16)a1.y; hv[6] = (_Float16)a1.z; hv[7] = (_Float16)a1.w;
            *(half8*)&Af[sr * 40 + sq * 8] = hv;
        }
        // ---- stage B (column gather; f32 -> f16) ----
        {
            const float* Bp = B + (size_t)(k0 + sq * 8) * N + cb + sr;
            half8 hv;
#pragma unroll
            for (int i = 0; i < 8; i++) hv[i] = (_Float16)Bp[(size_t)i * N];
            *(half8*)&Bf[sr * 40 + sq * 8] = hv;
        }
        __syncthreads();
        // ---- fragments + MFMA ----
        const half8 af = *(const half8*)&Af[(w * 16 + l15) * 40 + quad * 8];
#pragma unroll
        for (int s = 0; s < 4; s++) {
            const half8 bf = *(const half8*)&Bf[(s * 16 + l15) * 40 + quad * 8];
            acc[s] = __builtin_amdgcn_mfma_f32_16x16x32_f16(af, bf, acc[s], 0, 0, 0);
        }
    }
    // ---- epilogue: v16T[(h*144 + c*9 + l)][n] f16 scatter ----
#pragma unroll
    for (int s = 0; s < 4; s++) {
#pragma unroll
        for (int r = 0; r < 4; r++) {
            const int row = rb + w * 16 + quad * 4 + r;
            const int col = cb + s * 16 + l15;
            const int n = row / 9, l = row - n * 9, hq = col >> 4, cvq = col & 15;
            v16T[((size_t)hq * 144 + cvq * 9 + l) * 2048 + n] = (_Float16)acc[s][r];
        }
    }
}

// out-GEMM (R23, verified): C = (sum of 4 f16 partials)(18432x128) @ Wo(128x256)
// N-tile 128, grid (2,288) = 576 blocks = 2.25/CU.
__global__ __launch_bounds__(256) void outg_k(const _Float16* __restrict__ A, const float* __restrict__ B,
                                              float* __restrict__ Cv) {
    __shared__ __align__(16) _Float16 Af[64 * 40];    // [row][k]
    __shared__ __align__(16) _Float16 Bf[128 * 40];   // [col][k]
    const int tid = threadIdx.x;
    const int w = tid >> 6, lane = tid & 63;
    const int l15 = lane & 15, quad = lane >> 4;
    const int rb = blockIdx.y * 64, cb = blockIdx.x * 128;
    const int sr = tid >> 2, sq = tid & 3;            // stager: row/col 0..63, k-quartet 0..3
    const int N = 256, Kd = 128;

    float4v acc[8];
#pragma unroll
    for (int s = 0; s < 8; s++) acc[s] = float4v{0.f, 0.f, 0.f, 0.f};

    for (int k0 = 0; k0 < Kd; k0 += 32) {
        __syncthreads();
        // ---- stage A: 4-partial f32 sum -> f16 ----
        {
            const _Float16* Ap16 = A + (size_t)(rb + sr) * Kd + k0 + sq * 8;
            const half8 p0 = *(const half8*)(Ap16);
            const half8 p1 = *(const half8*)(Ap16 + 2359296);
            const half8 p2 = *(const half8*)(Ap16 + 4718592);
            const half8 p3 = *(const half8*)(Ap16 + 7077888);
            half8 hv;
#pragma unroll
            for (int i = 0; i < 8; i++)
                hv[i] = (_Float16)((float)p0[i] + (float)p1[i] + (float)p2[i] + (float)p3[i]);
            *(half8*)&Af[sr * 40 + sq * 8] = hv;
        }
        // ---- stage B: 128 cols (two passes of 64) ----
#pragma unroll
        for (int hf = 0; hf < 2; hf++) {
            const float* Bp = B + (size_t)(k0 + sq * 8) * N + cb + hf * 64 + sr;
            half8 hv;
#pragma unroll
            for (int i = 0; i < 8; i++) hv[i] = (_Float16)Bp[(size_t)i * N];
            *(half8*)&Bf[(hf * 64 + sr) * 40 + sq * 8] = hv;
        }
        __syncthreads();
        const half8 af = *(const half8*)&Af[(w * 16 + l15) * 40 + quad * 8];
#pragma unroll
        for (int s = 0; s < 8; s++) {
            const half8 bf = *(const half8*)&Bf[(s * 16 + l15) * 40 + quad * 8];
            acc[s] = __builtin_amdgcn_mfma_f32_16x16x32_f16(af, bf, acc[s], 0, 0, 0);
        }
    }
    // ---- epilogue: plain f32 C ----
#pragma unroll
    for (int s = 0; s < 8; s++) {
#pragma unroll
        for (int r = 0; r < 4; r++) {
            const int row = rb + w * 16 + quad * 4 + r;
            const int col = cb + s * 16 + l15;
            Cv[(size_t)row * N + col] = acc[s][r];
        }
    }
}

// MFMA multipole (R21 + R24 setprio, verified):
//   M16[kkut][h][cl*32+d] = sum_n trigA * kfA * v16T
// grid (8,9,7) = 504 blocks ~2/CU; LDS 56KB dbuf; h->XCD affinity.
__global__ __launch_bounds__(256, 2) void multipole_mm_k(const _Float16* __restrict__ trigA,
                                                         const _Float16* __restrict__ kfA,
                                                         const _Float16* __restrict__ v16T,
                                                         _Float16* __restrict__ M16) {
    const int h   = blockIdx.x;
    const int tid = threadIdx.x;
    const int w = tid >> 6, lane = tid & 63;
    const int l15 = lane & 15, quad = lane >> 4;
    const int cb  = blockIdx.y * 512 + w * 128;   // 4 cl per wave -> 128 cols
    const int cl0 = cb >> 5;
    const int r0  = blockIdx.z * 64;              // rows (kkut), 7*64 = 448

    __shared__ __align__(16) _Float16 sb[2][28][512];   // 56 KB

    float4v acc[4][8];
#pragma unroll
    for (int rt = 0; rt < 4; rt++)
#pragma unroll
        for (int s = 0; s < 8; s++) acc[rt][s] = float4v{0.f, 0.f, 0.f, 0.f};

    const _Float16* afg0 = trigA + (size_t)(r0 + l15) * 32 + quad * 8;            // + nb5*16384; +512/row-tile
    const _Float16* kqg0 = kfA + (size_t)h * 65536 + (size_t)l15 * 32 + quad * 8; // + nb5*1024
    const _Float16* kqg1 = kqg0 + 512;
    const int vs = lane >> 4, vc = (lane >> 2) & 3, vg = lane & 3;                // vq gather decomp
    const _Float16* vqg = v16T + (size_t)(h * 144 + cl0 + vc) * 2048 + vs * 32 + vg * 8; // + nbr

    half8 g0, g1, g2, g3, g4, g5, g6;

#define GATHER(nbr_) { \
        const size_t t5 = (size_t)((nbr_) >> 5) + w; \
        g0 = *(const half8*)(afg0 + t5 * 16384); \
        g1 = *(const half8*)(afg0 + t5 * 16384 + 512); \
        g2 = *(const half8*)(afg0 + t5 * 16384 + 1024); \
        g3 = *(const half8*)(afg0 + t5 * 16384 + 1536); \
        g4 = *(const half8*)(kqg0 + t5 * 1024); \
        g5 = *(const half8*)(kqg1 + t5 * 1024); \
        g6 = *(const half8*)(vqg + (nbr_)); }

#define DSWRITE(b_) { \
        *(half8*)&sb[b_][w * 6 + 0][lane * 8] = g0; \
        *(half8*)&sb[b_][w * 6 + 1][lane * 8] = g1; \
        *(half8*)&sb[b_][w * 6 + 2][lane * 8] = g2; \
        *(half8*)&sb[b_][w * 6 + 3][lane * 8] = g3; \
        *(half8*)&sb[b_][w * 6 + 4][lane * 8] = g4; \
        *(half8*)&sb[b_][w * 6 + 5][lane * 8] = g5; \
        *(half8*)&sb[b_][24 + w][lane * 8] = g6; }

#define STEP(s_) { \
        const half8 af0 = *(const half8*)&sb[cur][(s_) * 6 + 0][lane * 8]; \
        const half8 af1 = *(const half8*)&sb[cur][(s_) * 6 + 1][lane * 8]; \
        const half8 af2 = *(const half8*)&sb[cur][(s_) * 6 + 2][lane * 8]; \
        const half8 af3 = *(const half8*)&sb[cur][(s_) * 6 + 3][lane * 8]; \
        const half8 kq0 = *(const half8*)&sb[cur][(s_) * 6 + 4][lane * 8]; \
        const half8 kq1 = *(const half8*)&sb[cur][(s_) * 6 + 5][lane * 8]; \
        _Pragma("unroll") \
        for (int c = 0; c < 4; c++) { \
            const half8 vq = *(const half8*)&sb[cur][24 + w][((s_) * 4 + c) * 32 + quad * 8]; \
            const half8 b0 = kq0 * vq; \
            const half8 b1 = kq1 * vq; \
            acc[0][2 * c]     = __builtin_amdgcn_mfma_f32_16x16x32_f16(af0, b0, acc[0][2 * c],     0, 0, 0); \
            acc[0][2 * c + 1] = __builtin_amdgcn_mfma_f32_16x16x32_f16(af0, b1, acc[0][2 * c + 1], 0, 0, 0); \
            acc[1][2 * c]     = __builtin_amdgcn_mfma_f32_16x16x32_f16(af1, b0, acc[1][2 * c],     0, 0, 0); \
            acc[1][2 * c + 1] = __builtin_amdgcn_mfma_f32_16x16x32_f16(af1, b1, acc[1][2 * c + 1], 0, 0, 0); \
            acc[2][2 * c]     = __builtin_amdgcn_mfma_f32_16x16x32_f16(af2, b0, acc[2][2 * c],     0, 0, 0); \
            acc[2][2 * c + 1] = __builtin_amdgcn_mfma_f32_16x16x32_f16(af2, b1, acc[2][2 * c + 1], 0, 0, 0); \
            acc[3][2 * c]     = __builtin_amdgcn_mfma_f32_16x16x32_f16(af3, b0, acc[3][2 * c],     0, 0, 0); \
            acc[3][2 * c + 1] = __builtin_amdgcn_mfma_f32_16x16x32_f16(af3, b1, acc[3][2 * c + 1], 0, 0, 0); \
        } }

    int cur = 0;
    GATHER(0)
    DSWRITE(0)
    __syncthreads();
#pragma unroll 1
    for (int r = 0; r < 16; ++r) {
        if (r < 15) GATHER((r + 1) * 128)
        __builtin_amdgcn_s_setprio(1);
        STEP(0)
        STEP(1)
        STEP(2)
        STEP(3)
        __builtin_amdgcn_s_setprio(0);
        if (r < 15) DSWRITE(cur ^ 1)
        __syncthreads();
        cur ^= 1;
    }

#undef GATHER
#undef DSWRITE
#undef STEP

    // epilogue: C fragment -> M16[kkut][h][col]
#pragma unroll
    for (int rt = 0; rt < 4; rt++)
#pragma unroll
        for (int c = 0; c < 4; c++)
#pragma unroll
            for (int half = 0; half < 2; half++)
#pragma unroll
                for (int r = 0; r < 4; r++) {
                    const int row = r0 + rt * 16 + quad * 4 + r;
                    const int col = cb + c * 32 + half * 16 + l15;
                    M16[((size_t)row * 8 + h) * 4608 + col] = (_Float16)acc[rt][c * 2 + half][r];
                }
}

// MG[kt][h][...] = sum_l M16 * G  (R22 vectorized LDS path; R26: grid (8,400)
// with h = blockIdx.x so linear%8 = h -> fold readers land on the XCD whose
// L2 holds multipole's M16 writes for that head (R12 affinity mechanism);
// old (400,8) scattered each head's readers across all 8 XCDs).
__global__ __launch_bounds__(256) void fold_k(const _Float16* __restrict__ Mv, const float* __restrict__ G,
                                              _Float16* __restrict__ MG) {
    const int h = blockIdx.x, kt = blockIdx.y;
    const int tid = threadIdx.x;
    __shared__ __align__(16) _Float16 ms16[144 * 40];   // [cl][d], stride 40 halves (80 B)
    __shared__ float gs[81];
    const _Float16* src = Mv + ((size_t)kt * 8 + h) * 4608;
    for (int o = tid; o < 576; o += 256) {
        const half8 v = *(const half8*)(src + o * 8);
        *(half8*)&ms16[(o >> 2) * 40 + (o & 3) * 8] = v;
    }
    const int kk = kt / 50, u = (kt >> 1) % 25;
    if (tid < 81) gs[tid] = G[(((size_t)kk * 8 + h) * 25 + u) * 81 + tid];
    __syncthreads();
    _Float16* dst = MG + ((size_t)kt * 8 + h) * 4608;
    for (int o = tid; o < 576; o += 256) {
        const int i0 = o * 8;
        const int ct = i0 >> 9, quad = (i0 >> 7) & 3, l15 = (i0 >> 3) & 15;
        const int d0 = quad * 8;
        const int cm = ct * 16 + l15, c = cm / 9, m = cm - c * 9;
        float s0 = 0.f, s1 = 0.f, s2 = 0.f, s3 = 0.f, s4 = 0.f, s5 = 0.f, s6 = 0.f, s7 = 0.f;
#pragma unroll
        for (int l = 0; l < 9; l++) {
            const float g = gs[l * 9 + m];
            const half8 mv = *(const half8*)&ms16[(c * 9 + l) * 40 + d0];
            s0 += (float)mv[0] * g; s1 += (float)mv[1] * g;
            s2 += (float)mv[2] * g; s3 += (float)mv[3] * g;
            s4 += (float)mv[4] * g; s5 += (float)mv[5] * g;
            s6 += (float)mv[6] * g; s7 += (float)mv[7] * g;
        }
        half8 hv;
        hv[0] = (_Float16)s0; hv[1] = (_Float16)s1; hv[2] = (_Float16)s2; hv[3] = (_Float16)s3;
        hv[4] = (_Float16)s4; hv[5] = (_Float16)s5; hv[6] = (_Float16)s6; hv[7] = (_Float16)s7;
        *(half8*)(dst + i0) = hv;
    }
}

// local stage via MFMA (R20 config + R24 setprio, verified):
// R15 geometry (32 rows/wave, 4 slices x 100kt, 2 blk/CU, 4-kt rounds) +
// f16 partial writes + rz in f32 epilogue. grid (8,4,16) = 512 = 2/CU.
__global__ __launch_bounds__(256, 2) void mm_local_k(const float* __restrict__ qf, const _Float16* __restrict__ trigA,
                                                     const _Float16* __restrict__ MG, const float* __restrict__ rZ,
                                                     _Float16* __restrict__ outp) {
    const int combo = blockIdx.y * 8 + blockIdx.x;
    const int h = combo >> 2;
    const int slice = combo & 3;
    const int n0 = blockIdx.z * 128;
    const int tid = threadIdx.x;
    const int w = tid >> 6, lane = tid & 63;
    const int l15 = lane & 15, quad = lane >> 4;

    // staging sb[2][4][4608] f16 (73728B), overlaid later by epilogue eb (37888B)
    __shared__ __align__(16) unsigned char smem_raw[73728];
    _Float16 (*sb)[4][4608] = (_Float16 (*)[4][4608])smem_raw;

    const int nbase = n0 + w * 32;                      // 32 rows per wave
    half8 qfr16[2];
#pragma unroll
    for (int rt = 0; rt < 2; rt++) {
        const int n = nbase + rt * 16 + l15;
        const float* qp = qf + (size_t)n * 256 + h * 32 + quad * 8;
#pragma unroll
        for (int j = 0; j < 8; j++) qfr16[rt][j] = (_Float16)qp[j];
    }
    float4v acc[2][9];
#pragma unroll
    for (int rt = 0; rt < 2; rt++)
#pragma unroll
        for (int ct = 0; ct < 9; ct++) acc[rt][ct] = float4v{0.f, 0.f, 0.f, 0.f};

    const int kt0 = slice * 100;
    const _Float16* mg0 = MG + (((size_t)kt0 * 8 + h) * 4608) + lane * 8;
    const _Float16* trg0 = trigA + (size_t)(nbase >> 5) * 16384 + (size_t)kt0 * 32 + l15;

#define STAGE4(b_, base_) { \
        const _Float16* src = mg0 + (size_t)((base_) + w) * 8 * 4608; \
        _Float16* dstl = &sb[b_][w][0]; \
        _Pragma("unroll") \
        for (int i = 0; i < 9; i++) \
            __builtin_amdgcn_global_load_lds( \
                (const __attribute__((address_space(1))) void*)(src + i * 512), \
                (__attribute__((address_space(3))) void*)(dstl + i * 512), 16, 0, 0); }

#define COMPUTE(kl) { \
        half8 tv0, tv1; \
        _Pragma("unroll") \
        for (int j = 0; j < 8; j++) { tv0[j] = ta[kl]; tv1[j] = tb[kl]; } \
        const half8 af0 = tv0 * qfr16[0]; \
        const half8 af1 = tv1 * qfr16[1]; \
        _Pragma("unroll") \
        for (int ct = 0; ct < 9; ct++) { \
            const half8 b = *(const half8*)&sb[cur][kl][ct * 512 + quad * 128 + l15 * 8]; \
            acc[0][ct] = __builtin_amdgcn_mfma_f32_16x16x32_f16(af0, b, acc[0][ct], 0, 0, 0); \
            acc[1][ct] = __builtin_amdgcn_mfma_f32_16x16x32_f16(af1, b, acc[1][ct], 0, 0, 0); \
        } }

    _Float16 ta[4], tb[4], ua[4], ub[4];
    int cur = 0;
    STAGE4(0, 0)
#pragma unroll
    for (int kl = 0; kl < 4; kl++) { ta[kl] = trg0[kl * 32]; tb[kl] = trg0[kl * 32 + 16]; }
    __syncthreads();

#pragma unroll 1
    for (int r = 0; r < 25; ++r) {
        if (r < 24) {
            STAGE4(cur ^ 1, (r + 1) * 4)
#pragma unroll
            for (int kl = 0; kl < 4; kl++) {
                const size_t o = (size_t)((r + 1) * 4 + kl) * 32;
                ua[kl] = trg0[o]; ub[kl] = trg0[o + 16];
            }
        }
        __builtin_amdgcn_s_setprio(1);
        COMPUTE(0) COMPUTE(1) COMPUTE(2) COMPUTE(3)
        __builtin_amdgcn_s_setprio(0);
        __syncthreads();
        cur ^= 1;
#pragma unroll
        for (int kl = 0; kl < 4; kl++) { ta[kl] = ua[kl]; tb[kl] = ub[kl]; }
    }

#undef STAGE4
#undef COMPUTE

    // epilogue: LDS transpose -> coalesced f16 stores into outp[slice][n][m][h*16+c]
    float* ebp = (float*)smem_raw;
    _Float16* dst = outp + (size_t)slice * 2359296;
    const int g4 = lane >> 2, sub = lane & 3;
#pragma unroll
    for (int rt = 0; rt < 2; rt++) {
        __syncthreads();
#pragma unroll
        for (int ct = 0; ct < 9; ct++) {
            const int cm = ct * 16 + l15;
            const int c = cm / 9, m = cm - c * 9;
#pragma unroll
            for (int r = 0; r < 4; r++)
                ebp[(size_t)(w * 16 + quad * 4 + r) * 148 + m * 16 + c] = acc[rt][ct][r];
        }
        __syncthreads();
#pragma unroll
        for (int s = 0; s < 9; s++) {
            const int li = s * 16 + g4;            // 0..143 line index
            const int nl = li / 9, m = li - nl * 9;
            const float4 v4 = *(const float4*)&ebp[(size_t)(w * 16 + nl) * 148 + m * 16 + sub * 4];
            const int n = nbase + rt * 16 + nl;
            const float rzv = rZ[(size_t)n * 8 + h];
            half4v hv;
            hv[0] = (_Float16)(v4.x * rzv); hv[1] = (_Float16)(v4.y * rzv);
            hv[2] = (_Float16)(v4.z * rzv); hv[3] = (_Float16)(v4.w * rzv);
            *(half4v*)&dst[((size_t)n * 9 + m) * 128 + h * 16 + sub * 4] = hv;
        }
    }
}

// ================================ launcher =================================
extern "C" void kernel_launch(void* const* d_in, const int* in_sizes, int n_in,
                              void* d_out, int out_size, void* d_ws, size_t ws_size,
                              hipStream_t stream) {
    const float* pos  = (const float*)d_in[0];
    const float* feat = (const float*)d_in[1];
    const float* Wq   = (const float*)d_in[2];
    const float* Wk   = (const float*)d_in[3];
    const float* Wv   = (const float*)d_in[4];
    const float* Wo   = (const float*)d_in[5];
    const float* a    = (const float*)d_in[6];
    const float* kap  = (const float*)d_in[7];
    float* out = (float*)d_out;
    float* ws = (float*)d_ws;

    // float-slot layout (~77.8 MB total)
    float* qf    = ws;                    // 524288
    float* kfAF  = qf + 524288;           // 262144 slots = kfA f16[8][64][2][512]
    float* vTF   = kfAF + 262144;         // 1179648 slots = v16T f16[1152*2048]
    float* trigF = vTF + 1179648;         // 524288 slots = trigA f16[64][512][32]
    float* ksum  = trigF + 524288;        // 256
    float* rz    = ksum + 256;            // 16384
    float* G     = rz + 16384;            // 129600
    float* M16F  = G + 129600;            // 9437184 slots = M16 f16[512*8*4608]; later outp f16[4][2359296]
    float* regX  = M16F + 9437184;        // 7372800 slots: R (first 1572864), later MG f16[400*8*4608]
    float* R     = regX;
    _Float16* trigA = (_Float16*)trigF;
    _Float16* kfA   = (_Float16*)kfAF;
    _Float16* v16T  = (_Float16*)vTF;
    _Float16* M16   = (_Float16*)M16F;
    _Float16* MG16  = (_Float16*)regX;
    _Float16* outp16 = (_Float16*)M16F;   // overlay: M16 dead after fold_k; 4 f16 partial buffers

    const float* cst = d_const_g;

    hipLaunchKernelGGL(radtrig_k, dim3(2048), dim3(256), 0, stream, feat, pos, kap, cst, R, trigA, ksum);
    hipLaunchKernelGGL(qk_gemm_k, dim3(8, 64), dim3(256), 0, stream, R, Wq, Wk, qf, kfA, ksum);
    hipLaunchKernelGGL(vgemm_zg_k, dim3(2, 352), dim3(256), 0, stream, feat, Wv, v16T, qf, ksum, rz, a, cst, G);
    hipLaunchKernelGGL(multipole_mm_k, dim3(8, 9, 7), dim3(256), 0, stream, trigA, kfA, v16T, M16);
    hipLaunchKernelGGL(fold_k, dim3(8, 400), dim3(256), 0, stream, M16, G, MG16);
    hipLaunchKernelGGL(mm_local_k, dim3(8, 4, 16), dim3(256), 0, stream, qf, trigA, MG16, rz, outp16);
    hipLaunchKernelGGL(outg_k, dim3(2, 288), dim3(256), 0, stream, outp16, Wo, out);
}

// Round 15
// 264.623 us; speedup vs baseline: 1.3049x; 1.0450x over previous
//
#include <hip/hip_runtime.h>
#include <cmath>
#include <complex>
#include <algorithm>

// ---------------------------------------------------------------------------
// Problem constants: LMAX=2, NC=9, H=8, DQK=32, CV=16, K=8, U=25, N=2048, C=256
// ---------------------------------------------------------------------------

typedef _Float16 half8 __attribute__((ext_vector_type(8)));
typedef _Float16 half4v __attribute__((ext_vector_type(4)));
typedef float float4v __attribute__((ext_vector_type(4)));

// ========================= host-side constant tables ========================
namespace {

using cd = std::complex<double>;

static double fct(int n) { double r = 1.0; for (int i = 2; i <= n; ++i) r *= i; return r; }

static double cg_coef(int j1, int m1, int j2, int m2, int j, int m) {
    if (m1 + m2 != m || j < std::abs(j1 - j2) || j > j1 + j2) return 0.0;
    double pref = std::sqrt((2 * j + 1) * fct(j + j1 - j2) * fct(j - j1 + j2) * fct(j1 + j2 - j) / fct(j1 + j2 + j + 1));
    pref *= std::sqrt(fct(j + m) * fct(j - m) * fct(j1 - m1) * fct(j1 + m1) * fct(j2 - m2) * fct(j2 + m2));
    double s = 0.0;
    for (int k = 0; k <= j1 + j2 - j; ++k) {
        int d0 = k, d1 = j1 + j2 - j - k, d2 = j1 - m1 - k, d3 = j2 + m2 - k, d4 = j - j2 + m1 + k, d5 = j - j1 - m2 + k;
        if (d0 < 0 || d1 < 0 || d2 < 0 || d3 < 0 || d4 < 0 || d5 < 0) continue;
        s += ((k & 1) ? -1.0 : 1.0) / (fct(d0) * fct(d1) * fct(d2) * fct(d3) * fct(d4) * fct(d5));
    }
    return pref * s;
}

static void umat(int l, cd u[5][5]) {
    for (int i = 0; i < 5; i++) for (int j = 0; j < 5; j++) u[i][j] = cd(0, 0);
    const double s = 1.0 / std::sqrt(2.0);
    for (int m = -l; m <= l; m++) {
        double sgn = (std::abs(m) & 1) ? -1.0 : 1.0;   // (-1)^m
        if (m > 0)      { u[l + m][l + m] = cd(sgn * s, 0); u[l + m][l - m] = cd(s, 0); }
        else if (m == 0){ u[l][l] = cd(1, 0); }
        else            { u[l + m][l + m] = cd(0, s);       u[l + m][l - m] = cd(0, -sgn * s); }
    }
}

static void real_cg_f(int l1, int l2, int L, double out[5][5][5]) {
    cd U1[5][5], U2[5][5], UL[5][5];
    umat(l1, U1); umat(l2, U2); umat(L, UL);
    const int n1 = 2 * l1 + 1, n2 = 2 * l2 + 1, n3 = 2 * L + 1;
    double cgt[5][5][5];
    for (int i1 = 0; i1 < n1; i1++) for (int i2 = 0; i2 < n2; i2++) for (int i3 = 0; i3 < n3; i3++)
        cgt[i1][i2][i3] = cg_coef(l1, i1 - l1, l2, i2 - l2, L, i3 - L);
    cd r[5][5][5];
    double nr = 0, ni = 0;
    for (int a1 = 0; a1 < n1; a1++) for (int b = 0; b < n2; b++) for (int c = 0; c < n3; c++) {
        cd acc(0, 0);
        for (int uu = 0; uu < n1; uu++) for (int vv = 0; vv < n2; vv++) for (int w = 0; w < n3; w++) {
            double cval = cgt[uu][vv][w];
            if (cval == 0.0) continue;
            acc += U1[a1][uu] * U2[b][vv] * std::conj(UL[c][w]) * cval;
        }
        r[a1][b][c] = acc;
        nr += acc.real() * acc.real();
        ni += acc.imag() * acc.imag();
    }
    const bool useRe = std::sqrt(nr) >= std::sqrt(ni);
    for (int a1 = 0; a1 < n1; a1++) for (int b = 0; b < n2; b++) for (int c = 0; c < n3; c++)
        out[a1][b][c] = useRe ? r[a1][b][c].real() : r[a1][b][c].imag();
}

// device constant buffer layout: YW[9*25] | RRED[9*81] | DIRS[25*3]  = 1029 floats
static float  h_const[1029];
static float* d_const_g = nullptr;

struct GlobalInit {
    GlobalInit() {
        const double PI = 3.14159265358979323846;
        const double gx[5] = {-0.9061798459386640, -0.5384693101056831, 0.0, 0.5384693101056831, 0.9061798459386640};
        const double gw[5] = { 0.23692688505618908, 0.47862867049936647, 0.5688888888888889, 0.47862867049936647, 0.23692688505618908};
        double YW[9][25], DIRS[25][3];
        for (int u = 0; u < 25; ++u) {
            const int it = u / 5, ip = u % 5;
            const double ct = gx[it], wq = gw[it] * (2.0 * PI / 5.0), ph = 2.0 * PI * ip / 5.0;
            const double st = std::sqrt(std::max(1.0 - ct * ct, 0.0));
            const double x = st * std::cos(ph), y = st * std::sin(ph), z = ct;
            DIRS[u][0] = x; DIRS[u][1] = y; DIRS[u][2] = z;
            double Y[9];
            Y[0] = 0.282095;           Y[1] = 0.488603 * y;      Y[2] = 0.488603 * z;
            Y[3] = 0.488603 * x;       Y[4] = 1.092548 * x * y;  Y[5] = 1.092548 * y * z;
            Y[6] = 0.315392 * (3 * z * z - 1); Y[7] = 1.092548 * x * z; Y[8] = 0.546274 * (x * x - y * y);
            for (int e = 0; e < 9; e++) YW[e][u] = Y[e] * wq;
        }
        double RRED[9][9][9];
        for (int i = 0; i < 9; i++) for (int j = 0; j < 9; j++) for (int k = 0; k < 9; k++) RRED[i][j][k] = 0.0;
        const int off[3] = {0, 1, 4};
        double cnt[3] = {0, 0, 0};
        double rc[5][5][5];
        for (int l1 = 0; l1 <= 2; l1++) for (int l2 = 0; l2 <= 2; l2++) {
            const int Llo = std::abs(l1 - l2), Lhi = std::min(l1 + l2, 2);
            for (int L = Llo; L <= Lhi; L++) {
                real_cg_f(l1, l2, L, rc);
                for (int i1 = 0; i1 < 2 * l1 + 1; i1++)
                    for (int i2 = 0; i2 < 2 * l2 + 1; i2++)
                        for (int i3 = 0; i3 < 2 * L + 1; i3++)
                            RRED[off[l1] + i1][off[l2] + i2][off[L] + i3] += rc[i1][i2][i3];
                cnt[L] += 1.0;
            }
        }
        for (int L = 0; L <= 2; L++) {
            const double dv = std::max(cnt[L], 1.0);
            for (int a1 = 0; a1 < 9; a1++) for (int b = 0; b < 9; b++)
                for (int k = 0; k < 2 * L + 1; k++) RRED[a1][b][off[L] + k] /= dv;
        }
        for (int e = 0; e < 9; e++) for (int u = 0; u < 25; u++) h_const[e * 25 + u] = (float)YW[e][u];
        for (int e = 0; e < 9; e++) for (int l = 0; l < 9; l++) for (int m = 0; m < 9; m++)
            h_const[225 + e * 81 + l * 9 + m] = (float)RRED[e][l][m];
        for (int u = 0; u < 25; u++) for (int ax = 0; ax < 3; ax++) h_const[954 + u * 3 + ax] = (float)DIRS[u][ax];
        if (hipMalloc((void**)&d_const_g, 1029 * sizeof(float)) == hipSuccess)
            hipMemcpy(d_const_g, h_const, 1029 * sizeof(float), hipMemcpyHostToDevice);
    }
} g_init;

} // namespace

// ============================== device kernels ==============================

// merged radial + trig (R23, verified) + R25: block 0 zeroes ksum[256].
__global__ void radtrig_k(const float* __restrict__ feat, const float* __restrict__ pos,
                          const float* __restrict__ kappa, const float* __restrict__ cst,
                          float* __restrict__ R, _Float16* __restrict__ trigA,
                          float* __restrict__ ksum) {
    const int n = blockIdx.x, t = threadIdx.x;
    if (n == 0) ksum[t] = 0.f;
    {
        const float* f = feat + (size_t)n * 9 * 256 + t;
        const float f0 = f[0];
        const float a1 = f[256], a2 = f[512], a3 = f[768];
        const float b1 = f[1024], b2 = f[1280], b3 = f[1536], b4 = f[1792], b5 = f[2048];
        const float r1 = sqrtf(a1 * a1 + a2 * a2 + a3 * a3 + 1e-8f);
        const float r2 = sqrtf(b1 * b1 + b2 * b2 + b3 * b3 + b4 * b4 + b5 * b5 + 1e-8f);
        float* o = R + (size_t)n * 768 + t;
        o[0] = f0; o[256] = r1; o[512] = r2;
    }
    const size_t base = (size_t)(n >> 5) * 16384 + (n & 31);
    if (t < 200) {
        const int kq = t / 25, u = t - kq * 25;
        const float* dirs = cst + 954;
        const float ph = kappa[kq] * (pos[n * 3] * dirs[u * 3] + pos[n * 3 + 1] * dirs[u * 3 + 1] + pos[n * 3 + 2] * dirs[u * 3 + 2]);
        float s, c;
        sincosf(ph, &s, &c);
        const int kkut = (kq * 25 + u) * 2;
        trigA[base + (size_t)kkut * 32] = (_Float16)c;
        trigA[base + (size_t)(kkut + 1) * 32] = (_Float16)s;
    } else {
        const int kkut = 400 + (t - 200) * 2;
        trigA[base + (size_t)kkut * 32] = (_Float16)0.f;
        trigA[base + (size_t)(kkut + 1) * 32] = (_Float16)0.f;
    }
}

// merged Q/K + V projection GEMMs (R27): grid(1088), 1D.
//   bid < 512:  qk path (R24 2-blk/CU geometry + R25 fused ksum): bx=bid&7,
//               by=bid>>3; bx<4 -> Wq (qf f32), bx>=4 -> Wk (kfA f16 + ksum).
//   bid >= 512: V-GEMM path (R22/R26 mode-2): vb=bid-512, cb=(vb&1)*64,
//               rb=(vb>>1)*64; v16T f16 scatter.
// Legal same-dispatch merge: qk needs only R (radtrig), V needs only feat/Wv.
// Saves one dispatch + gap (R23/R25 mechanism). LDS unioned in one buffer.
__global__ __launch_bounds__(256) void qkv_gemm_k(const float* __restrict__ Rr,
                                                  const float* __restrict__ Wq,
                                                  const float* __restrict__ Wk,
                                                  const float* __restrict__ feat,
                                                  const float* __restrict__ Wv,
                                                  float* __restrict__ qf,
                                                  _Float16* __restrict__ kfA,
                                                  float* __restrict__ ksum,
                                                  _Float16* __restrict__ v16T) {
    __shared__ __align__(16) unsigned char smem[10496];
    const int bid = blockIdx.x;
    const int tid = threadIdx.x;
    const int w = tid >> 6, lane = tid & 63;
    const int l15 = lane & 15, quad = lane >> 4;

    if (bid < 512) {
        // ---------------- qk path ----------------
        _Float16* Af = (_Float16*)smem;                 // 32*40 halves (2560 B)
        _Float16* Bf = (_Float16*)(smem + 2560);        // 64*40 halves (5120 B)
        float* kred = (float*)(smem + 7680);            // 64 floats (256 B)
        const int bx = bid & 7, by = bid >> 3;
        const int rh = w & 1, ch = w >> 1;
        const bool isK = bx >= 4;
        const int cb = (bx & 3) * 64;
        const int rb = by * 32;
        const float* B = isK ? Wk : Wq;
        const int N = 256, Kd = 768;
        const int sra = tid >> 3, sqa = tid & 7;   // A stager: 32 rows x 8 k-quads
        const int srb = tid >> 2, sqb = tid & 3;   // B stager: 64 cols x 4 k-octets

        if (isK && tid < 64) kred[tid] = 0.f;

        float4v acc[2];
        acc[0] = float4v{0.f, 0.f, 0.f, 0.f};
        acc[1] = float4v{0.f, 0.f, 0.f, 0.f};

        for (int k0 = 0; k0 < Kd; k0 += 32) {
            __syncthreads();
            {
                const float* Ap = Rr + (size_t)(rb + sra) * Kd + k0 + sqa * 4;
                const float4 a0 = *(const float4*)(Ap);
                half4v hv;
                hv[0] = (_Float16)a0.x; hv[1] = (_Float16)a0.y; hv[2] = (_Float16)a0.z; hv[3] = (_Float16)a0.w;
                *(half4v*)&Af[sra * 40 + sqa * 4] = hv;
            }
            {
                const float* Bp = B + (size_t)(k0 + sqb * 8) * N + cb + srb;
                half8 hv;
#pragma unroll
                for (int i = 0; i < 8; i++) hv[i] = (_Float16)Bp[(size_t)i * N];
                *(half8*)&Bf[srb * 40 + sqb * 8] = hv;
            }
            __syncthreads();
            const half8 af = *(const half8*)&Af[(rh * 16 + l15) * 40 + quad * 8];
#pragma unroll
            for (int s = 0; s < 2; s++) {
                const half8 bf = *(const half8*)&Bf[(ch * 32 + s * 16 + l15) * 40 + quad * 8];
                acc[s] = __builtin_amdgcn_mfma_f32_16x16x32_f16(af, bf, acc[s], 0, 0, 0);
            }
        }
#pragma unroll
        for (int s = 0; s < 2; s++) {
            float colsum = 0.f;
#pragma unroll
            for (int r = 0; r < 4; r++) {
                const int row = rb + rh * 16 + quad * 4 + r;
                const int col = cb + ch * 32 + s * 16 + l15;
                float val = acc[s][r];
                val = (val > 0.f ? val : expf(val) - 1.f) + 1.f;
                if (isK) {
                    const int hh = col >> 5, dd = col & 31, tt = dd >> 4, ll = dd & 15;
                    const _Float16 h16 = (_Float16)val;
                    kfA[(size_t)hh * 65536 + (size_t)(row >> 5) * 1024 + tt * 512 + ll * 32 + (row & 31)] = h16;
                    colsum += (float)h16;
                } else {
                    qf[(size_t)row * 256 + col] = val;
                }
            }
            if (isK) atomicAdd(&kred[ch * 32 + s * 16 + l15], colsum);
        }
        if (isK) {
            __syncthreads();
            if (tid < 64) atomicAdd(&ksum[cb + tid], kred[tid]);
        }
        return;
    }

    // ---------------- V-GEMM path ----------------
    _Float16* Af = (_Float16*)smem;                 // 64*40 halves
    _Float16* Bf = (_Float16*)(smem + 5120);        // 64*40 halves
    const int vb = bid - 512;
    const int cb = (vb & 1) * 64, rb = (vb >> 1) * 64;
    const int sr = tid >> 2, sq = tid & 3;
    const int N = 128, Kd = 256;

    float4v acc[4];
#pragma unroll
    for (int s = 0; s < 4; s++) acc[s] = float4v{0.f, 0.f, 0.f, 0.f};

    for (int k0 = 0; k0 < Kd; k0 += 32) {
        __syncthreads();
        {
            const float* Ap = feat + (size_t)(rb + sr) * Kd + k0 + sq * 8;
            const float4 a0 = *(const float4*)(Ap);
            const float4 a1 = *(const float4*)(Ap + 4);
            half8 hv;
            hv[0] = (_Float16)a0.x; hv[1] = (_Float16)a0.y; hv[2] = (_Float16)a0.z; hv[3] = (_Float16)a0.w;
            hv[4] = (_Float16)a1.x; hv[5] = (_Float16)a1.y; hv[6] = (_Float16)a1.z; hv[7] = (_Float16)a1.w;
            *(half8*)&Af[sr * 40 + sq * 8] = hv;
        }
        {
            const float* Bp = Wv + (size_t)(k0 + sq * 8) * N + cb + sr;
            half8 hv;
#pragma unroll
            for (int i = 0; i < 8; i++) hv[i] = (_Float16)Bp[(size_t)i * N];
            *(half8*)&Bf[sr * 40 + sq * 8] = hv;
        }
        __syncthreads();
        const half8 af = *(const half8*)&Af[(w * 16 + l15) * 40 + quad * 8];
#pragma unroll
        for (int s = 0; s < 4; s++) {
            const half8 bf = *(const half8*)&Bf[(s * 16 + l15) * 40 + quad * 8];
            acc[s] = __builtin_amdgcn_mfma_f32_16x16x32_f16(af, bf, acc[s], 0, 0, 0);
        }
    }
#pragma unroll
    for (int s = 0; s < 4; s++) {
#pragma unroll
        for (int r = 0; r < 4; r++) {
            const int row = rb + w * 16 + quad * 4 + r;
            const int col = cb + s * 16 + l15;
            const int n = row / 9, l = row - n * 9, hq = col >> 4, cvq = col & 15;
            v16T[((size_t)hq * 144 + cvq * 9 + l) * 2048 + n] = (_Float16)acc[s][r];
        }
    }
}

// out-GEMM (R23, verified): C = (sum of 4 f16 partials)(18432x128) @ Wo(128x256)
// N-tile 128, grid (2,288) = 576 blocks = 2.25/CU.
__global__ __launch_bounds__(256) void outg_k(const _Float16* __restrict__ A, const float* __restrict__ B,
                                              float* __restrict__ Cv) {
    __shared__ __align__(16) _Float16 Af[64 * 40];    // [row][k]
    __shared__ __align__(16) _Float16 Bf[128 * 40];   // [col][k]
    const int tid = threadIdx.x;
    const int w = tid >> 6, lane = tid & 63;
    const int l15 = lane & 15, quad = lane >> 4;
    const int rb = blockIdx.y * 64, cb = blockIdx.x * 128;
    const int sr = tid >> 2, sq = tid & 3;            // stager: row/col 0..63, k-quartet 0..3
    const int N = 256, Kd = 128;

    float4v acc[8];
#pragma unroll
    for (int s = 0; s < 8; s++) acc[s] = float4v{0.f, 0.f, 0.f, 0.f};

    for (int k0 = 0; k0 < Kd; k0 += 32) {
        __syncthreads();
        // ---- stage A: 4-partial f32 sum -> f16 ----
        {
            const _Float16* Ap16 = A + (size_t)(rb + sr) * Kd + k0 + sq * 8;
            const half8 p0 = *(const half8*)(Ap16);
            const half8 p1 = *(const half8*)(Ap16 + 2359296);
            const half8 p2 = *(const half8*)(Ap16 + 4718592);
            const half8 p3 = *(const half8*)(Ap16 + 7077888);
            half8 hv;
#pragma unroll
            for (int i = 0; i < 8; i++)
                hv[i] = (_Float16)((float)p0[i] + (float)p1[i] + (float)p2[i] + (float)p3[i]);
            *(half8*)&Af[sr * 40 + sq * 8] = hv;
        }
        // ---- stage B: 128 cols (two passes of 64) ----
#pragma unroll
        for (int hf = 0; hf < 2; hf++) {
            const float* Bp = B + (size_t)(k0 + sq * 8) * N + cb + hf * 64 + sr;
            half8 hv;
#pragma unroll
            for (int i = 0; i < 8; i++) hv[i] = (_Float16)Bp[(size_t)i * N];
            *(half8*)&Bf[(hf * 64 + sr) * 40 + sq * 8] = hv;
        }
        __syncthreads();
        const half8 af = *(const half8*)&Af[(w * 16 + l15) * 40 + quad * 8];
#pragma unroll
        for (int s = 0; s < 8; s++) {
            const half8 bf = *(const half8*)&Bf[(s * 16 + l15) * 40 + quad * 8];
            acc[s] = __builtin_amdgcn_mfma_f32_16x16x32_f16(af, bf, acc[s], 0, 0, 0);
        }
    }
    // ---- epilogue: plain f32 C ----
#pragma unroll
    for (int s = 0; s < 8; s++) {
#pragma unroll
        for (int r = 0; r < 4; r++) {
            const int row = rb + w * 16 + quad * 4 + r;
            const int col = cb + s * 16 + l15;
            Cv[(size_t)row * N + col] = acc[s][r];
        }
    }
}

// MFMA multipole (R21 + R24 setprio, verified) + R27: merged zg blocks.
//   grid (8,9,9): z<7 -> multipole rows z*64; z>=7 -> zg block
//   zb = (z-7)*72 + y*8 + x in [0,144): zb<64 -> rz, 64<=zb<128 -> G, else noop.
// zg depends on qf/ksum (prev dispatch); rz/G consumed by later dispatches.
__global__ __launch_bounds__(256, 2) void multipole_mm_k(const _Float16* __restrict__ trigA,
                                                         const _Float16* __restrict__ kfA,
                                                         const _Float16* __restrict__ v16T,
                                                         _Float16* __restrict__ M16,
                                                         const float* __restrict__ qf,
                                                         const float* __restrict__ ksum,
                                                         float* __restrict__ rz,
                                                         const float* __restrict__ a,
                                                         const float* __restrict__ cst,
                                                         float* __restrict__ G) {
    if (blockIdx.z >= 7) {
        const int zb = (blockIdx.z - 7) * 72 + blockIdx.y * 8 + blockIdx.x;
        if (zb >= 128) return;
        if (zb < 64) {
            const int idx = zb * 256 + threadIdx.x;   // N*H = 16384
            const int n = idx >> 3, h = idx & 7;
            float s = 0.f;
#pragma unroll
            for (int d = 0; d < 32; d++) s += qf[(size_t)n * 256 + h * 32 + d] * ksum[h * 32 + d];
            rz[idx] = 1.0f / (s + 1e-6f);
        } else {
            const int b = zb - 64;
            const int kk = b & 7, h = b >> 3;
            __shared__ float ae[9];
            if (threadIdx.x < 9) {
                const int ldeg[9] = {0, 1, 1, 1, 2, 2, 2, 2, 2};
                ae[threadIdx.x] = a[ldeg[threadIdx.x] * 64 + h * 8 + kk];
            }
            __syncthreads();
            const float* yw = cst;
            const float* rred = cst + 225;
            for (int i = threadIdx.x; i < 25 * 81; i += 256) {
                const int u = i / 81, lm = i - u * 81;
                float s = 0.f;
#pragma unroll
                for (int e = 0; e < 9; e++) s += ae[e] * yw[e * 25 + u] * rred[e * 81 + lm];
                G[((size_t)(kk * 8 + h) * 25 + u) * 81 + lm] = s;
            }
        }
        return;
    }

    const int h   = blockIdx.x;
    const int tid = threadIdx.x;
    const int w = tid >> 6, lane = tid & 63;
    const int l15 = lane & 15, quad = lane >> 4;
    const int cb  = blockIdx.y * 512 + w * 128;   // 4 cl per wave -> 128 cols
    const int cl0 = cb >> 5;
    const int r0  = blockIdx.z * 64;              // rows (kkut), 7*64 = 448

    __shared__ __align__(16) _Float16 sb[2][28][512];   // 56 KB

    float4v acc[4][8];
#pragma unroll
    for (int rt = 0; rt < 4; rt++)
#pragma unroll
        for (int s = 0; s < 8; s++) acc[rt][s] = float4v{0.f, 0.f, 0.f, 0.f};

    const _Float16* afg0 = trigA + (size_t)(r0 + l15) * 32 + quad * 8;            // + nb5*16384; +512/row-tile
    const _Float16* kqg0 = kfA + (size_t)h * 65536 + (size_t)l15 * 32 + quad * 8; // + nb5*1024
    const _Float16* kqg1 = kqg0 + 512;
    const int vs = lane >> 4, vc = (lane >> 2) & 3, vg = lane & 3;                // vq gather decomp
    const _Float16* vqg = v16T + (size_t)(h * 144 + cl0 + vc) * 2048 + vs * 32 + vg * 8; // + nbr

    half8 g0, g1, g2, g3, g4, g5, g6;

#define GATHER(nbr_) { \
        const size_t t5 = (size_t)((nbr_) >> 5) + w; \
        g0 = *(const half8*)(afg0 + t5 * 16384); \
        g1 = *(const half8*)(afg0 + t5 * 16384 + 512); \
        g2 = *(const half8*)(afg0 + t5 * 16384 + 1024); \
        g3 = *(const half8*)(afg0 + t5 * 16384 + 1536); \
        g4 = *(const half8*)(kqg0 + t5 * 1024); \
        g5 = *(const half8*)(kqg1 + t5 * 1024); \
        g6 = *(const half8*)(vqg + (nbr_)); }

#define DSWRITE(b_) { \
        *(half8*)&sb[b_][w * 6 + 0][lane * 8] = g0; \
        *(half8*)&sb[b_][w * 6 + 1][lane * 8] = g1; \
        *(half8*)&sb[b_][w * 6 + 2][lane * 8] = g2; \
        *(half8*)&sb[b_][w * 6 + 3][lane * 8] = g3; \
        *(half8*)&sb[b_][w * 6 + 4][lane * 8] = g4; \
        *(half8*)&sb[b_][w * 6 + 5][lane * 8] = g5; \
        *(half8*)&sb[b_][24 + w][lane * 8] = g6; }

#define STEP(s_) { \
        const half8 af0 = *(const half8*)&sb[cur][(s_) * 6 + 0][lane * 8]; \
        const half8 af1 = *(const half8*)&sb[cur][(s_) * 6 + 1][lane * 8]; \
        const half8 af2 = *(const half8*)&sb[cur][(s_) * 6 + 2][lane * 8]; \
        const half8 af3 = *(const half8*)&sb[cur][(s_) * 6 + 3][lane * 8]; \
        const half8 kq0 = *(const half8*)&sb[cur][(s_) * 6 + 4][lane * 8]; \
        const half8 kq1 = *(const half8*)&sb[cur][(s_) * 6 + 5][lane * 8]; \
        _Pragma("unroll") \
        for (int c = 0; c < 4; c++) { \
            const half8 vq = *(const half8*)&sb[cur][24 + w][((s_) * 4 + c) * 32 + quad * 8]; \
            const half8 b0 = kq0 * vq; \
            const half8 b1 = kq1 * vq; \
            acc[0][2 * c]     = __builtin_amdgcn_mfma_f32_16x16x32_f16(af0, b0, acc[0][2 * c],     0, 0, 0); \
            acc[0][2 * c + 1] = __builtin_amdgcn_mfma_f32_16x16x32_f16(af0, b1, acc[0][2 * c + 1], 0, 0, 0); \
            acc[1][2 * c]     = __builtin_amdgcn_mfma_f32_16x16x32_f16(af1, b0, acc[1][2 * c],     0, 0, 0); \
            acc[1][2 * c + 1] = __builtin_amdgcn_mfma_f32_16x16x32_f16(af1, b1, acc[1][2 * c + 1], 0, 0, 0); \
            acc[2][2 * c]     = __builtin_amdgcn_mfma_f32_16x16x32_f16(af2, b0, acc[2][2 * c],     0, 0, 0); \
            acc[2][2 * c + 1] = __builtin_amdgcn_mfma_f32_16x16x32_f16(af2, b1, acc[2][2 * c + 1], 0, 0, 0); \
            acc[3][2 * c]     = __builtin_amdgcn_mfma_f32_16x16x32_f16(af3, b0, acc[3][2 * c],     0, 0, 0); \
            acc[3][2 * c + 1] = __builtin_amdgcn_mfma_f32_16x16x32_f16(af3, b1, acc[3][2 * c + 1], 0, 0, 0); \
        } }

    int cur = 0;
    GATHER(0)
    DSWRITE(0)
    __syncthreads();
#pragma unroll 1
    for (int r = 0; r < 16; ++r) {
        if (r < 15) GATHER((r + 1) * 128)
        __builtin_amdgcn_s_setprio(1);
        STEP(0)
        STEP(1)
        STEP(2)
        STEP(3)
        __builtin_amdgcn_s_setprio(0);
        if (r < 15) DSWRITE(cur ^ 1)
        __syncthreads();
        cur ^= 1;
    }

#undef GATHER
#undef DSWRITE
#undef STEP

    // epilogue: C fragment -> M16[kkut][h][col]
#pragma unroll
    for (int rt = 0; rt < 4; rt++)
#pragma unroll
        for (int c = 0; c < 4; c++)
#pragma unroll
            for (int half = 0; half < 2; half++)
#pragma unroll
                for (int r = 0; r < 4; r++) {
                    const int row = r0 + rt * 16 + quad * 4 + r;
                    const int col = cb + c * 32 + half * 16 + l15;
                    M16[((size_t)row * 8 + h) * 4608 + col] = (_Float16)acc[rt][c * 2 + half][r];
                }
}

// MG[kt][h][...] = sum_l M16 * G  (R22 vectorized LDS path; R26 grid (8,400)
// h = blockIdx.x -> linear%8 = h matches multipole's M16 write affinity).
__global__ __launch_bounds__(256) void fold_k(const _Float16* __restrict__ Mv, const float* __restrict__ G,
                                              _Float16* __restrict__ MG) {
    const int h = blockIdx.x, kt = blockIdx.y;
    const int tid = threadIdx.x;
    __shared__ __align__(16) _Float16 ms16[144 * 40];   // [cl][d], stride 40 halves (80 B)
    __shared__ float gs[81];
    const _Float16* src = Mv + ((size_t)kt * 8 + h) * 4608;
    for (int o = tid; o < 576; o += 256) {
        const half8 v = *(const half8*)(src + o * 8);
        *(half8*)&ms16[(o >> 2) * 40 + (o & 3) * 8] = v;
    }
    const int kk = kt / 50, u = (kt >> 1) % 25;
    if (tid < 81) gs[tid] = G[(((size_t)kk * 8 + h) * 25 + u) * 81 + tid];
    __syncthreads();
    _Float16* dst = MG + ((size_t)kt * 8 + h) * 4608;
    for (int o = tid; o < 576; o += 256) {
        const int i0 = o * 8;
        const int ct = i0 >> 9, quad = (i0 >> 7) & 3, l15 = (i0 >> 3) & 15;
        const int d0 = quad * 8;
        const int cm = ct * 16 + l15, c = cm / 9, m = cm - c * 9;
        float s0 = 0.f, s1 = 0.f, s2 = 0.f, s3 = 0.f, s4 = 0.f, s5 = 0.f, s6 = 0.f, s7 = 0.f;
#pragma unroll
        for (int l = 0; l < 9; l++) {
            const float g = gs[l * 9 + m];
            const half8 mv = *(const half8*)&ms16[(c * 9 + l) * 40 + d0];
            s0 += (float)mv[0] * g; s1 += (float)mv[1] * g;
            s2 += (float)mv[2] * g; s3 += (float)mv[3] * g;
            s4 += (float)mv[4] * g; s5 += (float)mv[5] * g;
            s6 += (float)mv[6] * g; s7 += (float)mv[7] * g;
        }
        half8 hv;
        hv[0] = (_Float16)s0; hv[1] = (_Float16)s1; hv[2] = (_Float16)s2; hv[3] = (_Float16)s3;
        hv[4] = (_Float16)s4; hv[5] = (_Float16)s5; hv[6] = (_Float16)s6; hv[7] = (_Float16)s7;
        *(half8*)(dst + i0) = hv;
    }
}

// local stage via MFMA (R20 config + R24 setprio, verified) + R27 affinity:
// decode h = blockIdx.x, slice = blockIdx.y so linear%8 = h -> readers for
// head h land on the XCD whose L2 holds fold's freshly written MG slab
// (3.7 MB/head < 4 MB; L2 persists across dispatches). Per-XCD read capacity
// unchanged vs old decode; delta is write-to-read reuse.
__global__ __launch_bounds__(256, 2) void mm_local_k(const float* __restrict__ qf, const _Float16* __restrict__ trigA,
                                                     const _Float16* __restrict__ MG, const float* __restrict__ rZ,
                                                     _Float16* __restrict__ outp) {
    const int h = blockIdx.x;
    const int slice = blockIdx.y;
    const int n0 = blockIdx.z * 128;
    const int tid = threadIdx.x;
    const int w = tid >> 6, lane = tid & 63;
    const int l15 = lane & 15, quad = lane >> 4;

    // staging sb[2][4][4608] f16 (73728B), overlaid later by epilogue eb (37888B)
    __shared__ __align__(16) unsigned char smem_raw[73728];
    _Float16 (*sb)[4][4608] = (_Float16 (*)[4][4608])smem_raw;

    const int nbase = n0 + w * 32;                      // 32 rows per wave
    half8 qfr16[2];
#pragma unroll
    for (int rt = 0; rt < 2; rt++) {
        const int n = nbase + rt * 16 + l15;
        const float* qp = qf + (size_t)n * 256 + h * 32 + quad * 8;
#pragma unroll
        for (int j = 0; j < 8; j++) qfr16[rt][j] = (_Float16)qp[j];
    }
    float4v acc[2][9];
#pragma unroll
    for (int rt = 0; rt < 2; rt++)
#pragma unroll
        for (int ct = 0; ct < 9; ct++) acc[rt][ct] = float4v{0.f, 0.f, 0.f, 0.f};

    const int kt0 = slice * 100;
    const _Float16* mg0 = MG + (((size_t)kt0 * 8 + h) * 4608) + lane * 8;
    const _Float16* trg0 = trigA + (size_t)(nbase >> 5) * 16384 + (size_t)kt0 * 32 + l15;

#define STAGE4(b_, base_) { \
        const _Float16* src = mg0 + (size_t)((base_) + w) * 8 * 4608; \
        _Float16* dstl = &sb[b_][w][0]; \
        _Pragma("unroll") \
        for (int i = 0; i < 9; i++) \
            __builtin_amdgcn_global_load_lds( \
                (const __attribute__((address_space(1))) void*)(src + i * 512), \
                (__attribute__((address_space(3))) void*)(dstl + i * 512), 16, 0, 0); }

#define COMPUTE(kl) { \
        half8 tv0, tv1; \
        _Pragma("unroll") \
        for (int j = 0; j < 8; j++) { tv0[j] = ta[kl]; tv1[j] = tb[kl]; } \
        const half8 af0 = tv0 * qfr16[0]; \
        const half8 af1 = tv1 * qfr16[1]; \
        _Pragma("unroll") \
        for (int ct = 0; ct < 9; ct++) { \
            const half8 b = *(const half8*)&sb[cur][kl][ct * 512 + quad * 128 + l15 * 8]; \
            acc[0][ct] = __builtin_amdgcn_mfma_f32_16x16x32_f16(af0, b, acc[0][ct], 0, 0, 0); \
            acc[1][ct] = __builtin_amdgcn_mfma_f32_16x16x32_f16(af1, b, acc[1][ct], 0, 0, 0); \
        } }

    _Float16 ta[4], tb[4], ua[4], ub[4];
    int cur = 0;
    STAGE4(0, 0)
#pragma unroll
    for (int kl = 0; kl < 4; kl++) { ta[kl] = trg0[kl * 32]; tb[kl] = trg0[kl * 32 + 16]; }
    __syncthreads();

#pragma unroll 1
    for (int r = 0; r < 25; ++r) {
        if (r < 24) {
            STAGE4(cur ^ 1, (r + 1) * 4)
#pragma unroll
            for (int kl = 0; kl < 4; kl++) {
                const size_t o = (size_t)((r + 1) * 4 + kl) * 32;
                ua[kl] = trg0[o]; ub[kl] = trg0[o + 16];
            }
        }
        __builtin_amdgcn_s_setprio(1);
        COMPUTE(0) COMPUTE(1) COMPUTE(2) COMPUTE(3)
        __builtin_amdgcn_s_setprio(0);
        __syncthreads();
        cur ^= 1;
#pragma unroll
        for (int kl = 0; kl < 4; kl++) { ta[kl] = ua[kl]; tb[kl] = ub[kl]; }
    }

#undef STAGE4
#undef COMPUTE

    // epilogue: LDS transpose -> coalesced f16 stores into outp[slice][n][m][h*16+c]
    float* ebp = (float*)smem_raw;
    _Float16* dst = outp + (size_t)slice * 2359296;
    const int g4 = lane >> 2, sub = lane & 3;
#pragma unroll
    for (int rt = 0; rt < 2; rt++) {
        __syncthreads();
#pragma unroll
        for (int ct = 0; ct < 9; ct++) {
            const int cm = ct * 16 + l15;
            const int c = cm / 9, m = cm - c * 9;
#pragma unroll
            for (int r = 0; r < 4; r++)
                ebp[(size_t)(w * 16 + quad * 4 + r) * 148 + m * 16 + c] = acc[rt][ct][r];
        }
        __syncthreads();
#pragma unroll
        for (int s = 0; s < 9; s++) {
            const int li = s * 16 + g4;            // 0..143 line index
            const int nl = li / 9, m = li - nl * 9;
            const float4 v4 = *(const float4*)&ebp[(size_t)(w * 16 + nl) * 148 + m * 16 + sub * 4];
            const int n = nbase + rt * 16 + nl;
            const float rzv = rZ[(size_t)n * 8 + h];
            half4v hv;
            hv[0] = (_Float16)(v4.x * rzv); hv[1] = (_Float16)(v4.y * rzv);
            hv[2] = (_Float16)(v4.z * rzv); hv[3] = (_Float16)(v4.w * rzv);
            *(half4v*)&dst[((size_t)n * 9 + m) * 128 + h * 16 + sub * 4] = hv;
        }
    }
}

// ================================ launcher =================================
extern "C" void kernel_launch(void* const* d_in, const int* in_sizes, int n_in,
                              void* d_out, int out_size, void* d_ws, size_t ws_size,
                              hipStream_t stream) {
    const float* pos  = (const float*)d_in[0];
    const float* feat = (const float*)d_in[1];
    const float* Wq   = (const float*)d_in[2];
    const float* Wk   = (const float*)d_in[3];
    const float* Wv   = (const float*)d_in[4];
    const float* Wo   = (const float*)d_in[5];
    const float* a    = (const float*)d_in[6];
    const float* kap  = (const float*)d_in[7];
    float* out = (float*)d_out;
    float* ws = (float*)d_ws;

    // float-slot layout (~77.8 MB total)
    float* qf    = ws;                    // 524288
    float* kfAF  = qf + 524288;           // 262144 slots = kfA f16[8][64][2][512]
    float* vTF   = kfAF + 262144;         // 1179648 slots = v16T f16[1152*2048]
    float* trigF = vTF + 1179648;         // 524288 slots = trigA f16[64][512][32]
    float* ksum  = trigF + 524288;        // 256
    float* rz    = ksum + 256;            // 16384
    float* G     = rz + 16384;            // 129600
    float* M16F  = G + 129600;            // 9437184 slots = M16 f16[512*8*4608]; later outp f16[4][2359296]
    float* regX  = M16F + 9437184;        // 7372800 slots: R (first 1572864), later MG f16[400*8*4608]
    float* R     = regX;
    _Float16* trigA = (_Float16*)trigF;
    _Float16* kfA   = (_Float16*)kfAF;
    _Float16* v16T  = (_Float16*)vTF;
    _Float16* M16   = (_Float16*)M16F;
    _Float16* MG16  = (_Float16*)regX;
    _Float16* outp16 = (_Float16*)M16F;   // overlay: M16 dead after fold_k; 4 f16 partial buffers

    const float* cst = d_const_g;

    hipLaunchKernelGGL(radtrig_k, dim3(2048), dim3(256), 0, stream, feat, pos, kap, cst, R, trigA, ksum);
    hipLaunchKernelGGL(qkv_gemm_k, dim3(1088), dim3(256), 0, stream, R, Wq, Wk, feat, Wv, qf, kfA, ksum, v16T);
    hipLaunchKernelGGL(multipole_mm_k, dim3(8, 9, 9), dim3(256), 0, stream, trigA, kfA, v16T, M16, qf, ksum, rz, a, cst, G);
    hipLaunchKernelGGL(fold_k, dim3(8, 400), dim3(256), 0, stream, M16, G, MG16);
    hipLaunchKernelGGL(mm_local_k, dim3(8, 4, 16), dim3(256), 0, stream, qf, trigA, MG16, rz, outp16);
    hipLaunchKernelGGL(outg_k, dim3(2, 288), dim3(256), 0, stream, outp16, Wo, out);
}